// Round 8
// baseline (627.927 us; speedup 1.0000x reference)
//
#include <hip/hip_runtime.h>
#include <math.h>

// ---------------------------------------------------------------------------
// EmergencyGNNEnhanced: encoder (32->256->128) -> 3x GCN (->64) -> edge MLP.
// CSR built on-device each call. agg[v] = dinv[v]*(sum_{u->v} y[u] + y[v]).
//
// R8: fill rebuilt as a mapping-independent two-pass bucket partition.
// R7's nt-load fix failed (WRITE 73->68MB): col-line amplification is
// cross-XCD partial lines (a node's 16 entries written from many XCDs),
// not L2 capacity. Pass A: read edges ONCE, LDS-bucket by 2048-node window,
// flush full 64B lines to bucket scratch (1 global atomic / 16 edges).
// Pass B: ONE block per bucket places col entries -> every col line is
// written by a single block/L2 -> full-line writebacks by construction.
// MFMA layouts HW-verified (R5-R7 passed).
// ---------------------------------------------------------------------------

#define N_NODES 100000
#define N_EDGES 1600000
#define N_EL    200000
#define SCAN_NB 196          // ceil(100000/512)

#define KBUCK   49           // ceil(100000/2048) windows of 2048 nodes
#define WSHIFT  11
#define WMASK   2047
#define BCAP    96           // LDS entries per bucket
#define BSTRIDE 49152        // scratch ints per bucket (expected 32.7k, 85 sigma)
#define PART_NB 256          // pass-A blocks
#define CHUNK   6250         // ceil(N_EDGES / PART_NB)

typedef __attribute__((ext_vector_type(8))) short short8_t;
typedef __attribute__((ext_vector_type(4))) float f32x4;

__device__ __forceinline__ unsigned short f2bf(float f) {
    unsigned u = __float_as_uint(f);
    unsigned r = u + 0x7FFFu + ((u >> 16) & 1u);   // RNE
    return (unsigned short)(r >> 16);
}

__device__ __forceinline__ float2 up16(unsigned u) {
    union { unsigned v; _Float16 h[2]; } c; c.v = u;
    return make_float2((float)c.h[0], (float)c.h[1]);
}

// ---------------- CSR build ----------------
__global__ __launch_bounds__(256) void deg_kernel(const int* __restrict__ ei, int* __restrict__ cnt) {
    int e = blockIdx.x * 256 + threadIdx.x;
    if (e < N_EDGES) {
        int d = __builtin_nontemporal_load(ei + N_EDGES + e);
        atomicAdd(&cnt[d], 1);
    }
}

__global__ __launch_bounds__(256) void dinv_kernel(const int* __restrict__ cnt, float* __restrict__ dinv) {
    int i = blockIdx.x * 256 + threadIdx.x;
    if (i < N_NODES) dinv[i] = rsqrtf((float)(cnt[i] + 1));   // +1 self loop
}

__global__ __launch_bounds__(256) void scan1(const int* __restrict__ cnt, int* __restrict__ partial) {
    __shared__ int sm[256];
    int b = blockIdx.x, t = threadIdx.x;
    int base = b * 512;
    int v = 0;
    if (base + t < N_NODES)       v += cnt[base + t];
    if (base + 256 + t < N_NODES) v += cnt[base + 256 + t];
    sm[t] = v; __syncthreads();
    for (int s = 128; s > 0; s >>= 1) { if (t < s) sm[t] += sm[t + s]; __syncthreads(); }
    if (t == 0) partial[b] = sm[0];
}

__global__ __launch_bounds__(256) void scan2(int* __restrict__ partial, int* __restrict__ row_ptr) {
    __shared__ int sm[256];
    int t = threadIdx.x;
    int v = (t < SCAN_NB) ? partial[t] : 0;
    sm[t] = v; __syncthreads();
    for (int s = 1; s < 256; s <<= 1) {
        int add = (t >= s) ? sm[t - s] : 0;
        __syncthreads();
        sm[t] += add;
        __syncthreads();
    }
    if (t < SCAN_NB) partial[t] = sm[t] - v;          // exclusive
    if (t == 0) row_ptr[N_NODES] = N_EDGES;
}

__global__ __launch_bounds__(256) void scan3(const int* __restrict__ cnt, const int* __restrict__ partial,
                                             int* __restrict__ row_ptr, int* __restrict__ cursor) {
    __shared__ int sm[256];
    int b = blockIdx.x, t = threadIdx.x;
    int base = b * 512;
    int i0 = base + 2 * t, i1 = i0 + 1;
    int e0 = (i0 < N_NODES) ? cnt[i0] : 0;
    int e1 = (i1 < N_NODES) ? cnt[i1] : 0;
    int s2 = e0 + e1;
    sm[t] = s2; __syncthreads();
    for (int s = 1; s < 256; s <<= 1) {
        int add = (t >= s) ? sm[t - s] : 0;
        __syncthreads();
        sm[t] += add;
        __syncthreads();
    }
    int excl = sm[t] - s2 + partial[b];
    if (i0 < N_NODES) { row_ptr[i0] = excl;      cursor[i0] = excl; }
    if (i1 < N_NODES) { row_ptr[i1] = excl + e0; cursor[i1] = excl + e0; }
}

// ---- fill pass A: partition edges into 49 dst-window buckets ----
// Entry pack: (d & 2047) << 17 | src   (src < 2^17, local d 11 bits).
__global__ __launch_bounds__(256) void fill_part(const int* __restrict__ ei,
                                                 int* __restrict__ btail, int* __restrict__ bscr) {
    __shared__ int lbuf[KBUCK][BCAP];
    __shared__ int lcnt[KBUCK];
    int t = threadIdx.x;
    if (t < KBUCK) lcnt[t] = 0;
    __syncthreads();

    int e0   = blockIdx.x * CHUNK;
    int eend = e0 + CHUNK; if (eend > N_EDGES) eend = N_EDGES;
    int rounds = (CHUNK + 255) / 256;

    for (int r = 0; r < rounds; ++r) {
        int e = e0 + r * 256 + t;
        if (e < eend) {
            int s = ei[e];
            int d = ei[N_EDGES + e];
            int b = d >> WSHIFT;
            int entry = ((d & WMASK) << 17) | s;
            int pos = atomicAdd(&lcnt[b], 1);
            if (pos < BCAP) lbuf[b][pos] = entry;
            else {                               // rare skew spill
                int p = atomicAdd(&btail[b], 1);
                bscr[(size_t)b * BSTRIDE + p] = entry;
            }
        }
        __syncthreads();
        if (t < KBUCK) {
            int c = lcnt[t]; if (c > BCAP) c = BCAP;
            int nf = c & ~15;                    // full 64B lines only
            if (nf) {
                int gb = atomicAdd(&btail[t], nf);
                int* dst = bscr + (size_t)t * BSTRIDE + gb;
                for (int i = 0; i < nf; ++i) dst[i] = lbuf[t][i];
                int rem = c - nf;
                for (int i = 0; i < rem; ++i) lbuf[t][i] = lbuf[t][nf + i];
                lcnt[t] = rem;
            }
        }
        __syncthreads();
    }
    // drain partials (once per bucket per block)
    if (t < KBUCK) {
        int c = lcnt[t]; if (c > BCAP) c = BCAP;
        if (c) {
            int gb = atomicAdd(&btail[t], c);
            int* dst = bscr + (size_t)t * BSTRIDE + gb;
            for (int i = 0; i < c; ++i) dst[i] = lbuf[t][i];
        }
    }
}

// ---- fill pass B: one block per bucket -> single-L2 col window ----
__global__ __launch_bounds__(1024) void fill_place(const int* __restrict__ btail, const int* __restrict__ bscr,
                                                   int* __restrict__ cursor, int* __restrict__ col) {
    int b = blockIdx.x;
    int n = btail[b];
    int nodebase = b << WSHIFT;
    const int* src = bscr + (size_t)b * BSTRIDE;
    for (int i = threadIdx.x; i < n; i += 1024) {
        int e = src[i];
        int d = nodebase + (e >> 17);
        int p = atomicAdd(&cursor[d], 1);
        col[p] = e & 0x1FFFF;
    }
}

// ---------------- enc1: weight-stationary 32->256, bf16 output ----------------
__global__ __launch_bounds__(256, 2) void enc1_kernel(
    const float* __restrict__ x, const float* __restrict__ W,
    const float* __restrict__ bias, unsigned short* __restrict__ C)
{
    __shared__ float Ws[32][256];
    __shared__ float xt[32][68];
    __shared__ float bs[256];

    int t  = threadIdx.x;
    int r0 = blockIdx.x * 64;

    #pragma unroll
    for (int j = 0; j < 8; ++j) {
        int idx = t + j * 256;
        int kk = idx >> 6, cf = idx & 63;
        *(float4*)&Ws[kk][cf * 4] = *(const float4*)&W[kk * 256 + cf * 4];
    }
    if (t < 64) *(float4*)&bs[t * 4] = *(const float4*)&bias[t * 4];

    #pragma unroll
    for (int j = 0; j < 2; ++j) {
        int fidx = t + j * 256;
        int row = fidx >> 3, kf = fidx & 7;
        int gr = r0 + row;
        float4 v = (gr < N_NODES) ? *(const float4*)&x[(size_t)gr * 32 + kf * 4]
                                  : make_float4(0.f, 0.f, 0.f, 0.f);
        xt[kf * 4 + 0][row] = v.x; xt[kf * 4 + 1][row] = v.y;
        xt[kf * 4 + 2][row] = v.z; xt[kf * 4 + 3][row] = v.w;
    }
    __syncthreads();

    int tx = t & 63, ty = t >> 6;
    float4 b4 = *(const float4*)&bs[tx * 4];
    float4 acc[16];
    #pragma unroll
    for (int r = 0; r < 16; ++r) acc[r] = b4;

    #pragma unroll 4
    for (int k = 0; k < 32; ++k) {
        float4 w4 = *(const float4*)&Ws[k][tx * 4];
        #pragma unroll
        for (int j = 0; j < 4; ++j) {
            float4 a4 = *(const float4*)&xt[k][ty * 16 + j * 4];
            acc[j * 4 + 0].x += a4.x * w4.x; acc[j * 4 + 0].y += a4.x * w4.y;
            acc[j * 4 + 0].z += a4.x * w4.z; acc[j * 4 + 0].w += a4.x * w4.w;
            acc[j * 4 + 1].x += a4.y * w4.x; acc[j * 4 + 1].y += a4.y * w4.y;
            acc[j * 4 + 1].z += a4.y * w4.z; acc[j * 4 + 1].w += a4.y * w4.w;
            acc[j * 4 + 2].x += a4.z * w4.x; acc[j * 4 + 2].y += a4.z * w4.y;
            acc[j * 4 + 2].z += a4.z * w4.z; acc[j * 4 + 2].w += a4.z * w4.w;
            acc[j * 4 + 3].x += a4.w * w4.x; acc[j * 4 + 3].y += a4.w * w4.y;
            acc[j * 4 + 3].z += a4.w * w4.z; acc[j * 4 + 3].w += a4.w * w4.w;
        }
    }

    #pragma unroll
    for (int r = 0; r < 16; ++r) {
        int gr = r0 + ty * 16 + r;
        if (gr < N_NODES) {
            float4 v = acc[r];
            unsigned p0 = (unsigned)f2bf(fmaxf(v.x, 0.f)) | ((unsigned)f2bf(fmaxf(v.y, 0.f)) << 16);
            unsigned p1 = (unsigned)f2bf(fmaxf(v.z, 0.f)) | ((unsigned)f2bf(fmaxf(v.w, 0.f)) << 16);
            *(uint2*)&C[(size_t)gr * 256 + tx * 4] = make_uint2(p0, p1);
        }
    }
}

// ---------------- weight swizzle: fp32 W[K][N] -> bf16 B-fragment order -----
template<int KTOT, int NTOT>
__global__ __launch_bounds__(256) void wprep_kernel(const float* __restrict__ W, unsigned short* __restrict__ Wp) {
    int flat = blockIdx.x * 256 + threadIdx.x;
    if (flat >= KTOT * NTOT) return;
    int j = flat & 7, lane = (flat >> 3) & 63, kstep = (flat >> 9) & 1;
    int rest = flat >> 10;
    int ntile = rest % (NTOT / 16), chunk = rest / (NTOT / 16);
    int k = chunk * 64 + kstep * 32 + (lane >> 4) * 8 + j;
    int n = ntile * 16 + (lane & 15);
    Wp[flat] = f2bf(W[(size_t)k * NTOT + n]);
}

// ---------------- bf16 MFMA GEMM ----------------
template<int NTOT, int KTOT, bool GATHER, bool BIAS_RELU, int OUTT>
__device__ __forceinline__ void mfma_gemm_body(
    const unsigned short* __restrict__ A, const unsigned short* __restrict__ Wp,
    const float* __restrict__ bias, const float* __restrict__ dinv,
    void* __restrict__ Cout, const int* __restrict__ gidx, int M)
{
    constexpr int NT16 = NTOT / 16;
    constexpr int NCH  = KTOT / 64;
    __shared__ unsigned short As[64][72];
    __shared__ unsigned short Wls[NT16 * 1024];

    int t = threadIdx.x, wave = t >> 6, lane = t & 63;
    int m0 = blockIdx.x * 64;

    f32x4 acc[NT16];
    #pragma unroll
    for (int nt = 0; nt < NT16; ++nt) acc[nt] = (f32x4){0.f, 0.f, 0.f, 0.f};

    for (int ch = 0; ch < NCH; ++ch) {
        #pragma unroll
        for (int j = 0; j < 2; ++j) {
            int idx = t + j * 256;
            int row = idx >> 3, seg = idx & 7;
            int gr = m0 + row;
            uint4 v = make_uint4(0u, 0u, 0u, 0u);
            if (gr < M) {
                const unsigned short* src;
                if (GATHER) {
                    int node = (ch == 0) ? gidx[gr] : gidx[N_EL + gr];
                    src = A + (size_t)node * 64 + seg * 8;
                } else {
                    src = A + (size_t)gr * KTOT + ch * 64 + seg * 8;
                }
                v = *(const uint4*)src;
            }
            *(uint4*)&As[row][seg * 8] = v;
        }
        constexpr int WL16 = NT16 * 128;            // uint4 count
        #pragma unroll
        for (int j = 0; j < WL16 / 256; ++j) {
            int idx = t + j * 256;
            ((uint4*)Wls)[idx] = ((const uint4*)(Wp + (size_t)ch * NT16 * 1024))[idx];
        }
        __syncthreads();

        #pragma unroll
        for (int ks = 0; ks < 2; ++ks) {
            short8_t af = *(const short8_t*)&As[wave * 16 + (lane & 15)][ks * 32 + (lane >> 4) * 8];
            #pragma unroll
            for (int nt = 0; nt < NT16; ++nt) {
                short8_t bf = *(const short8_t*)&Wls[((nt * 2 + ks) * 64 + lane) * 8];
                acc[nt] = __builtin_amdgcn_mfma_f32_16x16x32_bf16(af, bf, acc[nt], 0, 0, 0);
            }
        }
        __syncthreads();
    }

    int cb = lane & 15, rq = lane >> 4;
    #pragma unroll
    for (int nt = 0; nt < NT16; ++nt) {
        int col = nt * 16 + cb;
        float bv = BIAS_RELU ? bias[col] : 0.f;
        #pragma unroll
        for (int r = 0; r < 4; ++r) {
            int gr = m0 + wave * 16 + rq * 4 + r;
            if (gr < M) {
                float val;
                if (BIAS_RELU) val = fmaxf(acc[nt][r] + bv, 0.f);
                else           val = acc[nt][r] * dinv[gr];
                size_t o = (size_t)gr * NTOT + col;
                if (OUTT == 1)      ((unsigned short*)Cout)[o] = f2bf(val);
                else if (OUTT == 2) ((_Float16*)Cout)[o] = (_Float16)val;
                else                ((float*)Cout)[o] = val;
            }
        }
    }
}

__global__ __launch_bounds__(256, 4) void mfma_enc2(const unsigned short* A, const unsigned short* Wp,
                                                    const float* b, unsigned short* C, int M) {
    mfma_gemm_body<128, 256, false, true, 1>(A, Wp, b, nullptr, C, nullptr, M);
}
__global__ __launch_bounds__(256, 4) void mfma_conv0(const unsigned short* A, const unsigned short* Wp,
                                                     const float* dinv, _Float16* C, int M) {
    mfma_gemm_body<64, 128, false, false, 2>(A, Wp, nullptr, dinv, C, nullptr, M);
}
__global__ __launch_bounds__(256, 4) void mfma_ep1(const unsigned short* A, const unsigned short* Wp,
                                                   const float* b, unsigned short* C, const int* gidx, int M) {
    mfma_gemm_body<128, 128, true, true, 1>(A, Wp, b, nullptr, C, gidx, M);
}

// ---------------- ep2 fused with ep3: sigmoid(relu(e1@W2+b2) . w3 + b3) -----
__global__ __launch_bounds__(256, 4) void mfma_ep2f(
    const unsigned short* __restrict__ A, const unsigned short* __restrict__ Wp,
    const float* __restrict__ b2, const float* __restrict__ w3,
    const float* __restrict__ b3, float* __restrict__ out, int M)
{
    constexpr int NT16 = 4;
    __shared__ unsigned short As[64][72];
    __shared__ unsigned short Wls[NT16 * 1024];

    int t = threadIdx.x, wave = t >> 6, lane = t & 63;
    int m0 = blockIdx.x * 64;

    f32x4 acc[NT16];
    #pragma unroll
    for (int nt = 0; nt < NT16; ++nt) acc[nt] = (f32x4){0.f, 0.f, 0.f, 0.f};

    for (int ch = 0; ch < 2; ++ch) {
        #pragma unroll
        for (int j = 0; j < 2; ++j) {
            int idx = t + j * 256;
            int row = idx >> 3, seg = idx & 7;
            int gr = m0 + row;
            uint4 v = make_uint4(0u, 0u, 0u, 0u);
            if (gr < M) v = *(const uint4*)(A + (size_t)gr * 128 + ch * 64 + seg * 8);
            *(uint4*)&As[row][seg * 8] = v;
        }
        #pragma unroll
        for (int j = 0; j < 2; ++j) {
            int idx = t + j * 256;
            ((uint4*)Wls)[idx] = ((const uint4*)(Wp + (size_t)ch * NT16 * 1024))[idx];
        }
        __syncthreads();

        #pragma unroll
        for (int ks = 0; ks < 2; ++ks) {
            short8_t af = *(const short8_t*)&As[wave * 16 + (lane & 15)][ks * 32 + (lane >> 4) * 8];
            #pragma unroll
            for (int nt = 0; nt < NT16; ++nt) {
                short8_t bf = *(const short8_t*)&Wls[((nt * 2 + ks) * 64 + lane) * 8];
                acc[nt] = __builtin_amdgcn_mfma_f32_16x16x32_bf16(af, bf, acc[nt], 0, 0, 0);
            }
        }
        __syncthreads();
    }

    int cb = lane & 15, rq = lane >> 4;
    float s0 = 0.f, s1 = 0.f, s2 = 0.f, s3 = 0.f;
    #pragma unroll
    for (int nt = 0; nt < NT16; ++nt) {
        int col = nt * 16 + cb;
        float bv = b2[col], wv = w3[col];
        s0 += fmaxf(acc[nt][0] + bv, 0.f) * wv;
        s1 += fmaxf(acc[nt][1] + bv, 0.f) * wv;
        s2 += fmaxf(acc[nt][2] + bv, 0.f) * wv;
        s3 += fmaxf(acc[nt][3] + bv, 0.f) * wv;
    }
    #pragma unroll
    for (int off = 1; off < 16; off <<= 1) {
        s0 += __shfl_xor(s0, off);
        s1 += __shfl_xor(s1, off);
        s2 += __shfl_xor(s2, off);
        s3 += __shfl_xor(s3, off);
    }
    if (cb == 0) {
        int gr = m0 + wave * 16 + rq * 4;
        if (gr + 3 < M) {
            float bb = b3[0];
            float4 o;
            o.x = 1.f / (1.f + expf(-(s0 + bb)));
            o.y = 1.f / (1.f + expf(-(s1 + bb)));
            o.z = 1.f / (1.f + expf(-(s2 + bb)));
            o.w = 1.f / (1.f + expf(-(s3 + bb)));
            *(float4*)&out[gr] = o;
        }
    }
}

// ---------------- fp32 tiled GEMM (conv1/2): y = f16(dinv .* (A@W)) ---------
template<int KTOT>
__device__ __forceinline__ void gemm_body(
    const float* __restrict__ A, const float* __restrict__ W,
    _Float16* __restrict__ C, const float* __restrict__ dinv, int M)
{
    constexpr int KB = 32;
    constexpr int NC = 64;
    __shared__ float As[KB][68];
    __shared__ float Ws[KB][64];

    int t  = threadIdx.x;
    int m0 = blockIdx.x * 64;
    int tx = t & 15, ty = t >> 4;

    float acc[4][4];
    #pragma unroll
    for (int r = 0; r < 4; ++r)
        #pragma unroll
        for (int c = 0; c < 4; ++c) acc[r][c] = 0.f;

    for (int k0 = 0; k0 < KTOT; k0 += KB) {
        #pragma unroll
        for (int j = 0; j < 2; ++j) {
            int idx = t + j * 256;
            int row = idx >> 3, kf = idx & 7;
            int gr  = m0 + row;
            float4 v = make_float4(0.f, 0.f, 0.f, 0.f);
            if (gr < M) v = *(const float4*)&A[(size_t)gr * KTOT + k0 + kf * 4];
            As[kf * 4 + 0][row] = v.x; As[kf * 4 + 1][row] = v.y;
            As[kf * 4 + 2][row] = v.z; As[kf * 4 + 3][row] = v.w;
        }
        #pragma unroll
        for (int j = 0; j < 2; ++j) {
            int idx = t + j * 256;
            int kk = idx >> 4, cf = idx & 15;
            *(float4*)&Ws[kk][cf * 4] = *(const float4*)&W[(size_t)(k0 + kk) * NC + cf * 4];
        }
        __syncthreads();

        #pragma unroll
        for (int kk = 0; kk < KB; ++kk) {
            float4 a4 = *(const float4*)&As[kk][ty * 4];
            float4 w4 = *(const float4*)&Ws[kk][tx * 4];
            acc[0][0] += a4.x * w4.x; acc[0][1] += a4.x * w4.y;
            acc[0][2] += a4.x * w4.z; acc[0][3] += a4.x * w4.w;
            acc[1][0] += a4.y * w4.x; acc[1][1] += a4.y * w4.y;
            acc[1][2] += a4.y * w4.z; acc[1][3] += a4.y * w4.w;
            acc[2][0] += a4.z * w4.x; acc[2][1] += a4.z * w4.y;
            acc[2][2] += a4.z * w4.z; acc[2][3] += a4.z * w4.w;
            acc[3][0] += a4.w * w4.x; acc[3][1] += a4.w * w4.y;
            acc[3][2] += a4.w * w4.z; acc[3][3] += a4.w * w4.w;
        }
        __syncthreads();
    }

    #pragma unroll
    for (int r = 0; r < 4; ++r) {
        int gr = m0 + ty * 4 + r;
        if (gr < M) {
            float s = dinv[gr];
            _Float16 tmp[4];
            tmp[0] = (_Float16)(acc[r][0] * s);
            tmp[1] = (_Float16)(acc[r][1] * s);
            tmp[2] = (_Float16)(acc[r][2] * s);
            tmp[3] = (_Float16)(acc[r][3] * s);
            *(uint2*)&C[(size_t)gr * NC + tx * 4] = *(uint2*)tmp;
        }
    }
}

__global__ __launch_bounds__(256, 4) void gemm_conv1(const float* A, const float* W, _Float16* C, const float* dinv, int M) {
    gemm_body<64>(A, W, C, dinv, M);
}
__global__ __launch_bounds__(256, 4) void gemm_conv2(const float* A, const float* W, _Float16* C, const float* dinv, int M) {
    gemm_body<64>(A, W, C, dinv, M);
}

// ---------------- CSR aggregation (R7 layout: 2 nodes/wave, f16x2/lane) -----
template<bool RESIDUAL, int OUTM>
__device__ __forceinline__ void agg_body(
    const unsigned* __restrict__ y32, const int* __restrict__ row_ptr, const int* __restrict__ col,
    const float* __restrict__ dinv, const float* __restrict__ bias,
    const float* __restrict__ hprev, float* __restrict__ hout,
    unsigned* __restrict__ hb32)
{
    int v  = blockIdx.x * 8 + (threadIdx.x >> 5);
    int sl = threadIdx.x & 31;
    if (v >= N_NODES) return;

    float2 a = up16(y32[(size_t)v * 32 + sl]);     // self loop
    float a0 = a.x, a1 = a.y;
    int s = row_ptr[v], e = row_ptr[v + 1];
    int i = s;
    for (; i + 3 < e; i += 4) {
        int u0 = col[i], u1 = col[i + 1], u2 = col[i + 2], u3 = col[i + 3];
        float2 f0 = up16(y32[(size_t)u0 * 32 + sl]);
        float2 f1 = up16(y32[(size_t)u1 * 32 + sl]);
        float2 f2 = up16(y32[(size_t)u2 * 32 + sl]);
        float2 f3 = up16(y32[(size_t)u3 * 32 + sl]);
        a0 += (f0.x + f1.x) + (f2.x + f3.x);
        a1 += (f0.y + f1.y) + (f2.y + f3.y);
    }
    for (; i < e; ++i) {
        float2 f = up16(y32[(size_t)col[i] * 32 + sl]);
        a0 += f.x; a1 += f.y;
    }
    float dv = dinv[v];
    float2 b = *(const float2*)&bias[sl * 2];
    float v0 = fmaxf(dv * a0 + b.x, 0.f);
    float v1 = fmaxf(dv * a1 + b.y, 0.f);
    size_t o = (size_t)v * 32 + sl;
    if (RESIDUAL) {
        float2 hp = *(const float2*)&hprev[o * 2];
        v0 += hp.x; v1 += hp.y;
    }
    if (OUTM == 2) {
        hb32[o] = (unsigned)f2bf(v0) | ((unsigned)f2bf(v1) << 16);
    } else {
        *(float2*)&hout[o * 2] = make_float2(v0, v1);
    }
}

__global__ __launch_bounds__(256) void agg0_kernel(const unsigned* y, const int* rp, const int* col,
                                                   const float* dinv, const float* b, float* h) {
    agg_body<false, 0>(y, rp, col, dinv, b, nullptr, h, nullptr);
}
__global__ __launch_bounds__(256) void agg1_kernel(const unsigned* y, const int* rp, const int* col,
                                                   const float* dinv, const float* b, float* h) {
    agg_body<true, 1>(y, rp, col, dinv, b, h, h, nullptr);   // in-place: half-wave owns its row
}
__global__ __launch_bounds__(256) void agg2_kernel(const unsigned* y, const int* rp, const int* col,
                                                   const float* dinv, const float* b,
                                                   const float* hprev, unsigned* hb) {
    agg_body<true, 2>(y, rp, col, dinv, b, hprev, nullptr, hb);
}

extern "C" void kernel_launch(void* const* d_in, const int* in_sizes, int n_in,
                              void* d_out, int out_size, void* d_ws, size_t ws_size,
                              hipStream_t stream) {
    const float* x       = (const float*)d_in[0];
    const int*   ei      = (const int*)d_in[1];
    const int*   eli     = (const int*)d_in[2];
    const float* enc_w1  = (const float*)d_in[3];
    const float* enc_b1  = (const float*)d_in[4];
    const float* enc_w2  = (const float*)d_in[5];
    const float* enc_b2  = (const float*)d_in[6];
    const float* conv_w0 = (const float*)d_in[7];
    const float* conv_b0 = (const float*)d_in[8];
    const float* conv_w1 = (const float*)d_in[9];
    const float* conv_b1 = (const float*)d_in[10];
    const float* conv_w2 = (const float*)d_in[11];
    const float* conv_b2 = (const float*)d_in[12];
    const float* ep_w1   = (const float*)d_in[13];
    const float* ep_b1   = (const float*)d_in[14];
    const float* ep_w2   = (const float*)d_in[15];
    const float* ep_b2   = (const float*)d_in[16];
    const float* ep_w3   = (const float*)d_in[17];
    const float* ep_b3   = (const float*)d_in[18];
    float* out = (float*)d_out;

    // ---- workspace layout (float offsets) ----
    float* fws = (float*)d_ws;
    unsigned short* h1b  = (unsigned short*)fws;                 // bf16 [100k,256] = 12.8M f
    unsigned short* e1b  = (unsigned short*)(fws + 12800000);    // bf16 [200k,128] = 12.8M f
    unsigned short* h128b= e1b;                                  // alias: bf16 [100k,128] (dead before ep1)
    _Float16* yb         = (_Float16*)(fws + 25600000);          // f16 [100k,64] = 3.2M f
    float* h64           = fws + 28800000;                       // f32 [100k,64] = 6.4M f
    unsigned short* h64b = (unsigned short*)(fws + 35200000);    // bf16 [100k,64] = 3.2M f
    int*   col     = (int*)(fws + 38400000);                     // 1.6M i
    int*   row_ptr = col + 1600000;                              // 100001 (padded)
    int*   cursor  = row_ptr + 100032;
    int*   cnt     = cursor + 100000;
    float* dinvp   = (float*)(cnt + 100000);
    int*   partial = (int*)(dinvp + 100000);                     // 256
    unsigned short* w2p = (unsigned short*)(partial + 256);      // enc_w2: 32768 us
    unsigned short* w0p = w2p + 32768;                           // conv_w0: 8192 us
    unsigned short* w1p = w0p + 8192;                            // ep_w1: 16384 us
    unsigned short* wp2 = w1p + 16384;                           // ep_w2: 8192 us
    int*   btail   = (int*)(wp2 + 8192);                         // 49 i (+pad)
    int*   bscr    = btail + 64;                                 // 49*49152 = 2.41M i

    // ---- CSR build + weight swizzle ----
    hipMemsetAsync(cnt, 0, N_NODES * sizeof(int), stream);
    hipMemsetAsync(btail, 0, 64 * sizeof(int), stream);
    deg_kernel <<<(N_EDGES + 255) / 256, 256, 0, stream>>>(ei, cnt);
    fill_part<<<PART_NB, 256, 0, stream>>>(ei, btail, bscr);
    wprep_kernel<256, 128><<<128, 256, 0, stream>>>(enc_w2,  w2p);
    wprep_kernel<128,  64><<< 32, 256, 0, stream>>>(conv_w0, w0p);
    wprep_kernel<128, 128><<< 64, 256, 0, stream>>>(ep_w1,   w1p);
    wprep_kernel<128,  64><<< 32, 256, 0, stream>>>(ep_w2,   wp2);
    dinv_kernel<<<(N_NODES + 255) / 256, 256, 0, stream>>>(cnt, dinvp);
    scan1<<<SCAN_NB, 256, 0, stream>>>(cnt, partial);
    scan2<<<1, 256, 0, stream>>>(partial, row_ptr);
    scan3<<<SCAN_NB, 256, 0, stream>>>(cnt, partial, row_ptr, cursor);
    fill_place<<<KBUCK, 1024, 0, stream>>>(btail, bscr, cursor, col);

    const int GBN = (N_NODES + 63) / 64;   // 1563
    const int GBE = N_EL / 64;             // 3125
    const int GBA = (N_NODES + 7) / 8;     // 12500

    // ---- encoder ----
    enc1_kernel<<<GBN, 256, 0, stream>>>(x, enc_w1, enc_b1, h1b);
    mfma_enc2<<<GBN, 256, 0, stream>>>(h1b, w2p, enc_b2, h128b, N_NODES);

    // ---- GCN layer 0: 128 -> 64 (MFMA, bf16 in, f16 y out) ----
    mfma_conv0<<<GBN, 256, 0, stream>>>(h128b, w0p, dinvp, yb, N_NODES);
    agg0_kernel<<<GBA, 256, 0, stream>>>((const unsigned*)yb, row_ptr, col, dinvp, conv_b0, h64);

    // ---- GCN layer 1: 64 -> 64, residual ----
    gemm_conv1<<<GBN, 256, 0, stream>>>(h64, conv_w1, yb, dinvp, N_NODES);
    agg1_kernel<<<GBA, 256, 0, stream>>>((const unsigned*)yb, row_ptr, col, dinvp, conv_b1, h64);

    // ---- GCN layer 2: 64 -> 64, residual, bf16 out for ep1 ----
    gemm_conv2<<<GBN, 256, 0, stream>>>(h64, conv_w2, yb, dinvp, N_NODES);
    agg2_kernel<<<GBA, 256, 0, stream>>>((const unsigned*)yb, row_ptr, col, dinvp, conv_b2, h64, (unsigned*)h64b);

    // ---- edge predictor (bf16 MFMA; ep2+ep3 fused) ----
    mfma_ep1<<<GBE, 256, 0, stream>>>(h64b, w1p, ep_b1, e1b, eli, N_EL);
    mfma_ep2f<<<GBE, 256, 0, stream>>>(e1b, wp2, ep_b2, ep_w3, ep_b3, out, N_EL);
}

// Round 9
// 502.864 us; speedup vs baseline: 1.2487x; 1.2487x over previous
//
#include <hip/hip_runtime.h>
#include <math.h>

// ---------------------------------------------------------------------------
// EmergencyGNNEnhanced: encoder (32->256->128) -> 3x GCN (->64) -> edge MLP.
// CSR built on-device each call. agg[v] = dinv[v]*(sum_{u->v} y[u] + y[v]).
//
// R9: fill with ALL-COALESCED global writes. R8 proved scattered 4B stores
// cost ~40B HBM write each regardless of locality (62MB for 6.4MB logical,
// even with one block per bucket). So: pass A chunks edges into 98 LDS
// buckets and flushes ONCE cooperatively (contiguous per-bucket runs);
// pass B scatters within LDS (lcur LDS atomics -> lbuf) and streams the
// bucket's contiguous col segment out coalesced. Zero scattered global
// stores, zero global cursor atomics. MFMA layouts HW-verified (R5-R8).
// ---------------------------------------------------------------------------

#define N_NODES 100000
#define N_EDGES 1600000
#define N_EL    200000
#define SCAN_NB 196          // ceil(100000/512)

#define KBUCK   98           // ceil(100000/1024) windows of 1024 nodes
#define WSHIFT  10
#define WMASK   1023
#define BCAP    128          // LDS entries/bucket in pass A (chunk avg 64, 8 sigma)
#define BSTRIDE 24576        // scratch ints per bucket (seglen ~16.4k avg)
#define PART_NB 256
#define CHUNK   6250         // ceil(N_EDGES / PART_NB)
#define LCAP    20480        // pass-B LDS staging (seglen max ~17k)

typedef __attribute__((ext_vector_type(8))) short short8_t;
typedef __attribute__((ext_vector_type(4))) float f32x4;

__device__ __forceinline__ unsigned short f2bf(float f) {
    unsigned u = __float_as_uint(f);
    unsigned r = u + 0x7FFFu + ((u >> 16) & 1u);   // RNE
    return (unsigned short)(r >> 16);
}

__device__ __forceinline__ float2 up16(unsigned u) {
    union { unsigned v; _Float16 h[2]; } c; c.v = u;
    return make_float2((float)c.h[0], (float)c.h[1]);
}

// ---------------- CSR build ----------------
__global__ __launch_bounds__(256) void deg_kernel(const int* __restrict__ ei, int* __restrict__ cnt) {
    int e = blockIdx.x * 256 + threadIdx.x;
    if (e < N_EDGES) {
        int d = __builtin_nontemporal_load(ei + N_EDGES + e);
        atomicAdd(&cnt[d], 1);
    }
}

__global__ __launch_bounds__(256) void dinv_kernel(const int* __restrict__ cnt, float* __restrict__ dinv) {
    int i = blockIdx.x * 256 + threadIdx.x;
    if (i < N_NODES) dinv[i] = rsqrtf((float)(cnt[i] + 1));   // +1 self loop
}

__global__ __launch_bounds__(256) void scan1(const int* __restrict__ cnt, int* __restrict__ partial) {
    __shared__ int sm[256];
    int b = blockIdx.x, t = threadIdx.x;
    int base = b * 512;
    int v = 0;
    if (base + t < N_NODES)       v += cnt[base + t];
    if (base + 256 + t < N_NODES) v += cnt[base + 256 + t];
    sm[t] = v; __syncthreads();
    for (int s = 128; s > 0; s >>= 1) { if (t < s) sm[t] += sm[t + s]; __syncthreads(); }
    if (t == 0) partial[b] = sm[0];
}

__global__ __launch_bounds__(256) void scan2(int* __restrict__ partial, int* __restrict__ row_ptr) {
    __shared__ int sm[256];
    int t = threadIdx.x;
    int v = (t < SCAN_NB) ? partial[t] : 0;
    sm[t] = v; __syncthreads();
    for (int s = 1; s < 256; s <<= 1) {
        int add = (t >= s) ? sm[t - s] : 0;
        __syncthreads();
        sm[t] += add;
        __syncthreads();
    }
    if (t < SCAN_NB) partial[t] = sm[t] - v;          // exclusive
    if (t == 0) row_ptr[N_NODES] = N_EDGES;
}

__global__ __launch_bounds__(256) void scan3(const int* __restrict__ cnt, const int* __restrict__ partial,
                                             int* __restrict__ row_ptr) {
    __shared__ int sm[256];
    int b = blockIdx.x, t = threadIdx.x;
    int base = b * 512;
    int i0 = base + 2 * t, i1 = i0 + 1;
    int e0 = (i0 < N_NODES) ? cnt[i0] : 0;
    int e1 = (i1 < N_NODES) ? cnt[i1] : 0;
    int s2 = e0 + e1;
    sm[t] = s2; __syncthreads();
    for (int s = 1; s < 256; s <<= 1) {
        int add = (t >= s) ? sm[t - s] : 0;
        __syncthreads();
        sm[t] += add;
        __syncthreads();
    }
    int excl = sm[t] - s2 + partial[b];
    if (i0 < N_NODES) row_ptr[i0] = excl;
    if (i1 < N_NODES) row_ptr[i1] = excl + e0;
}

// ---- fill pass A: partition edges into 98 dst-window buckets ----
// Entry pack: (d & 1023) << 17 | src (src < 2^17). Whole 6250-edge chunk
// accumulates in LDS, then ONE cooperative flush with contiguous runs.
__global__ __launch_bounds__(256) void fill_part(const int* __restrict__ ei,
                                                 int* __restrict__ btail, int* __restrict__ bscr) {
    __shared__ int lbuf[KBUCK][BCAP];     // 50 KB
    __shared__ int lcnt[KBUCK];
    __shared__ int offs[KBUCK + 1];
    __shared__ int gbase[KBUCK];
    int t = threadIdx.x;
    for (int i = t; i < KBUCK; i += 256) lcnt[i] = 0;
    __syncthreads();

    int e0   = blockIdx.x * CHUNK;
    int eend = e0 + CHUNK; if (eend > N_EDGES) eend = N_EDGES;
    for (int e = e0 + t; e < eend; e += 256) {
        int s = __builtin_nontemporal_load(ei + e);
        int d = __builtin_nontemporal_load(ei + N_EDGES + e);
        int b = d >> WSHIFT;
        int entry = ((d & WMASK) << 17) | s;
        int pos = atomicAdd(&lcnt[b], 1);
        if (pos < BCAP) lbuf[b][pos] = entry;
        else {                                  // statistical-skew spill (rare)
            int p = atomicAdd(&btail[b], 1);
            bscr[b * BSTRIDE + p] = entry;
        }
    }
    __syncthreads();

    if (t < KBUCK) {
        int c = lcnt[t]; if (c > BCAP) c = BCAP;
        lcnt[t] = c;
        gbase[t] = atomicAdd(&btail[t], c);
    }
    __syncthreads();
    if (t == 0) {
        offs[0] = 0;
        for (int b = 0; b < KBUCK; ++b) offs[b + 1] = offs[b] + lcnt[b];
    }
    __syncthreads();

    int T = offs[KBUCK];
    for (int i = t; i < T; i += 256) {
        int loB = 0, hiB = KBUCK;               // binary search bucket
        while (hiB - loB > 1) { int mid = (loB + hiB) >> 1; if (offs[mid] <= i) loB = mid; else hiB = mid; }
        int j = i - offs[loB];
        bscr[loB * BSTRIDE + gbase[loB] + j] = lbuf[loB][j];
    }
}

// ---- fill pass B: LDS scatter, coalesced col segment write ----
// Bucket b's col segment [row_ptr[lo], row_ptr[hi]) is contiguous: scatter
// entries into lbuf via LDS cursor atomics, then stream out full lines.
__global__ __launch_bounds__(1024) void fill_place(const int* __restrict__ btail, const int* __restrict__ bscr,
                                                   const int* __restrict__ row_ptr, int* __restrict__ col) {
    __shared__ int lcur[1024];
    __shared__ int lbuf[LCAP];                  // 80 KB
    int b = blockIdx.x, t = threadIdx.x;
    int lo = b << WSHIFT;
    int hi = lo + 1024; if (hi > N_NODES) hi = N_NODES;
    int segstart = row_ptr[lo];
    int seglen   = row_ptr[hi] - segstart;
    int n = btail[b];
    const int* src = bscr + b * BSTRIDE;
    if (t < hi - lo) lcur[t] = row_ptr[lo + t] - segstart;
    __syncthreads();

    if (seglen <= LCAP) {
        for (int i = t; i < n; i += 1024) {
            int e = src[i];
            int pos = atomicAdd(&lcur[e >> 17], 1);
            lbuf[pos] = e & 0x1FFFF;
        }
        __syncthreads();
        for (int i = t; i < seglen; i += 1024)
            col[segstart + i] = lbuf[i];
    } else {                                    // safety fallback (never for this dist)
        for (int i = t; i < n; i += 1024) {
            int e = src[i];
            int pos = atomicAdd(&lcur[e >> 17], 1);
            col[segstart + pos] = e & 0x1FFFF;
        }
    }
}

// ---------------- enc1: weight-stationary 32->256, bf16 output ----------------
__global__ __launch_bounds__(256, 2) void enc1_kernel(
    const float* __restrict__ x, const float* __restrict__ W,
    const float* __restrict__ bias, unsigned short* __restrict__ C)
{
    __shared__ float Ws[32][256];
    __shared__ float xt[32][68];
    __shared__ float bs[256];

    int t  = threadIdx.x;
    int r0 = blockIdx.x * 64;

    #pragma unroll
    for (int j = 0; j < 8; ++j) {
        int idx = t + j * 256;
        int kk = idx >> 6, cf = idx & 63;
        *(float4*)&Ws[kk][cf * 4] = *(const float4*)&W[kk * 256 + cf * 4];
    }
    if (t < 64) *(float4*)&bs[t * 4] = *(const float4*)&bias[t * 4];

    #pragma unroll
    for (int j = 0; j < 2; ++j) {
        int fidx = t + j * 256;
        int row = fidx >> 3, kf = fidx & 7;
        int gr = r0 + row;
        float4 v = (gr < N_NODES) ? *(const float4*)&x[(size_t)gr * 32 + kf * 4]
                                  : make_float4(0.f, 0.f, 0.f, 0.f);
        xt[kf * 4 + 0][row] = v.x; xt[kf * 4 + 1][row] = v.y;
        xt[kf * 4 + 2][row] = v.z; xt[kf * 4 + 3][row] = v.w;
    }
    __syncthreads();

    int tx = t & 63, ty = t >> 6;
    float4 b4 = *(const float4*)&bs[tx * 4];
    float4 acc[16];
    #pragma unroll
    for (int r = 0; r < 16; ++r) acc[r] = b4;

    #pragma unroll 4
    for (int k = 0; k < 32; ++k) {
        float4 w4 = *(const float4*)&Ws[k][tx * 4];
        #pragma unroll
        for (int j = 0; j < 4; ++j) {
            float4 a4 = *(const float4*)&xt[k][ty * 16 + j * 4];
            acc[j * 4 + 0].x += a4.x * w4.x; acc[j * 4 + 0].y += a4.x * w4.y;
            acc[j * 4 + 0].z += a4.x * w4.z; acc[j * 4 + 0].w += a4.x * w4.w;
            acc[j * 4 + 1].x += a4.y * w4.x; acc[j * 4 + 1].y += a4.y * w4.y;
            acc[j * 4 + 1].z += a4.y * w4.z; acc[j * 4 + 1].w += a4.y * w4.w;
            acc[j * 4 + 2].x += a4.z * w4.x; acc[j * 4 + 2].y += a4.z * w4.y;
            acc[j * 4 + 2].z += a4.z * w4.z; acc[j * 4 + 2].w += a4.z * w4.w;
            acc[j * 4 + 3].x += a4.w * w4.x; acc[j * 4 + 3].y += a4.w * w4.y;
            acc[j * 4 + 3].z += a4.w * w4.z; acc[j * 4 + 3].w += a4.w * w4.w;
        }
    }

    #pragma unroll
    for (int r = 0; r < 16; ++r) {
        int gr = r0 + ty * 16 + r;
        if (gr < N_NODES) {
            float4 v = acc[r];
            unsigned p0 = (unsigned)f2bf(fmaxf(v.x, 0.f)) | ((unsigned)f2bf(fmaxf(v.y, 0.f)) << 16);
            unsigned p1 = (unsigned)f2bf(fmaxf(v.z, 0.f)) | ((unsigned)f2bf(fmaxf(v.w, 0.f)) << 16);
            *(uint2*)&C[(size_t)gr * 256 + tx * 4] = make_uint2(p0, p1);
        }
    }
}

// ---------------- weight swizzle: fp32 W[K][N] -> bf16 B-fragment order -----
template<int KTOT, int NTOT>
__global__ __launch_bounds__(256) void wprep_kernel(const float* __restrict__ W, unsigned short* __restrict__ Wp) {
    int flat = blockIdx.x * 256 + threadIdx.x;
    if (flat >= KTOT * NTOT) return;
    int j = flat & 7, lane = (flat >> 3) & 63, kstep = (flat >> 9) & 1;
    int rest = flat >> 10;
    int ntile = rest % (NTOT / 16), chunk = rest / (NTOT / 16);
    int k = chunk * 64 + kstep * 32 + (lane >> 4) * 8 + j;
    int n = ntile * 16 + (lane & 15);
    Wp[flat] = f2bf(W[(size_t)k * NTOT + n]);
}

// ---------------- bf16 MFMA GEMM ----------------
template<int NTOT, int KTOT, bool GATHER, bool BIAS_RELU, int OUTT>
__device__ __forceinline__ void mfma_gemm_body(
    const unsigned short* __restrict__ A, const unsigned short* __restrict__ Wp,
    const float* __restrict__ bias, const float* __restrict__ dinv,
    void* __restrict__ Cout, const int* __restrict__ gidx, int M)
{
    constexpr int NT16 = NTOT / 16;
    constexpr int NCH  = KTOT / 64;
    __shared__ unsigned short As[64][72];
    __shared__ unsigned short Wls[NT16 * 1024];

    int t = threadIdx.x, wave = t >> 6, lane = t & 63;
    int m0 = blockIdx.x * 64;

    f32x4 acc[NT16];
    #pragma unroll
    for (int nt = 0; nt < NT16; ++nt) acc[nt] = (f32x4){0.f, 0.f, 0.f, 0.f};

    for (int ch = 0; ch < NCH; ++ch) {
        #pragma unroll
        for (int j = 0; j < 2; ++j) {
            int idx = t + j * 256;
            int row = idx >> 3, seg = idx & 7;
            int gr = m0 + row;
            uint4 v = make_uint4(0u, 0u, 0u, 0u);
            if (gr < M) {
                const unsigned short* src;
                if (GATHER) {
                    int node = (ch == 0) ? gidx[gr] : gidx[N_EL + gr];
                    src = A + (size_t)node * 64 + seg * 8;
                } else {
                    src = A + (size_t)gr * KTOT + ch * 64 + seg * 8;
                }
                v = *(const uint4*)src;
            }
            *(uint4*)&As[row][seg * 8] = v;
        }
        constexpr int WL16 = NT16 * 128;            // uint4 count
        #pragma unroll
        for (int j = 0; j < WL16 / 256; ++j) {
            int idx = t + j * 256;
            ((uint4*)Wls)[idx] = ((const uint4*)(Wp + (size_t)ch * NT16 * 1024))[idx];
        }
        __syncthreads();

        #pragma unroll
        for (int ks = 0; ks < 2; ++ks) {
            short8_t af = *(const short8_t*)&As[wave * 16 + (lane & 15)][ks * 32 + (lane >> 4) * 8];
            #pragma unroll
            for (int nt = 0; nt < NT16; ++nt) {
                short8_t bf = *(const short8_t*)&Wls[((nt * 2 + ks) * 64 + lane) * 8];
                acc[nt] = __builtin_amdgcn_mfma_f32_16x16x32_bf16(af, bf, acc[nt], 0, 0, 0);
            }
        }
        __syncthreads();
    }

    int cb = lane & 15, rq = lane >> 4;
    #pragma unroll
    for (int nt = 0; nt < NT16; ++nt) {
        int col = nt * 16 + cb;
        float bv = BIAS_RELU ? bias[col] : 0.f;
        #pragma unroll
        for (int r = 0; r < 4; ++r) {
            int gr = m0 + wave * 16 + rq * 4 + r;
            if (gr < M) {
                float val;
                if (BIAS_RELU) val = fmaxf(acc[nt][r] + bv, 0.f);
                else           val = acc[nt][r] * dinv[gr];
                size_t o = (size_t)gr * NTOT + col;
                if (OUTT == 1)      ((unsigned short*)Cout)[o] = f2bf(val);
                else if (OUTT == 2) ((_Float16*)Cout)[o] = (_Float16)val;
                else                ((float*)Cout)[o] = val;
            }
        }
    }
}

__global__ __launch_bounds__(256, 4) void mfma_enc2(const unsigned short* A, const unsigned short* Wp,
                                                    const float* b, unsigned short* C, int M) {
    mfma_gemm_body<128, 256, false, true, 1>(A, Wp, b, nullptr, C, nullptr, M);
}
__global__ __launch_bounds__(256, 4) void mfma_conv0(const unsigned short* A, const unsigned short* Wp,
                                                     const float* dinv, _Float16* C, int M) {
    mfma_gemm_body<64, 128, false, false, 2>(A, Wp, nullptr, dinv, C, nullptr, M);
}
__global__ __launch_bounds__(256, 4) void mfma_ep1(const unsigned short* A, const unsigned short* Wp,
                                                   const float* b, unsigned short* C, const int* gidx, int M) {
    mfma_gemm_body<128, 128, true, true, 1>(A, Wp, b, nullptr, C, gidx, M);
}

// ---------------- ep2 fused with ep3: sigmoid(relu(e1@W2+b2) . w3 + b3) -----
__global__ __launch_bounds__(256, 4) void mfma_ep2f(
    const unsigned short* __restrict__ A, const unsigned short* __restrict__ Wp,
    const float* __restrict__ b2, const float* __restrict__ w3,
    const float* __restrict__ b3, float* __restrict__ out, int M)
{
    constexpr int NT16 = 4;
    __shared__ unsigned short As[64][72];
    __shared__ unsigned short Wls[NT16 * 1024];

    int t = threadIdx.x, wave = t >> 6, lane = t & 63;
    int m0 = blockIdx.x * 64;

    f32x4 acc[NT16];
    #pragma unroll
    for (int nt = 0; nt < NT16; ++nt) acc[nt] = (f32x4){0.f, 0.f, 0.f, 0.f};

    for (int ch = 0; ch < 2; ++ch) {
        #pragma unroll
        for (int j = 0; j < 2; ++j) {
            int idx = t + j * 256;
            int row = idx >> 3, seg = idx & 7;
            int gr = m0 + row;
            uint4 v = make_uint4(0u, 0u, 0u, 0u);
            if (gr < M) v = *(const uint4*)(A + (size_t)gr * 128 + ch * 64 + seg * 8);
            *(uint4*)&As[row][seg * 8] = v;
        }
        #pragma unroll
        for (int j = 0; j < 2; ++j) {
            int idx = t + j * 256;
            ((uint4*)Wls)[idx] = ((const uint4*)(Wp + (size_t)ch * NT16 * 1024))[idx];
        }
        __syncthreads();

        #pragma unroll
        for (int ks = 0; ks < 2; ++ks) {
            short8_t af = *(const short8_t*)&As[wave * 16 + (lane & 15)][ks * 32 + (lane >> 4) * 8];
            #pragma unroll
            for (int nt = 0; nt < NT16; ++nt) {
                short8_t bf = *(const short8_t*)&Wls[((nt * 2 + ks) * 64 + lane) * 8];
                acc[nt] = __builtin_amdgcn_mfma_f32_16x16x32_bf16(af, bf, acc[nt], 0, 0, 0);
            }
        }
        __syncthreads();
    }

    int cb = lane & 15, rq = lane >> 4;
    float s0 = 0.f, s1 = 0.f, s2 = 0.f, s3 = 0.f;
    #pragma unroll
    for (int nt = 0; nt < NT16; ++nt) {
        int col = nt * 16 + cb;
        float bv = b2[col], wv = w3[col];
        s0 += fmaxf(acc[nt][0] + bv, 0.f) * wv;
        s1 += fmaxf(acc[nt][1] + bv, 0.f) * wv;
        s2 += fmaxf(acc[nt][2] + bv, 0.f) * wv;
        s3 += fmaxf(acc[nt][3] + bv, 0.f) * wv;
    }
    #pragma unroll
    for (int off = 1; off < 16; off <<= 1) {
        s0 += __shfl_xor(s0, off);
        s1 += __shfl_xor(s1, off);
        s2 += __shfl_xor(s2, off);
        s3 += __shfl_xor(s3, off);
    }
    if (cb == 0) {
        int gr = m0 + wave * 16 + rq * 4;
        if (gr + 3 < M) {
            float bb = b3[0];
            float4 o;
            o.x = 1.f / (1.f + expf(-(s0 + bb)));
            o.y = 1.f / (1.f + expf(-(s1 + bb)));
            o.z = 1.f / (1.f + expf(-(s2 + bb)));
            o.w = 1.f / (1.f + expf(-(s3 + bb)));
            *(float4*)&out[gr] = o;
        }
    }
}

// ---------------- fp32 tiled GEMM (conv1/2): y = f16(dinv .* (A@W)) ---------
template<int KTOT>
__device__ __forceinline__ void gemm_body(
    const float* __restrict__ A, const float* __restrict__ W,
    _Float16* __restrict__ C, const float* __restrict__ dinv, int M)
{
    constexpr int KB = 32;
    constexpr int NC = 64;
    __shared__ float As[KB][68];
    __shared__ float Ws[KB][64];

    int t  = threadIdx.x;
    int m0 = blockIdx.x * 64;
    int tx = t & 15, ty = t >> 4;

    float acc[4][4];
    #pragma unroll
    for (int r = 0; r < 4; ++r)
        #pragma unroll
        for (int c = 0; c < 4; ++c) acc[r][c] = 0.f;

    for (int k0 = 0; k0 < KTOT; k0 += KB) {
        #pragma unroll
        for (int j = 0; j < 2; ++j) {
            int idx = t + j * 256;
            int row = idx >> 3, kf = idx & 7;
            int gr  = m0 + row;
            float4 v = make_float4(0.f, 0.f, 0.f, 0.f);
            if (gr < M) v = *(const float4*)&A[(size_t)gr * KTOT + k0 + kf * 4];
            As[kf * 4 + 0][row] = v.x; As[kf * 4 + 1][row] = v.y;
            As[kf * 4 + 2][row] = v.z; As[kf * 4 + 3][row] = v.w;
        }
        #pragma unroll
        for (int j = 0; j < 2; ++j) {
            int idx = t + j * 256;
            int kk = idx >> 4, cf = idx & 15;
            *(float4*)&Ws[kk][cf * 4] = *(const float4*)&W[(size_t)(k0 + kk) * NC + cf * 4];
        }
        __syncthreads();

        #pragma unroll
        for (int kk = 0; kk < KB; ++kk) {
            float4 a4 = *(const float4*)&As[kk][ty * 4];
            float4 w4 = *(const float4*)&Ws[kk][tx * 4];
            acc[0][0] += a4.x * w4.x; acc[0][1] += a4.x * w4.y;
            acc[0][2] += a4.x * w4.z; acc[0][3] += a4.x * w4.w;
            acc[1][0] += a4.y * w4.x; acc[1][1] += a4.y * w4.y;
            acc[1][2] += a4.y * w4.z; acc[1][3] += a4.y * w4.w;
            acc[2][0] += a4.z * w4.x; acc[2][1] += a4.z * w4.y;
            acc[2][2] += a4.z * w4.z; acc[2][3] += a4.z * w4.w;
            acc[3][0] += a4.w * w4.x; acc[3][1] += a4.w * w4.y;
            acc[3][2] += a4.w * w4.z; acc[3][3] += a4.w * w4.w;
        }
        __syncthreads();
    }

    #pragma unroll
    for (int r = 0; r < 4; ++r) {
        int gr = m0 + ty * 4 + r;
        if (gr < M) {
            float s = dinv[gr];
            _Float16 tmp[4];
            tmp[0] = (_Float16)(acc[r][0] * s);
            tmp[1] = (_Float16)(acc[r][1] * s);
            tmp[2] = (_Float16)(acc[r][2] * s);
            tmp[3] = (_Float16)(acc[r][3] * s);
            *(uint2*)&C[(size_t)gr * NC + tx * 4] = *(uint2*)tmp;
        }
    }
}

__global__ __launch_bounds__(256, 4) void gemm_conv1(const float* A, const float* W, _Float16* C, const float* dinv, int M) {
    gemm_body<64>(A, W, C, dinv, M);
}
__global__ __launch_bounds__(256, 4) void gemm_conv2(const float* A, const float* W, _Float16* C, const float* dinv, int M) {
    gemm_body<64>(A, W, C, dinv, M);
}

// ---------------- CSR aggregation (2 nodes/wave, f16x2/lane) ----------------
template<bool RESIDUAL, int OUTM>
__device__ __forceinline__ void agg_body(
    const unsigned* __restrict__ y32, const int* __restrict__ row_ptr, const int* __restrict__ col,
    const float* __restrict__ dinv, const float* __restrict__ bias,
    const float* __restrict__ hprev, float* __restrict__ hout,
    unsigned* __restrict__ hb32)
{
    int v  = blockIdx.x * 8 + (threadIdx.x >> 5);
    int sl = threadIdx.x & 31;
    if (v >= N_NODES) return;

    float2 a = up16(y32[(size_t)v * 32 + sl]);     // self loop
    float a0 = a.x, a1 = a.y;
    int s = row_ptr[v], e = row_ptr[v + 1];
    int i = s;
    for (; i + 3 < e; i += 4) {
        int u0 = col[i], u1 = col[i + 1], u2 = col[i + 2], u3 = col[i + 3];
        float2 f0 = up16(y32[(size_t)u0 * 32 + sl]);
        float2 f1 = up16(y32[(size_t)u1 * 32 + sl]);
        float2 f2 = up16(y32[(size_t)u2 * 32 + sl]);
        float2 f3 = up16(y32[(size_t)u3 * 32 + sl]);
        a0 += (f0.x + f1.x) + (f2.x + f3.x);
        a1 += (f0.y + f1.y) + (f2.y + f3.y);
    }
    for (; i < e; ++i) {
        float2 f = up16(y32[(size_t)col[i] * 32 + sl]);
        a0 += f.x; a1 += f.y;
    }
    float dv = dinv[v];
    float2 b = *(const float2*)&bias[sl * 2];
    float v0 = fmaxf(dv * a0 + b.x, 0.f);
    float v1 = fmaxf(dv * a1 + b.y, 0.f);
    size_t o = (size_t)v * 32 + sl;
    if (RESIDUAL) {
        float2 hp = *(const float2*)&hprev[o * 2];
        v0 += hp.x; v1 += hp.y;
    }
    if (OUTM == 2) {
        hb32[o] = (unsigned)f2bf(v0) | ((unsigned)f2bf(v1) << 16);
    } else {
        *(float2*)&hout[o * 2] = make_float2(v0, v1);
    }
}

__global__ __launch_bounds__(256) void agg0_kernel(const unsigned* y, const int* rp, const int* col,
                                                   const float* dinv, const float* b, float* h) {
    agg_body<false, 0>(y, rp, col, dinv, b, nullptr, h, nullptr);
}
__global__ __launch_bounds__(256) void agg1_kernel(const unsigned* y, const int* rp, const int* col,
                                                   const float* dinv, const float* b, float* h) {
    agg_body<true, 1>(y, rp, col, dinv, b, h, h, nullptr);   // in-place: half-wave owns its row
}
__global__ __launch_bounds__(256) void agg2_kernel(const unsigned* y, const int* rp, const int* col,
                                                   const float* dinv, const float* b,
                                                   const float* hprev, unsigned* hb) {
    agg_body<true, 2>(y, rp, col, dinv, b, hprev, nullptr, hb);
}

extern "C" void kernel_launch(void* const* d_in, const int* in_sizes, int n_in,
                              void* d_out, int out_size, void* d_ws, size_t ws_size,
                              hipStream_t stream) {
    const float* x       = (const float*)d_in[0];
    const int*   ei      = (const int*)d_in[1];
    const int*   eli     = (const int*)d_in[2];
    const float* enc_w1  = (const float*)d_in[3];
    const float* enc_b1  = (const float*)d_in[4];
    const float* enc_w2  = (const float*)d_in[5];
    const float* enc_b2  = (const float*)d_in[6];
    const float* conv_w0 = (const float*)d_in[7];
    const float* conv_b0 = (const float*)d_in[8];
    const float* conv_w1 = (const float*)d_in[9];
    const float* conv_b1 = (const float*)d_in[10];
    const float* conv_w2 = (const float*)d_in[11];
    const float* conv_b2 = (const float*)d_in[12];
    const float* ep_w1   = (const float*)d_in[13];
    const float* ep_b1   = (const float*)d_in[14];
    const float* ep_w2   = (const float*)d_in[15];
    const float* ep_b2   = (const float*)d_in[16];
    const float* ep_w3   = (const float*)d_in[17];
    const float* ep_b3   = (const float*)d_in[18];
    float* out = (float*)d_out;

    // ---- workspace layout (float offsets) ----
    float* fws = (float*)d_ws;
    unsigned short* h1b  = (unsigned short*)fws;                 // bf16 [100k,256] = 12.8M f
    unsigned short* e1b  = (unsigned short*)(fws + 12800000);    // bf16 [200k,128] = 12.8M f
    unsigned short* h128b= e1b;                                  // alias: bf16 [100k,128] (dead before ep1)
    _Float16* yb         = (_Float16*)(fws + 25600000);          // f16 [100k,64] = 3.2M f
    float* h64           = fws + 28800000;                       // f32 [100k,64] = 6.4M f
    unsigned short* h64b = (unsigned short*)(fws + 35200000);    // bf16 [100k,64] = 3.2M f
    int*   col     = (int*)(fws + 38400000);                     // 1.6M i
    int*   row_ptr = col + 1600000;                              // 100001 (padded)
    int*   cnt     = row_ptr + 100032;
    float* dinvp   = (float*)(cnt + 100000);
    int*   partial = (int*)(dinvp + 100000);                     // 256
    unsigned short* w2p = (unsigned short*)(partial + 256);      // enc_w2: 32768 us
    unsigned short* w0p = w2p + 32768;                           // conv_w0: 8192 us
    unsigned short* w1p = w0p + 8192;                            // ep_w1: 16384 us
    unsigned short* wp2 = w1p + 16384;                           // ep_w2: 8192 us
    int*   btail   = (int*)(wp2 + 8192);                         // 98 i (+pad to 128)
    int*   bscr    = btail + 128;                                // 98*24576 = 2.41M i

    // ---- CSR build + weight swizzle ----
    hipMemsetAsync(cnt, 0, N_NODES * sizeof(int), stream);
    hipMemsetAsync(btail, 0, 128 * sizeof(int), stream);
    deg_kernel <<<(N_EDGES + 255) / 256, 256, 0, stream>>>(ei, cnt);
    fill_part<<<PART_NB, 256, 0, stream>>>(ei, btail, bscr);
    wprep_kernel<256, 128><<<128, 256, 0, stream>>>(enc_w2,  w2p);
    wprep_kernel<128,  64><<< 32, 256, 0, stream>>>(conv_w0, w0p);
    wprep_kernel<128, 128><<< 64, 256, 0, stream>>>(ep_w1,   w1p);
    wprep_kernel<128,  64><<< 32, 256, 0, stream>>>(ep_w2,   wp2);
    dinv_kernel<<<(N_NODES + 255) / 256, 256, 0, stream>>>(cnt, dinvp);
    scan1<<<SCAN_NB, 256, 0, stream>>>(cnt, partial);
    scan2<<<1, 256, 0, stream>>>(partial, row_ptr);
    scan3<<<SCAN_NB, 256, 0, stream>>>(cnt, partial, row_ptr);
    fill_place<<<KBUCK, 1024, 0, stream>>>(btail, bscr, row_ptr, col);

    const int GBN = (N_NODES + 63) / 64;   // 1563
    const int GBE = N_EL / 64;             // 3125
    const int GBA = (N_NODES + 7) / 8;     // 12500

    // ---- encoder ----
    enc1_kernel<<<GBN, 256, 0, stream>>>(x, enc_w1, enc_b1, h1b);
    mfma_enc2<<<GBN, 256, 0, stream>>>(h1b, w2p, enc_b2, h128b, N_NODES);

    // ---- GCN layer 0: 128 -> 64 (MFMA, bf16 in, f16 y out) ----
    mfma_conv0<<<GBN, 256, 0, stream>>>(h128b, w0p, dinvp, yb, N_NODES);
    agg0_kernel<<<GBA, 256, 0, stream>>>((const unsigned*)yb, row_ptr, col, dinvp, conv_b0, h64);

    // ---- GCN layer 1: 64 -> 64, residual ----
    gemm_conv1<<<GBN, 256, 0, stream>>>(h64, conv_w1, yb, dinvp, N_NODES);
    agg1_kernel<<<GBA, 256, 0, stream>>>((const unsigned*)yb, row_ptr, col, dinvp, conv_b1, h64);

    // ---- GCN layer 2: 64 -> 64, residual, bf16 out for ep1 ----
    gemm_conv2<<<GBN, 256, 0, stream>>>(h64, conv_w2, yb, dinvp, N_NODES);
    agg2_kernel<<<GBA, 256, 0, stream>>>((const unsigned*)yb, row_ptr, col, dinvp, conv_b2, h64, (unsigned*)h64b);

    // ---- edge predictor (bf16 MFMA; ep2+ep3 fused) ----
    mfma_ep1<<<GBE, 256, 0, stream>>>(h64b, w1p, ep_b1, e1b, eli, N_EL);
    mfma_ep2f<<<GBE, 256, 0, stream>>>(e1b, wp2, ep_b2, ep_w3, ep_b3, out, N_EL);
}

// Round 10
// 438.622 us; speedup vs baseline: 1.4316x; 1.1465x over previous
//
#include <hip/hip_runtime.h>
#include <math.h>

// ---------------------------------------------------------------------------
// EmergencyGNNEnhanced: encoder (32->256->128) -> 3x GCN (->64) -> edge MLP.
// CSR built on-device each call. agg[v] = dinv[v]*(sum_{u->v} y[u] + y[v]).
//
// R10: degree count moved onto the bucket partition. R9 proved scattered 4B
// global stores/atomics cost ~32B HBM writeback each (deg: WRITE 50MB for a
// 400KB cnt array). deg_bucket: per-bucket LDS histogram over fill_part's
// contiguous entries + coalesced cnt/dinv writes. Zero global atomics in the
// whole CSR build now. MFMA layouts HW-verified (R5-R9 passed).
// ---------------------------------------------------------------------------

#define N_NODES 100000
#define N_EDGES 1600000
#define N_EL    200000
#define SCAN_NB 196          // ceil(100000/512)

#define KBUCK   98           // ceil(100000/1024) windows of 1024 nodes
#define WSHIFT  10
#define WMASK   1023
#define BCAP    128          // LDS entries/bucket in pass A (chunk avg 64, 8 sigma)
#define BSTRIDE 24576        // scratch ints per bucket (seglen ~16.4k avg)
#define PART_NB 256
#define CHUNK   6250         // ceil(N_EDGES / PART_NB)
#define LCAP    20480        // pass-B LDS staging (seglen max ~17k)

typedef __attribute__((ext_vector_type(8))) short short8_t;
typedef __attribute__((ext_vector_type(4))) float f32x4;

__device__ __forceinline__ unsigned short f2bf(float f) {
    unsigned u = __float_as_uint(f);
    unsigned r = u + 0x7FFFu + ((u >> 16) & 1u);   // RNE
    return (unsigned short)(r >> 16);
}

__device__ __forceinline__ float2 up16(unsigned u) {
    union { unsigned v; _Float16 h[2]; } c; c.v = u;
    return make_float2((float)c.h[0], (float)c.h[1]);
}

// ---- fill pass A: partition edges into 98 dst-window buckets ----
// Entry pack: (d & 1023) << 17 | src (src < 2^17). Whole 6250-edge chunk
// accumulates in LDS, then ONE cooperative flush with contiguous runs.
__global__ __launch_bounds__(256) void fill_part(const int* __restrict__ ei,
                                                 int* __restrict__ btail, int* __restrict__ bscr) {
    __shared__ int lbuf[KBUCK][BCAP];     // 50 KB
    __shared__ int lcnt[KBUCK];
    __shared__ int offs[KBUCK + 1];
    __shared__ int gbase[KBUCK];
    int t = threadIdx.x;
    for (int i = t; i < KBUCK; i += 256) lcnt[i] = 0;
    __syncthreads();

    int e0   = blockIdx.x * CHUNK;
    int eend = e0 + CHUNK; if (eend > N_EDGES) eend = N_EDGES;
    for (int e = e0 + t; e < eend; e += 256) {
        int s = __builtin_nontemporal_load(ei + e);
        int d = __builtin_nontemporal_load(ei + N_EDGES + e);
        int b = d >> WSHIFT;
        int entry = ((d & WMASK) << 17) | s;
        int pos = atomicAdd(&lcnt[b], 1);
        if (pos < BCAP) lbuf[b][pos] = entry;
        else {                                  // statistical-skew spill (rare)
            int p = atomicAdd(&btail[b], 1);
            bscr[b * BSTRIDE + p] = entry;
        }
    }
    __syncthreads();

    if (t < KBUCK) {
        int c = lcnt[t]; if (c > BCAP) c = BCAP;
        lcnt[t] = c;
        gbase[t] = atomicAdd(&btail[t], c);
    }
    __syncthreads();
    if (t == 0) {
        offs[0] = 0;
        for (int b = 0; b < KBUCK; ++b) offs[b + 1] = offs[b] + lcnt[b];
    }
    __syncthreads();

    int T = offs[KBUCK];
    for (int i = t; i < T; i += 256) {
        int loB = 0, hiB = KBUCK;               // binary search bucket
        while (hiB - loB > 1) { int mid = (loB + hiB) >> 1; if (offs[mid] <= i) loB = mid; else hiB = mid; }
        int j = i - offs[loB];
        bscr[loB * BSTRIDE + gbase[loB] + j] = lbuf[loB][j];
    }
}

// ---- degree + dinv from buckets: LDS histogram, coalesced writes ----
__global__ __launch_bounds__(1024) void deg_bucket(const int* __restrict__ btail, const int* __restrict__ bscr,
                                                   int* __restrict__ cnt, float* __restrict__ dinv) {
    __shared__ int lcnt[1024];
    int b = blockIdx.x, t = threadIdx.x;
    lcnt[t] = 0;
    __syncthreads();
    int n = btail[b];
    const int* src = bscr + b * BSTRIDE;
    for (int i = t; i < n; i += 1024)
        atomicAdd(&lcnt[src[i] >> 17], 1);
    __syncthreads();
    int v = (b << WSHIFT) + t;
    if (v < N_NODES) {
        int c = lcnt[t];
        cnt[v] = c;
        dinv[v] = rsqrtf((float)(c + 1));      // +1 self loop
    }
}

// ---------------- scans ----------------
__global__ __launch_bounds__(256) void scan1(const int* __restrict__ cnt, int* __restrict__ partial) {
    __shared__ int sm[256];
    int b = blockIdx.x, t = threadIdx.x;
    int base = b * 512;
    int v = 0;
    if (base + t < N_NODES)       v += cnt[base + t];
    if (base + 256 + t < N_NODES) v += cnt[base + 256 + t];
    sm[t] = v; __syncthreads();
    for (int s = 128; s > 0; s >>= 1) { if (t < s) sm[t] += sm[t + s]; __syncthreads(); }
    if (t == 0) partial[b] = sm[0];
}

__global__ __launch_bounds__(256) void scan2(int* __restrict__ partial, int* __restrict__ row_ptr) {
    __shared__ int sm[256];
    int t = threadIdx.x;
    int v = (t < SCAN_NB) ? partial[t] : 0;
    sm[t] = v; __syncthreads();
    for (int s = 1; s < 256; s <<= 1) {
        int add = (t >= s) ? sm[t - s] : 0;
        __syncthreads();
        sm[t] += add;
        __syncthreads();
    }
    if (t < SCAN_NB) partial[t] = sm[t] - v;          // exclusive
    if (t == 0) row_ptr[N_NODES] = N_EDGES;
}

__global__ __launch_bounds__(256) void scan3(const int* __restrict__ cnt, const int* __restrict__ partial,
                                             int* __restrict__ row_ptr) {
    __shared__ int sm[256];
    int b = blockIdx.x, t = threadIdx.x;
    int base = b * 512;
    int i0 = base + 2 * t, i1 = i0 + 1;
    int e0 = (i0 < N_NODES) ? cnt[i0] : 0;
    int e1 = (i1 < N_NODES) ? cnt[i1] : 0;
    int s2 = e0 + e1;
    sm[t] = s2; __syncthreads();
    for (int s = 1; s < 256; s <<= 1) {
        int add = (t >= s) ? sm[t - s] : 0;
        __syncthreads();
        sm[t] += add;
        __syncthreads();
    }
    int excl = sm[t] - s2 + partial[b];
    if (i0 < N_NODES) row_ptr[i0] = excl;
    if (i1 < N_NODES) row_ptr[i1] = excl + e0;
}

// ---- fill pass B: LDS scatter, coalesced col segment write ----
__global__ __launch_bounds__(1024) void fill_place(const int* __restrict__ btail, const int* __restrict__ bscr,
                                                   const int* __restrict__ row_ptr, int* __restrict__ col) {
    __shared__ int lcur[1024];
    __shared__ int lbuf[LCAP];                  // 80 KB
    int b = blockIdx.x, t = threadIdx.x;
    int lo = b << WSHIFT;
    int hi = lo + 1024; if (hi > N_NODES) hi = N_NODES;
    int segstart = row_ptr[lo];
    int seglen   = row_ptr[hi] - segstart;
    int n = btail[b];
    const int* src = bscr + b * BSTRIDE;
    if (t < hi - lo) lcur[t] = row_ptr[lo + t] - segstart;
    __syncthreads();

    if (seglen <= LCAP) {
        for (int i = t; i < n; i += 1024) {
            int e = src[i];
            int pos = atomicAdd(&lcur[e >> 17], 1);
            lbuf[pos] = e & 0x1FFFF;
        }
        __syncthreads();
        for (int i = t; i < seglen; i += 1024)
            col[segstart + i] = lbuf[i];
    } else {                                    // safety fallback (never for this dist)
        for (int i = t; i < n; i += 1024) {
            int e = src[i];
            int pos = atomicAdd(&lcur[e >> 17], 1);
            col[segstart + pos] = e & 0x1FFFF;
        }
    }
}

// ---------------- enc1: weight-stationary 32->256, bf16 output ----------------
__global__ __launch_bounds__(256, 2) void enc1_kernel(
    const float* __restrict__ x, const float* __restrict__ W,
    const float* __restrict__ bias, unsigned short* __restrict__ C)
{
    __shared__ float Ws[32][256];
    __shared__ float xt[32][68];
    __shared__ float bs[256];

    int t  = threadIdx.x;
    int r0 = blockIdx.x * 64;

    #pragma unroll
    for (int j = 0; j < 8; ++j) {
        int idx = t + j * 256;
        int kk = idx >> 6, cf = idx & 63;
        *(float4*)&Ws[kk][cf * 4] = *(const float4*)&W[kk * 256 + cf * 4];
    }
    if (t < 64) *(float4*)&bs[t * 4] = *(const float4*)&bias[t * 4];

    #pragma unroll
    for (int j = 0; j < 2; ++j) {
        int fidx = t + j * 256;
        int row = fidx >> 3, kf = fidx & 7;
        int gr = r0 + row;
        float4 v = (gr < N_NODES) ? *(const float4*)&x[(size_t)gr * 32 + kf * 4]
                                  : make_float4(0.f, 0.f, 0.f, 0.f);
        xt[kf * 4 + 0][row] = v.x; xt[kf * 4 + 1][row] = v.y;
        xt[kf * 4 + 2][row] = v.z; xt[kf * 4 + 3][row] = v.w;
    }
    __syncthreads();

    int tx = t & 63, ty = t >> 6;
    float4 b4 = *(const float4*)&bs[tx * 4];
    float4 acc[16];
    #pragma unroll
    for (int r = 0; r < 16; ++r) acc[r] = b4;

    #pragma unroll 4
    for (int k = 0; k < 32; ++k) {
        float4 w4 = *(const float4*)&Ws[k][tx * 4];
        #pragma unroll
        for (int j = 0; j < 4; ++j) {
            float4 a4 = *(const float4*)&xt[k][ty * 16 + j * 4];
            acc[j * 4 + 0].x += a4.x * w4.x; acc[j * 4 + 0].y += a4.x * w4.y;
            acc[j * 4 + 0].z += a4.x * w4.z; acc[j * 4 + 0].w += a4.x * w4.w;
            acc[j * 4 + 1].x += a4.y * w4.x; acc[j * 4 + 1].y += a4.y * w4.y;
            acc[j * 4 + 1].z += a4.y * w4.z; acc[j * 4 + 1].w += a4.y * w4.w;
            acc[j * 4 + 2].x += a4.z * w4.x; acc[j * 4 + 2].y += a4.z * w4.y;
            acc[j * 4 + 2].z += a4.z * w4.z; acc[j * 4 + 2].w += a4.z * w4.w;
            acc[j * 4 + 3].x += a4.w * w4.x; acc[j * 4 + 3].y += a4.w * w4.y;
            acc[j * 4 + 3].z += a4.w * w4.z; acc[j * 4 + 3].w += a4.w * w4.w;
        }
    }

    #pragma unroll
    for (int r = 0; r < 16; ++r) {
        int gr = r0 + ty * 16 + r;
        if (gr < N_NODES) {
            float4 v = acc[r];
            unsigned p0 = (unsigned)f2bf(fmaxf(v.x, 0.f)) | ((unsigned)f2bf(fmaxf(v.y, 0.f)) << 16);
            unsigned p1 = (unsigned)f2bf(fmaxf(v.z, 0.f)) | ((unsigned)f2bf(fmaxf(v.w, 0.f)) << 16);
            *(uint2*)&C[(size_t)gr * 256 + tx * 4] = make_uint2(p0, p1);
        }
    }
}

// ---------------- weight swizzle: fp32 W[K][N] -> bf16 B-fragment order -----
template<int KTOT, int NTOT>
__global__ __launch_bounds__(256) void wprep_kernel(const float* __restrict__ W, unsigned short* __restrict__ Wp) {
    int flat = blockIdx.x * 256 + threadIdx.x;
    if (flat >= KTOT * NTOT) return;
    int j = flat & 7, lane = (flat >> 3) & 63, kstep = (flat >> 9) & 1;
    int rest = flat >> 10;
    int ntile = rest % (NTOT / 16), chunk = rest / (NTOT / 16);
    int k = chunk * 64 + kstep * 32 + (lane >> 4) * 8 + j;
    int n = ntile * 16 + (lane & 15);
    Wp[flat] = f2bf(W[(size_t)k * NTOT + n]);
}

// ---------------- bf16 MFMA GEMM ----------------
template<int NTOT, int KTOT, bool GATHER, bool BIAS_RELU, int OUTT>
__device__ __forceinline__ void mfma_gemm_body(
    const unsigned short* __restrict__ A, const unsigned short* __restrict__ Wp,
    const float* __restrict__ bias, const float* __restrict__ dinv,
    void* __restrict__ Cout, const int* __restrict__ gidx, int M)
{
    constexpr int NT16 = NTOT / 16;
    constexpr int NCH  = KTOT / 64;
    __shared__ unsigned short As[64][72];
    __shared__ unsigned short Wls[NT16 * 1024];

    int t = threadIdx.x, wave = t >> 6, lane = t & 63;
    int m0 = blockIdx.x * 64;

    f32x4 acc[NT16];
    #pragma unroll
    for (int nt = 0; nt < NT16; ++nt) acc[nt] = (f32x4){0.f, 0.f, 0.f, 0.f};

    for (int ch = 0; ch < NCH; ++ch) {
        #pragma unroll
        for (int j = 0; j < 2; ++j) {
            int idx = t + j * 256;
            int row = idx >> 3, seg = idx & 7;
            int gr = m0 + row;
            uint4 v = make_uint4(0u, 0u, 0u, 0u);
            if (gr < M) {
                const unsigned short* src;
                if (GATHER) {
                    int node = (ch == 0) ? gidx[gr] : gidx[N_EL + gr];
                    src = A + (size_t)node * 64 + seg * 8;
                } else {
                    src = A + (size_t)gr * KTOT + ch * 64 + seg * 8;
                }
                v = *(const uint4*)src;
            }
            *(uint4*)&As[row][seg * 8] = v;
        }
        constexpr int WL16 = NT16 * 128;            // uint4 count
        #pragma unroll
        for (int j = 0; j < WL16 / 256; ++j) {
            int idx = t + j * 256;
            ((uint4*)Wls)[idx] = ((const uint4*)(Wp + (size_t)ch * NT16 * 1024))[idx];
        }
        __syncthreads();

        #pragma unroll
        for (int ks = 0; ks < 2; ++ks) {
            short8_t af = *(const short8_t*)&As[wave * 16 + (lane & 15)][ks * 32 + (lane >> 4) * 8];
            #pragma unroll
            for (int nt = 0; nt < NT16; ++nt) {
                short8_t bf = *(const short8_t*)&Wls[((nt * 2 + ks) * 64 + lane) * 8];
                acc[nt] = __builtin_amdgcn_mfma_f32_16x16x32_bf16(af, bf, acc[nt], 0, 0, 0);
            }
        }
        __syncthreads();
    }

    int cb = lane & 15, rq = lane >> 4;
    #pragma unroll
    for (int nt = 0; nt < NT16; ++nt) {
        int col = nt * 16 + cb;
        float bv = BIAS_RELU ? bias[col] : 0.f;
        #pragma unroll
        for (int r = 0; r < 4; ++r) {
            int gr = m0 + wave * 16 + rq * 4 + r;
            if (gr < M) {
                float val;
                if (BIAS_RELU) val = fmaxf(acc[nt][r] + bv, 0.f);
                else           val = acc[nt][r] * dinv[gr];
                size_t o = (size_t)gr * NTOT + col;
                if (OUTT == 1)      ((unsigned short*)Cout)[o] = f2bf(val);
                else if (OUTT == 2) ((_Float16*)Cout)[o] = (_Float16)val;
                else                ((float*)Cout)[o] = val;
            }
        }
    }
}

__global__ __launch_bounds__(256, 4) void mfma_enc2(const unsigned short* A, const unsigned short* Wp,
                                                    const float* b, unsigned short* C, int M) {
    mfma_gemm_body<128, 256, false, true, 1>(A, Wp, b, nullptr, C, nullptr, M);
}
__global__ __launch_bounds__(256, 4) void mfma_conv0(const unsigned short* A, const unsigned short* Wp,
                                                     const float* dinv, _Float16* C, int M) {
    mfma_gemm_body<64, 128, false, false, 2>(A, Wp, nullptr, dinv, C, nullptr, M);
}
__global__ __launch_bounds__(256, 4) void mfma_ep1(const unsigned short* A, const unsigned short* Wp,
                                                   const float* b, unsigned short* C, const int* gidx, int M) {
    mfma_gemm_body<128, 128, true, true, 1>(A, Wp, b, nullptr, C, gidx, M);
}

// ---------------- ep2 fused with ep3: sigmoid(relu(e1@W2+b2) . w3 + b3) -----
__global__ __launch_bounds__(256, 4) void mfma_ep2f(
    const unsigned short* __restrict__ A, const unsigned short* __restrict__ Wp,
    const float* __restrict__ b2, const float* __restrict__ w3,
    const float* __restrict__ b3, float* __restrict__ out, int M)
{
    constexpr int NT16 = 4;
    __shared__ unsigned short As[64][72];
    __shared__ unsigned short Wls[NT16 * 1024];

    int t = threadIdx.x, wave = t >> 6, lane = t & 63;
    int m0 = blockIdx.x * 64;

    f32x4 acc[NT16];
    #pragma unroll
    for (int nt = 0; nt < NT16; ++nt) acc[nt] = (f32x4){0.f, 0.f, 0.f, 0.f};

    for (int ch = 0; ch < 2; ++ch) {
        #pragma unroll
        for (int j = 0; j < 2; ++j) {
            int idx = t + j * 256;
            int row = idx >> 3, seg = idx & 7;
            int gr = m0 + row;
            uint4 v = make_uint4(0u, 0u, 0u, 0u);
            if (gr < M) v = *(const uint4*)(A + (size_t)gr * 128 + ch * 64 + seg * 8);
            *(uint4*)&As[row][seg * 8] = v;
        }
        #pragma unroll
        for (int j = 0; j < 2; ++j) {
            int idx = t + j * 256;
            ((uint4*)Wls)[idx] = ((const uint4*)(Wp + (size_t)ch * NT16 * 1024))[idx];
        }
        __syncthreads();

        #pragma unroll
        for (int ks = 0; ks < 2; ++ks) {
            short8_t af = *(const short8_t*)&As[wave * 16 + (lane & 15)][ks * 32 + (lane >> 4) * 8];
            #pragma unroll
            for (int nt = 0; nt < NT16; ++nt) {
                short8_t bf = *(const short8_t*)&Wls[((nt * 2 + ks) * 64 + lane) * 8];
                acc[nt] = __builtin_amdgcn_mfma_f32_16x16x32_bf16(af, bf, acc[nt], 0, 0, 0);
            }
        }
        __syncthreads();
    }

    int cb = lane & 15, rq = lane >> 4;
    float s0 = 0.f, s1 = 0.f, s2 = 0.f, s3 = 0.f;
    #pragma unroll
    for (int nt = 0; nt < NT16; ++nt) {
        int col = nt * 16 + cb;
        float bv = b2[col], wv = w3[col];
        s0 += fmaxf(acc[nt][0] + bv, 0.f) * wv;
        s1 += fmaxf(acc[nt][1] + bv, 0.f) * wv;
        s2 += fmaxf(acc[nt][2] + bv, 0.f) * wv;
        s3 += fmaxf(acc[nt][3] + bv, 0.f) * wv;
    }
    #pragma unroll
    for (int off = 1; off < 16; off <<= 1) {
        s0 += __shfl_xor(s0, off);
        s1 += __shfl_xor(s1, off);
        s2 += __shfl_xor(s2, off);
        s3 += __shfl_xor(s3, off);
    }
    if (cb == 0) {
        int gr = m0 + wave * 16 + rq * 4;
        if (gr + 3 < M) {
            float bb = b3[0];
            float4 o;
            o.x = 1.f / (1.f + expf(-(s0 + bb)));
            o.y = 1.f / (1.f + expf(-(s1 + bb)));
            o.z = 1.f / (1.f + expf(-(s2 + bb)));
            o.w = 1.f / (1.f + expf(-(s3 + bb)));
            *(float4*)&out[gr] = o;
        }
    }
}

// ---------------- fp32 tiled GEMM (conv1/2): y = f16(dinv .* (A@W)) ---------
template<int KTOT>
__device__ __forceinline__ void gemm_body(
    const float* __restrict__ A, const float* __restrict__ W,
    _Float16* __restrict__ C, const float* __restrict__ dinv, int M)
{
    constexpr int KB = 32;
    constexpr int NC = 64;
    __shared__ float As[KB][68];
    __shared__ float Ws[KB][64];

    int t  = threadIdx.x;
    int m0 = blockIdx.x * 64;
    int tx = t & 15, ty = t >> 4;

    float acc[4][4];
    #pragma unroll
    for (int r = 0; r < 4; ++r)
        #pragma unroll
        for (int c = 0; c < 4; ++c) acc[r][c] = 0.f;

    for (int k0 = 0; k0 < KTOT; k0 += KB) {
        #pragma unroll
        for (int j = 0; j < 2; ++j) {
            int idx = t + j * 256;
            int row = idx >> 3, kf = idx & 7;
            int gr  = m0 + row;
            float4 v = make_float4(0.f, 0.f, 0.f, 0.f);
            if (gr < M) v = *(const float4*)&A[(size_t)gr * KTOT + k0 + kf * 4];
            As[kf * 4 + 0][row] = v.x; As[kf * 4 + 1][row] = v.y;
            As[kf * 4 + 2][row] = v.z; As[kf * 4 + 3][row] = v.w;
        }
        #pragma unroll
        for (int j = 0; j < 2; ++j) {
            int idx = t + j * 256;
            int kk = idx >> 4, cf = idx & 15;
            *(float4*)&Ws[kk][cf * 4] = *(const float4*)&W[(size_t)(k0 + kk) * NC + cf * 4];
        }
        __syncthreads();

        #pragma unroll
        for (int kk = 0; kk < KB; ++kk) {
            float4 a4 = *(const float4*)&As[kk][ty * 4];
            float4 w4 = *(const float4*)&Ws[kk][tx * 4];
            acc[0][0] += a4.x * w4.x; acc[0][1] += a4.x * w4.y;
            acc[0][2] += a4.x * w4.z; acc[0][3] += a4.x * w4.w;
            acc[1][0] += a4.y * w4.x; acc[1][1] += a4.y * w4.y;
            acc[1][2] += a4.y * w4.z; acc[1][3] += a4.y * w4.w;
            acc[2][0] += a4.z * w4.x; acc[2][1] += a4.z * w4.y;
            acc[2][2] += a4.z * w4.z; acc[2][3] += a4.z * w4.w;
            acc[3][0] += a4.w * w4.x; acc[3][1] += a4.w * w4.y;
            acc[3][2] += a4.w * w4.z; acc[3][3] += a4.w * w4.w;
        }
        __syncthreads();
    }

    #pragma unroll
    for (int r = 0; r < 4; ++r) {
        int gr = m0 + ty * 4 + r;
        if (gr < M) {
            float s = dinv[gr];
            _Float16 tmp[4];
            tmp[0] = (_Float16)(acc[r][0] * s);
            tmp[1] = (_Float16)(acc[r][1] * s);
            tmp[2] = (_Float16)(acc[r][2] * s);
            tmp[3] = (_Float16)(acc[r][3] * s);
            *(uint2*)&C[(size_t)gr * NC + tx * 4] = *(uint2*)tmp;
        }
    }
}

__global__ __launch_bounds__(256, 4) void gemm_conv1(const float* A, const float* W, _Float16* C, const float* dinv, int M) {
    gemm_body<64>(A, W, C, dinv, M);
}
__global__ __launch_bounds__(256, 4) void gemm_conv2(const float* A, const float* W, _Float16* C, const float* dinv, int M) {
    gemm_body<64>(A, W, C, dinv, M);
}

// ---------------- CSR aggregation (2 nodes/wave, f16x2/lane) ----------------
template<bool RESIDUAL, int OUTM>
__device__ __forceinline__ void agg_body(
    const unsigned* __restrict__ y32, const int* __restrict__ row_ptr, const int* __restrict__ col,
    const float* __restrict__ dinv, const float* __restrict__ bias,
    const float* __restrict__ hprev, float* __restrict__ hout,
    unsigned* __restrict__ hb32)
{
    int v  = blockIdx.x * 8 + (threadIdx.x >> 5);
    int sl = threadIdx.x & 31;
    if (v >= N_NODES) return;

    float2 a = up16(y32[(size_t)v * 32 + sl]);     // self loop
    float a0 = a.x, a1 = a.y;
    int s = row_ptr[v], e = row_ptr[v + 1];
    int i = s;
    for (; i + 3 < e; i += 4) {
        int u0 = col[i], u1 = col[i + 1], u2 = col[i + 2], u3 = col[i + 3];
        float2 f0 = up16(y32[(size_t)u0 * 32 + sl]);
        float2 f1 = up16(y32[(size_t)u1 * 32 + sl]);
        float2 f2 = up16(y32[(size_t)u2 * 32 + sl]);
        float2 f3 = up16(y32[(size_t)u3 * 32 + sl]);
        a0 += (f0.x + f1.x) + (f2.x + f3.x);
        a1 += (f0.y + f1.y) + (f2.y + f3.y);
    }
    for (; i < e; ++i) {
        float2 f = up16(y32[(size_t)col[i] * 32 + sl]);
        a0 += f.x; a1 += f.y;
    }
    float dv = dinv[v];
    float2 b = *(const float2*)&bias[sl * 2];
    float v0 = fmaxf(dv * a0 + b.x, 0.f);
    float v1 = fmaxf(dv * a1 + b.y, 0.f);
    size_t o = (size_t)v * 32 + sl;
    if (RESIDUAL) {
        float2 hp = *(const float2*)&hprev[o * 2];
        v0 += hp.x; v1 += hp.y;
    }
    if (OUTM == 2) {
        hb32[o] = (unsigned)f2bf(v0) | ((unsigned)f2bf(v1) << 16);
    } else {
        *(float2*)&hout[o * 2] = make_float2(v0, v1);
    }
}

__global__ __launch_bounds__(256) void agg0_kernel(const unsigned* y, const int* rp, const int* col,
                                                   const float* dinv, const float* b, float* h) {
    agg_body<false, 0>(y, rp, col, dinv, b, nullptr, h, nullptr);
}
__global__ __launch_bounds__(256) void agg1_kernel(const unsigned* y, const int* rp, const int* col,
                                                   const float* dinv, const float* b, float* h) {
    agg_body<true, 1>(y, rp, col, dinv, b, h, h, nullptr);   // in-place: half-wave owns its row
}
__global__ __launch_bounds__(256) void agg2_kernel(const unsigned* y, const int* rp, const int* col,
                                                   const float* dinv, const float* b,
                                                   const float* hprev, unsigned* hb) {
    agg_body<true, 2>(y, rp, col, dinv, b, hprev, nullptr, hb);
}

extern "C" void kernel_launch(void* const* d_in, const int* in_sizes, int n_in,
                              void* d_out, int out_size, void* d_ws, size_t ws_size,
                              hipStream_t stream) {
    const float* x       = (const float*)d_in[0];
    const int*   ei      = (const int*)d_in[1];
    const int*   eli     = (const int*)d_in[2];
    const float* enc_w1  = (const float*)d_in[3];
    const float* enc_b1  = (const float*)d_in[4];
    const float* enc_w2  = (const float*)d_in[5];
    const float* enc_b2  = (const float*)d_in[6];
    const float* conv_w0 = (const float*)d_in[7];
    const float* conv_b0 = (const float*)d_in[8];
    const float* conv_w1 = (const float*)d_in[9];
    const float* conv_b1 = (const float*)d_in[10];
    const float* conv_w2 = (const float*)d_in[11];
    const float* conv_b2 = (const float*)d_in[12];
    const float* ep_w1   = (const float*)d_in[13];
    const float* ep_b1   = (const float*)d_in[14];
    const float* ep_w2   = (const float*)d_in[15];
    const float* ep_b2   = (const float*)d_in[16];
    const float* ep_w3   = (const float*)d_in[17];
    const float* ep_b3   = (const float*)d_in[18];
    float* out = (float*)d_out;

    // ---- workspace layout (float offsets) ----
    float* fws = (float*)d_ws;
    unsigned short* h1b  = (unsigned short*)fws;                 // bf16 [100k,256] = 12.8M f
    unsigned short* e1b  = (unsigned short*)(fws + 12800000);    // bf16 [200k,128] = 12.8M f
    unsigned short* h128b= e1b;                                  // alias: bf16 [100k,128] (dead before ep1)
    _Float16* yb         = (_Float16*)(fws + 25600000);          // f16 [100k,64] = 3.2M f
    float* h64           = fws + 28800000;                       // f32 [100k,64] = 6.4M f
    unsigned short* h64b = (unsigned short*)(fws + 35200000);    // bf16 [100k,64] = 3.2M f
    int*   col     = (int*)(fws + 38400000);                     // 1.6M i
    int*   row_ptr = col + 1600000;                              // 100001 (padded)
    int*   cnt     = row_ptr + 100032;
    float* dinvp   = (float*)(cnt + 100000);
    int*   partial = (int*)(dinvp + 100000);                     // 256
    unsigned short* w2p = (unsigned short*)(partial + 256);      // enc_w2: 32768 us
    unsigned short* w0p = w2p + 32768;                           // conv_w0: 8192 us
    unsigned short* w1p = w0p + 8192;                            // ep_w1: 16384 us
    unsigned short* wp2 = w1p + 16384;                           // ep_w2: 8192 us
    int*   btail   = (int*)(wp2 + 8192);                         // 98 i (+pad to 128)
    int*   bscr    = btail + 128;                                // 98*24576 = 2.41M i

    // ---- CSR build + weight swizzle (no global atomics anywhere) ----
    hipMemsetAsync(btail, 0, 128 * sizeof(int), stream);
    fill_part<<<PART_NB, 256, 0, stream>>>(ei, btail, bscr);
    deg_bucket<<<KBUCK, 1024, 0, stream>>>(btail, bscr, cnt, dinvp);
    wprep_kernel<256, 128><<<128, 256, 0, stream>>>(enc_w2,  w2p);
    wprep_kernel<128,  64><<< 32, 256, 0, stream>>>(conv_w0, w0p);
    wprep_kernel<128, 128><<< 64, 256, 0, stream>>>(ep_w1,   w1p);
    wprep_kernel<128,  64><<< 32, 256, 0, stream>>>(ep_w2,   wp2);
    scan1<<<SCAN_NB, 256, 0, stream>>>(cnt, partial);
    scan2<<<1, 256, 0, stream>>>(partial, row_ptr);
    scan3<<<SCAN_NB, 256, 0, stream>>>(cnt, partial, row_ptr);
    fill_place<<<KBUCK, 1024, 0, stream>>>(btail, bscr, row_ptr, col);

    const int GBN = (N_NODES + 63) / 64;   // 1563
    const int GBE = N_EL / 64;             // 3125
    const int GBA = (N_NODES + 7) / 8;     // 12500

    // ---- encoder ----
    enc1_kernel<<<GBN, 256, 0, stream>>>(x, enc_w1, enc_b1, h1b);
    mfma_enc2<<<GBN, 256, 0, stream>>>(h1b, w2p, enc_b2, h128b, N_NODES);

    // ---- GCN layer 0: 128 -> 64 (MFMA, bf16 in, f16 y out) ----
    mfma_conv0<<<GBN, 256, 0, stream>>>(h128b, w0p, dinvp, yb, N_NODES);
    agg0_kernel<<<GBA, 256, 0, stream>>>((const unsigned*)yb, row_ptr, col, dinvp, conv_b0, h64);

    // ---- GCN layer 1: 64 -> 64, residual ----
    gemm_conv1<<<GBN, 256, 0, stream>>>(h64, conv_w1, yb, dinvp, N_NODES);
    agg1_kernel<<<GBA, 256, 0, stream>>>((const unsigned*)yb, row_ptr, col, dinvp, conv_b1, h64);

    // ---- GCN layer 2: 64 -> 64, residual, bf16 out for ep1 ----
    gemm_conv2<<<GBN, 256, 0, stream>>>(h64, conv_w2, yb, dinvp, N_NODES);
    agg2_kernel<<<GBA, 256, 0, stream>>>((const unsigned*)yb, row_ptr, col, dinvp, conv_b2, h64, (unsigned*)h64b);

    // ---- edge predictor (bf16 MFMA; ep2+ep3 fused) ----
    mfma_ep1<<<GBE, 256, 0, stream>>>(h64b, w1p, ep_b1, e1b, eli, N_EL);
    mfma_ep2f<<<GBE, 256, 0, stream>>>(e1b, wp2, ep_b2, ep_w3, ep_b3, out, N_EL);
}

// Round 11
// 416.474 us; speedup vs baseline: 1.5077x; 1.0532x over previous
//
#include <hip/hip_runtime.h>
#include <math.h>

// ---------------------------------------------------------------------------
// EmergencyGNNEnhanced: encoder (32->256->128) -> 3x GCN (->64) -> edge MLP.
// CSR built on-device each call. agg[v] = dinv[v]*(sum_{u->v} y[u] + y[v]).
//
// R11: agg restructured 2 nodes/wave -> 4 nodes/wave (16-lane groups,
// uint2 = 4 f16 features per lane). One VMEM instruction now serves 4 edges
// (was 2) and each wave runs 4 independent gather streams (was 2) -- attacks
// the latency-bound profile (R10: 46us, VALUBusy 32%, 2.7TB/s counted).
// The 8x XCD fetch amplification (98MB = 8 x 12.8MB f16 y) is structural
// for a random gather; y dtype already minimal at f16.
// MFMA layouts HW-verified (R5-R10 passed).
// ---------------------------------------------------------------------------

#define N_NODES 100000
#define N_EDGES 1600000
#define N_EL    200000
#define SCAN_NB 196          // ceil(100000/512)

#define KBUCK   98           // ceil(100000/1024) windows of 1024 nodes
#define WSHIFT  10
#define WMASK   1023
#define BCAP    128          // LDS entries/bucket in pass A (chunk avg 64, 8 sigma)
#define BSTRIDE 24576        // scratch ints per bucket (seglen ~16.4k avg)
#define PART_NB 256
#define CHUNK   6250         // ceil(N_EDGES / PART_NB)
#define LCAP    20480        // pass-B LDS staging (seglen max ~17k)

typedef __attribute__((ext_vector_type(8))) short short8_t;
typedef __attribute__((ext_vector_type(4))) float f32x4;

__device__ __forceinline__ unsigned short f2bf(float f) {
    unsigned u = __float_as_uint(f);
    unsigned r = u + 0x7FFFu + ((u >> 16) & 1u);   // RNE
    return (unsigned short)(r >> 16);
}

__device__ __forceinline__ float2 up16(unsigned u) {
    union { unsigned v; _Float16 h[2]; } c; c.v = u;
    return make_float2((float)c.h[0], (float)c.h[1]);
}

// ---- fill pass A: partition edges into 98 dst-window buckets ----
__global__ __launch_bounds__(256) void fill_part(const int* __restrict__ ei,
                                                 int* __restrict__ btail, int* __restrict__ bscr) {
    __shared__ int lbuf[KBUCK][BCAP];     // 50 KB
    __shared__ int lcnt[KBUCK];
    __shared__ int offs[KBUCK + 1];
    __shared__ int gbase[KBUCK];
    int t = threadIdx.x;
    for (int i = t; i < KBUCK; i += 256) lcnt[i] = 0;
    __syncthreads();

    int e0   = blockIdx.x * CHUNK;
    int eend = e0 + CHUNK; if (eend > N_EDGES) eend = N_EDGES;
    for (int e = e0 + t; e < eend; e += 256) {
        int s = __builtin_nontemporal_load(ei + e);
        int d = __builtin_nontemporal_load(ei + N_EDGES + e);
        int b = d >> WSHIFT;
        int entry = ((d & WMASK) << 17) | s;
        int pos = atomicAdd(&lcnt[b], 1);
        if (pos < BCAP) lbuf[b][pos] = entry;
        else {                                  // statistical-skew spill (rare)
            int p = atomicAdd(&btail[b], 1);
            bscr[b * BSTRIDE + p] = entry;
        }
    }
    __syncthreads();

    if (t < KBUCK) {
        int c = lcnt[t]; if (c > BCAP) c = BCAP;
        lcnt[t] = c;
        gbase[t] = atomicAdd(&btail[t], c);
    }
    __syncthreads();
    if (t == 0) {
        offs[0] = 0;
        for (int b = 0; b < KBUCK; ++b) offs[b + 1] = offs[b] + lcnt[b];
    }
    __syncthreads();

    int T = offs[KBUCK];
    for (int i = t; i < T; i += 256) {
        int loB = 0, hiB = KBUCK;               // binary search bucket
        while (hiB - loB > 1) { int mid = (loB + hiB) >> 1; if (offs[mid] <= i) loB = mid; else hiB = mid; }
        int j = i - offs[loB];
        bscr[loB * BSTRIDE + gbase[loB] + j] = lbuf[loB][j];
    }
}

// ---- degree + dinv from buckets: LDS histogram, coalesced writes ----
__global__ __launch_bounds__(1024) void deg_bucket(const int* __restrict__ btail, const int* __restrict__ bscr,
                                                   int* __restrict__ cnt, float* __restrict__ dinv) {
    __shared__ int lcnt[1024];
    int b = blockIdx.x, t = threadIdx.x;
    lcnt[t] = 0;
    __syncthreads();
    int n = btail[b];
    const int* src = bscr + b * BSTRIDE;
    for (int i = t; i < n; i += 1024)
        atomicAdd(&lcnt[src[i] >> 17], 1);
    __syncthreads();
    int v = (b << WSHIFT) + t;
    if (v < N_NODES) {
        int c = lcnt[t];
        cnt[v] = c;
        dinv[v] = rsqrtf((float)(c + 1));      // +1 self loop
    }
}

// ---------------- scans ----------------
__global__ __launch_bounds__(256) void scan1(const int* __restrict__ cnt, int* __restrict__ partial) {
    __shared__ int sm[256];
    int b = blockIdx.x, t = threadIdx.x;
    int base = b * 512;
    int v = 0;
    if (base + t < N_NODES)       v += cnt[base + t];
    if (base + 256 + t < N_NODES) v += cnt[base + 256 + t];
    sm[t] = v; __syncthreads();
    for (int s = 128; s > 0; s >>= 1) { if (t < s) sm[t] += sm[t + s]; __syncthreads(); }
    if (t == 0) partial[b] = sm[0];
}

__global__ __launch_bounds__(256) void scan2(int* __restrict__ partial, int* __restrict__ row_ptr) {
    __shared__ int sm[256];
    int t = threadIdx.x;
    int v = (t < SCAN_NB) ? partial[t] : 0;
    sm[t] = v; __syncthreads();
    for (int s = 1; s < 256; s <<= 1) {
        int add = (t >= s) ? sm[t - s] : 0;
        __syncthreads();
        sm[t] += add;
        __syncthreads();
    }
    if (t < SCAN_NB) partial[t] = sm[t] - v;          // exclusive
    if (t == 0) row_ptr[N_NODES] = N_EDGES;
}

__global__ __launch_bounds__(256) void scan3(const int* __restrict__ cnt, const int* __restrict__ partial,
                                             int* __restrict__ row_ptr) {
    __shared__ int sm[256];
    int b = blockIdx.x, t = threadIdx.x;
    int base = b * 512;
    int i0 = base + 2 * t, i1 = i0 + 1;
    int e0 = (i0 < N_NODES) ? cnt[i0] : 0;
    int e1 = (i1 < N_NODES) ? cnt[i1] : 0;
    int s2 = e0 + e1;
    sm[t] = s2; __syncthreads();
    for (int s = 1; s < 256; s <<= 1) {
        int add = (t >= s) ? sm[t - s] : 0;
        __syncthreads();
        sm[t] += add;
        __syncthreads();
    }
    int excl = sm[t] - s2 + partial[b];
    if (i0 < N_NODES) row_ptr[i0] = excl;
    if (i1 < N_NODES) row_ptr[i1] = excl + e0;
}

// ---- fill pass B: LDS scatter, coalesced col segment write ----
__global__ __launch_bounds__(1024) void fill_place(const int* __restrict__ btail, const int* __restrict__ bscr,
                                                   const int* __restrict__ row_ptr, int* __restrict__ col) {
    __shared__ int lcur[1024];
    __shared__ int lbuf[LCAP];                  // 80 KB
    int b = blockIdx.x, t = threadIdx.x;
    int lo = b << WSHIFT;
    int hi = lo + 1024; if (hi > N_NODES) hi = N_NODES;
    int segstart = row_ptr[lo];
    int seglen   = row_ptr[hi] - segstart;
    int n = btail[b];
    const int* src = bscr + b * BSTRIDE;
    if (t < hi - lo) lcur[t] = row_ptr[lo + t] - segstart;
    __syncthreads();

    if (seglen <= LCAP) {
        for (int i = t; i < n; i += 1024) {
            int e = src[i];
            int pos = atomicAdd(&lcur[e >> 17], 1);
            lbuf[pos] = e & 0x1FFFF;
        }
        __syncthreads();
        for (int i = t; i < seglen; i += 1024)
            col[segstart + i] = lbuf[i];
    } else {                                    // safety fallback (never for this dist)
        for (int i = t; i < n; i += 1024) {
            int e = src[i];
            int pos = atomicAdd(&lcur[e >> 17], 1);
            col[segstart + pos] = e & 0x1FFFF;
        }
    }
}

// ---------------- enc1: weight-stationary 32->256, bf16 output ----------------
__global__ __launch_bounds__(256, 2) void enc1_kernel(
    const float* __restrict__ x, const float* __restrict__ W,
    const float* __restrict__ bias, unsigned short* __restrict__ C)
{
    __shared__ float Ws[32][256];
    __shared__ float xt[32][68];
    __shared__ float bs[256];

    int t  = threadIdx.x;
    int r0 = blockIdx.x * 64;

    #pragma unroll
    for (int j = 0; j < 8; ++j) {
        int idx = t + j * 256;
        int kk = idx >> 6, cf = idx & 63;
        *(float4*)&Ws[kk][cf * 4] = *(const float4*)&W[kk * 256 + cf * 4];
    }
    if (t < 64) *(float4*)&bs[t * 4] = *(const float4*)&bias[t * 4];

    #pragma unroll
    for (int j = 0; j < 2; ++j) {
        int fidx = t + j * 256;
        int row = fidx >> 3, kf = fidx & 7;
        int gr = r0 + row;
        float4 v = (gr < N_NODES) ? *(const float4*)&x[(size_t)gr * 32 + kf * 4]
                                  : make_float4(0.f, 0.f, 0.f, 0.f);
        xt[kf * 4 + 0][row] = v.x; xt[kf * 4 + 1][row] = v.y;
        xt[kf * 4 + 2][row] = v.z; xt[kf * 4 + 3][row] = v.w;
    }
    __syncthreads();

    int tx = t & 63, ty = t >> 6;
    float4 b4 = *(const float4*)&bs[tx * 4];
    float4 acc[16];
    #pragma unroll
    for (int r = 0; r < 16; ++r) acc[r] = b4;

    #pragma unroll 4
    for (int k = 0; k < 32; ++k) {
        float4 w4 = *(const float4*)&Ws[k][tx * 4];
        #pragma unroll
        for (int j = 0; j < 4; ++j) {
            float4 a4 = *(const float4*)&xt[k][ty * 16 + j * 4];
            acc[j * 4 + 0].x += a4.x * w4.x; acc[j * 4 + 0].y += a4.x * w4.y;
            acc[j * 4 + 0].z += a4.x * w4.z; acc[j * 4 + 0].w += a4.x * w4.w;
            acc[j * 4 + 1].x += a4.y * w4.x; acc[j * 4 + 1].y += a4.y * w4.y;
            acc[j * 4 + 1].z += a4.y * w4.z; acc[j * 4 + 1].w += a4.y * w4.w;
            acc[j * 4 + 2].x += a4.z * w4.x; acc[j * 4 + 2].y += a4.z * w4.y;
            acc[j * 4 + 2].z += a4.z * w4.z; acc[j * 4 + 2].w += a4.z * w4.w;
            acc[j * 4 + 3].x += a4.w * w4.x; acc[j * 4 + 3].y += a4.w * w4.y;
            acc[j * 4 + 3].z += a4.w * w4.z; acc[j * 4 + 3].w += a4.w * w4.w;
        }
    }

    #pragma unroll
    for (int r = 0; r < 16; ++r) {
        int gr = r0 + ty * 16 + r;
        if (gr < N_NODES) {
            float4 v = acc[r];
            unsigned p0 = (unsigned)f2bf(fmaxf(v.x, 0.f)) | ((unsigned)f2bf(fmaxf(v.y, 0.f)) << 16);
            unsigned p1 = (unsigned)f2bf(fmaxf(v.z, 0.f)) | ((unsigned)f2bf(fmaxf(v.w, 0.f)) << 16);
            *(uint2*)&C[(size_t)gr * 256 + tx * 4] = make_uint2(p0, p1);
        }
    }
}

// ---------------- weight swizzle: fp32 W[K][N] -> bf16 B-fragment order -----
template<int KTOT, int NTOT>
__global__ __launch_bounds__(256) void wprep_kernel(const float* __restrict__ W, unsigned short* __restrict__ Wp) {
    int flat = blockIdx.x * 256 + threadIdx.x;
    if (flat >= KTOT * NTOT) return;
    int j = flat & 7, lane = (flat >> 3) & 63, kstep = (flat >> 9) & 1;
    int rest = flat >> 10;
    int ntile = rest % (NTOT / 16), chunk = rest / (NTOT / 16);
    int k = chunk * 64 + kstep * 32 + (lane >> 4) * 8 + j;
    int n = ntile * 16 + (lane & 15);
    Wp[flat] = f2bf(W[(size_t)k * NTOT + n]);
}

// ---------------- bf16 MFMA GEMM ----------------
template<int NTOT, int KTOT, bool GATHER, bool BIAS_RELU, int OUTT>
__device__ __forceinline__ void mfma_gemm_body(
    const unsigned short* __restrict__ A, const unsigned short* __restrict__ Wp,
    const float* __restrict__ bias, const float* __restrict__ dinv,
    void* __restrict__ Cout, const int* __restrict__ gidx, int M)
{
    constexpr int NT16 = NTOT / 16;
    constexpr int NCH  = KTOT / 64;
    __shared__ unsigned short As[64][72];
    __shared__ unsigned short Wls[NT16 * 1024];

    int t = threadIdx.x, wave = t >> 6, lane = t & 63;
    int m0 = blockIdx.x * 64;

    f32x4 acc[NT16];
    #pragma unroll
    for (int nt = 0; nt < NT16; ++nt) acc[nt] = (f32x4){0.f, 0.f, 0.f, 0.f};

    for (int ch = 0; ch < NCH; ++ch) {
        #pragma unroll
        for (int j = 0; j < 2; ++j) {
            int idx = t + j * 256;
            int row = idx >> 3, seg = idx & 7;
            int gr = m0 + row;
            uint4 v = make_uint4(0u, 0u, 0u, 0u);
            if (gr < M) {
                const unsigned short* src;
                if (GATHER) {
                    int node = (ch == 0) ? gidx[gr] : gidx[N_EL + gr];
                    src = A + (size_t)node * 64 + seg * 8;
                } else {
                    src = A + (size_t)gr * KTOT + ch * 64 + seg * 8;
                }
                v = *(const uint4*)src;
            }
            *(uint4*)&As[row][seg * 8] = v;
        }
        constexpr int WL16 = NT16 * 128;            // uint4 count
        #pragma unroll
        for (int j = 0; j < WL16 / 256; ++j) {
            int idx = t + j * 256;
            ((uint4*)Wls)[idx] = ((const uint4*)(Wp + (size_t)ch * NT16 * 1024))[idx];
        }
        __syncthreads();

        #pragma unroll
        for (int ks = 0; ks < 2; ++ks) {
            short8_t af = *(const short8_t*)&As[wave * 16 + (lane & 15)][ks * 32 + (lane >> 4) * 8];
            #pragma unroll
            for (int nt = 0; nt < NT16; ++nt) {
                short8_t bf = *(const short8_t*)&Wls[((nt * 2 + ks) * 64 + lane) * 8];
                acc[nt] = __builtin_amdgcn_mfma_f32_16x16x32_bf16(af, bf, acc[nt], 0, 0, 0);
            }
        }
        __syncthreads();
    }

    int cb = lane & 15, rq = lane >> 4;
    #pragma unroll
    for (int nt = 0; nt < NT16; ++nt) {
        int col = nt * 16 + cb;
        float bv = BIAS_RELU ? bias[col] : 0.f;
        #pragma unroll
        for (int r = 0; r < 4; ++r) {
            int gr = m0 + wave * 16 + rq * 4 + r;
            if (gr < M) {
                float val;
                if (BIAS_RELU) val = fmaxf(acc[nt][r] + bv, 0.f);
                else           val = acc[nt][r] * dinv[gr];
                size_t o = (size_t)gr * NTOT + col;
                if (OUTT == 1)      ((unsigned short*)Cout)[o] = f2bf(val);
                else if (OUTT == 2) ((_Float16*)Cout)[o] = (_Float16)val;
                else                ((float*)Cout)[o] = val;
            }
        }
    }
}

__global__ __launch_bounds__(256, 4) void mfma_enc2(const unsigned short* A, const unsigned short* Wp,
                                                    const float* b, unsigned short* C, int M) {
    mfma_gemm_body<128, 256, false, true, 1>(A, Wp, b, nullptr, C, nullptr, M);
}
__global__ __launch_bounds__(256, 4) void mfma_conv0(const unsigned short* A, const unsigned short* Wp,
                                                     const float* dinv, _Float16* C, int M) {
    mfma_gemm_body<64, 128, false, false, 2>(A, Wp, nullptr, dinv, C, nullptr, M);
}
__global__ __launch_bounds__(256, 4) void mfma_ep1(const unsigned short* A, const unsigned short* Wp,
                                                   const float* b, unsigned short* C, const int* gidx, int M) {
    mfma_gemm_body<128, 128, true, true, 1>(A, Wp, b, nullptr, C, gidx, M);
}

// ---------------- ep2 fused with ep3: sigmoid(relu(e1@W2+b2) . w3 + b3) -----
__global__ __launch_bounds__(256, 4) void mfma_ep2f(
    const unsigned short* __restrict__ A, const unsigned short* __restrict__ Wp,
    const float* __restrict__ b2, const float* __restrict__ w3,
    const float* __restrict__ b3, float* __restrict__ out, int M)
{
    constexpr int NT16 = 4;
    __shared__ unsigned short As[64][72];
    __shared__ unsigned short Wls[NT16 * 1024];

    int t = threadIdx.x, wave = t >> 6, lane = t & 63;
    int m0 = blockIdx.x * 64;

    f32x4 acc[NT16];
    #pragma unroll
    for (int nt = 0; nt < NT16; ++nt) acc[nt] = (f32x4){0.f, 0.f, 0.f, 0.f};

    for (int ch = 0; ch < 2; ++ch) {
        #pragma unroll
        for (int j = 0; j < 2; ++j) {
            int idx = t + j * 256;
            int row = idx >> 3, seg = idx & 7;
            int gr = m0 + row;
            uint4 v = make_uint4(0u, 0u, 0u, 0u);
            if (gr < M) v = *(const uint4*)(A + (size_t)gr * 128 + ch * 64 + seg * 8);
            *(uint4*)&As[row][seg * 8] = v;
        }
        #pragma unroll
        for (int j = 0; j < 2; ++j) {
            int idx = t + j * 256;
            ((uint4*)Wls)[idx] = ((const uint4*)(Wp + (size_t)ch * NT16 * 1024))[idx];
        }
        __syncthreads();

        #pragma unroll
        for (int ks = 0; ks < 2; ++ks) {
            short8_t af = *(const short8_t*)&As[wave * 16 + (lane & 15)][ks * 32 + (lane >> 4) * 8];
            #pragma unroll
            for (int nt = 0; nt < NT16; ++nt) {
                short8_t bf = *(const short8_t*)&Wls[((nt * 2 + ks) * 64 + lane) * 8];
                acc[nt] = __builtin_amdgcn_mfma_f32_16x16x32_bf16(af, bf, acc[nt], 0, 0, 0);
            }
        }
        __syncthreads();
    }

    int cb = lane & 15, rq = lane >> 4;
    float s0 = 0.f, s1 = 0.f, s2 = 0.f, s3 = 0.f;
    #pragma unroll
    for (int nt = 0; nt < NT16; ++nt) {
        int col = nt * 16 + cb;
        float bv = b2[col], wv = w3[col];
        s0 += fmaxf(acc[nt][0] + bv, 0.f) * wv;
        s1 += fmaxf(acc[nt][1] + bv, 0.f) * wv;
        s2 += fmaxf(acc[nt][2] + bv, 0.f) * wv;
        s3 += fmaxf(acc[nt][3] + bv, 0.f) * wv;
    }
    #pragma unroll
    for (int off = 1; off < 16; off <<= 1) {
        s0 += __shfl_xor(s0, off);
        s1 += __shfl_xor(s1, off);
        s2 += __shfl_xor(s2, off);
        s3 += __shfl_xor(s3, off);
    }
    if (cb == 0) {
        int gr = m0 + wave * 16 + rq * 4;
        if (gr + 3 < M) {
            float bb = b3[0];
            float4 o;
            o.x = 1.f / (1.f + expf(-(s0 + bb)));
            o.y = 1.f / (1.f + expf(-(s1 + bb)));
            o.z = 1.f / (1.f + expf(-(s2 + bb)));
            o.w = 1.f / (1.f + expf(-(s3 + bb)));
            *(float4*)&out[gr] = o;
        }
    }
}

// ---------------- fp32 tiled GEMM (conv1/2): y = f16(dinv .* (A@W)) ---------
template<int KTOT>
__device__ __forceinline__ void gemm_body(
    const float* __restrict__ A, const float* __restrict__ W,
    _Float16* __restrict__ C, const float* __restrict__ dinv, int M)
{
    constexpr int KB = 32;
    constexpr int NC = 64;
    __shared__ float As[KB][68];
    __shared__ float Ws[KB][64];

    int t  = threadIdx.x;
    int m0 = blockIdx.x * 64;
    int tx = t & 15, ty = t >> 4;

    float acc[4][4];
    #pragma unroll
    for (int r = 0; r < 4; ++r)
        #pragma unroll
        for (int c = 0; c < 4; ++c) acc[r][c] = 0.f;

    for (int k0 = 0; k0 < KTOT; k0 += KB) {
        #pragma unroll
        for (int j = 0; j < 2; ++j) {
            int idx = t + j * 256;
            int row = idx >> 3, kf = idx & 7;
            int gr  = m0 + row;
            float4 v = make_float4(0.f, 0.f, 0.f, 0.f);
            if (gr < M) v = *(const float4*)&A[(size_t)gr * KTOT + k0 + kf * 4];
            As[kf * 4 + 0][row] = v.x; As[kf * 4 + 1][row] = v.y;
            As[kf * 4 + 2][row] = v.z; As[kf * 4 + 3][row] = v.w;
        }
        #pragma unroll
        for (int j = 0; j < 2; ++j) {
            int idx = t + j * 256;
            int kk = idx >> 4, cf = idx & 15;
            *(float4*)&Ws[kk][cf * 4] = *(const float4*)&W[(size_t)(k0 + kk) * NC + cf * 4];
        }
        __syncthreads();

        #pragma unroll
        for (int kk = 0; kk < KB; ++kk) {
            float4 a4 = *(const float4*)&As[kk][ty * 4];
            float4 w4 = *(const float4*)&Ws[kk][tx * 4];
            acc[0][0] += a4.x * w4.x; acc[0][1] += a4.x * w4.y;
            acc[0][2] += a4.x * w4.z; acc[0][3] += a4.x * w4.w;
            acc[1][0] += a4.y * w4.x; acc[1][1] += a4.y * w4.y;
            acc[1][2] += a4.y * w4.z; acc[1][3] += a4.y * w4.w;
            acc[2][0] += a4.z * w4.x; acc[2][1] += a4.z * w4.y;
            acc[2][2] += a4.z * w4.z; acc[2][3] += a4.z * w4.w;
            acc[3][0] += a4.w * w4.x; acc[3][1] += a4.w * w4.y;
            acc[3][2] += a4.w * w4.z; acc[3][3] += a4.w * w4.w;
        }
        __syncthreads();
    }

    #pragma unroll
    for (int r = 0; r < 4; ++r) {
        int gr = m0 + ty * 4 + r;
        if (gr < M) {
            float s = dinv[gr];
            _Float16 tmp[4];
            tmp[0] = (_Float16)(acc[r][0] * s);
            tmp[1] = (_Float16)(acc[r][1] * s);
            tmp[2] = (_Float16)(acc[r][2] * s);
            tmp[3] = (_Float16)(acc[r][3] * s);
            *(uint2*)&C[(size_t)gr * NC + tx * 4] = *(uint2*)tmp;
        }
    }
}

__global__ __launch_bounds__(256, 4) void gemm_conv1(const float* A, const float* W, _Float16* C, const float* dinv, int M) {
    gemm_body<64>(A, W, C, dinv, M);
}
__global__ __launch_bounds__(256, 4) void gemm_conv2(const float* A, const float* W, _Float16* C, const float* dinv, int M) {
    gemm_body<64>(A, W, C, dinv, M);
}

// ---------------- CSR aggregation (R11: 4 nodes/wave, uint2 = 4 f16/lane) ---
// 16-lane group per node: row = 16 lanes x 8B = 128B (2 cache lines). One
// wave-wide VMEM instruction serves 4 edges; 4 independent gather streams.
template<bool RESIDUAL, int OUTM>
__device__ __forceinline__ void agg_body(
    const uint2* __restrict__ y2, const int* __restrict__ row_ptr, const int* __restrict__ col,
    const float* __restrict__ dinv, const float* __restrict__ bias,
    const float* __restrict__ hprev, float* __restrict__ hout,
    uint2* __restrict__ hb2)
{
    int v  = blockIdx.x * 16 + (threadIdx.x >> 4);
    int sl = threadIdx.x & 15;
    if (v >= N_NODES) return;

    uint2 a = y2[(size_t)v * 16 + sl];             // self loop
    float2 alo = up16(a.x), ahi = up16(a.y);
    float s0 = alo.x, s1 = alo.y, s2 = ahi.x, s3 = ahi.y;

    int s = row_ptr[v], e = row_ptr[v + 1];
    int i = s;
    for (; i + 3 < e; i += 4) {
        int u0 = col[i], u1 = col[i + 1], u2 = col[i + 2], u3 = col[i + 3];
        uint2 f0 = y2[(size_t)u0 * 16 + sl];
        uint2 f1 = y2[(size_t)u1 * 16 + sl];
        uint2 f2 = y2[(size_t)u2 * 16 + sl];
        uint2 f3 = y2[(size_t)u3 * 16 + sl];
        float2 g0 = up16(f0.x), g1 = up16(f1.x), g2 = up16(f2.x), g3 = up16(f3.x);
        float2 h0 = up16(f0.y), h1 = up16(f1.y), h2 = up16(f2.y), h3 = up16(f3.y);
        s0 += (g0.x + g1.x) + (g2.x + g3.x);
        s1 += (g0.y + g1.y) + (g2.y + g3.y);
        s2 += (h0.x + h1.x) + (h2.x + h3.x);
        s3 += (h0.y + h1.y) + (h2.y + h3.y);
    }
    for (; i < e; ++i) {
        uint2 f = y2[(size_t)col[i] * 16 + sl];
        float2 g = up16(f.x), h = up16(f.y);
        s0 += g.x; s1 += g.y; s2 += h.x; s3 += h.y;
    }

    float dv = dinv[v];
    float4 b4 = *(const float4*)&bias[sl * 4];
    float v0 = fmaxf(dv * s0 + b4.x, 0.f);
    float v1 = fmaxf(dv * s1 + b4.y, 0.f);
    float v2 = fmaxf(dv * s2 + b4.z, 0.f);
    float v3 = fmaxf(dv * s3 + b4.w, 0.f);
    if (RESIDUAL) {
        float4 hp = *(const float4*)&hprev[(size_t)v * 64 + sl * 4];
        v0 += hp.x; v1 += hp.y; v2 += hp.z; v3 += hp.w;
    }
    if (OUTM == 2) {
        uint2 p;
        p.x = (unsigned)f2bf(v0) | ((unsigned)f2bf(v1) << 16);
        p.y = (unsigned)f2bf(v2) | ((unsigned)f2bf(v3) << 16);
        hb2[(size_t)v * 16 + sl] = p;
    } else {
        *(float4*)&hout[(size_t)v * 64 + sl * 4] = make_float4(v0, v1, v2, v3);
    }
}

__global__ __launch_bounds__(256) void agg0_kernel(const uint2* y, const int* rp, const int* col,
                                                   const float* dinv, const float* b, float* h) {
    agg_body<false, 0>(y, rp, col, dinv, b, nullptr, h, nullptr);
}
__global__ __launch_bounds__(256) void agg1_kernel(const uint2* y, const int* rp, const int* col,
                                                   const float* dinv, const float* b, float* h) {
    agg_body<true, 1>(y, rp, col, dinv, b, h, h, nullptr);   // in-place: group owns its row
}
__global__ __launch_bounds__(256) void agg2_kernel(const uint2* y, const int* rp, const int* col,
                                                   const float* dinv, const float* b,
                                                   const float* hprev, uint2* hb) {
    agg_body<true, 2>(y, rp, col, dinv, b, hprev, nullptr, hb);
}

extern "C" void kernel_launch(void* const* d_in, const int* in_sizes, int n_in,
                              void* d_out, int out_size, void* d_ws, size_t ws_size,
                              hipStream_t stream) {
    const float* x       = (const float*)d_in[0];
    const int*   ei      = (const int*)d_in[1];
    const int*   eli     = (const int*)d_in[2];
    const float* enc_w1  = (const float*)d_in[3];
    const float* enc_b1  = (const float*)d_in[4];
    const float* enc_w2  = (const float*)d_in[5];
    const float* enc_b2  = (const float*)d_in[6];
    const float* conv_w0 = (const float*)d_in[7];
    const float* conv_b0 = (const float*)d_in[8];
    const float* conv_w1 = (const float*)d_in[9];
    const float* conv_b1 = (const float*)d_in[10];
    const float* conv_w2 = (const float*)d_in[11];
    const float* conv_b2 = (const float*)d_in[12];
    const float* ep_w1   = (const float*)d_in[13];
    const float* ep_b1   = (const float*)d_in[14];
    const float* ep_w2   = (const float*)d_in[15];
    const float* ep_b2   = (const float*)d_in[16];
    const float* ep_w3   = (const float*)d_in[17];
    const float* ep_b3   = (const float*)d_in[18];
    float* out = (float*)d_out;

    // ---- workspace layout (float offsets) ----
    float* fws = (float*)d_ws;
    unsigned short* h1b  = (unsigned short*)fws;                 // bf16 [100k,256] = 12.8M f
    unsigned short* e1b  = (unsigned short*)(fws + 12800000);    // bf16 [200k,128] = 12.8M f
    unsigned short* h128b= e1b;                                  // alias: bf16 [100k,128] (dead before ep1)
    _Float16* yb         = (_Float16*)(fws + 25600000);          // f16 [100k,64] = 3.2M f
    float* h64           = fws + 28800000;                       // f32 [100k,64] = 6.4M f
    unsigned short* h64b = (unsigned short*)(fws + 35200000);    // bf16 [100k,64] = 3.2M f
    int*   col     = (int*)(fws + 38400000);                     // 1.6M i
    int*   row_ptr = col + 1600000;                              // 100001 (padded)
    int*   cnt     = row_ptr + 100032;
    float* dinvp   = (float*)(cnt + 100000);
    int*   partial = (int*)(dinvp + 100000);                     // 256
    unsigned short* w2p = (unsigned short*)(partial + 256);      // enc_w2: 32768 us
    unsigned short* w0p = w2p + 32768;                           // conv_w0: 8192 us
    unsigned short* w1p = w0p + 8192;                            // ep_w1: 16384 us
    unsigned short* wp2 = w1p + 16384;                           // ep_w2: 8192 us
    int*   btail   = (int*)(wp2 + 8192);                         // 98 i (+pad to 128)
    int*   bscr    = btail + 128;                                // 98*24576 = 2.41M i

    // ---- CSR build + weight swizzle (no global atomics anywhere) ----
    hipMemsetAsync(btail, 0, 128 * sizeof(int), stream);
    fill_part<<<PART_NB, 256, 0, stream>>>(ei, btail, bscr);
    deg_bucket<<<KBUCK, 1024, 0, stream>>>(btail, bscr, cnt, dinvp);
    wprep_kernel<256, 128><<<128, 256, 0, stream>>>(enc_w2,  w2p);
    wprep_kernel<128,  64><<< 32, 256, 0, stream>>>(conv_w0, w0p);
    wprep_kernel<128, 128><<< 64, 256, 0, stream>>>(ep_w1,   w1p);
    wprep_kernel<128,  64><<< 32, 256, 0, stream>>>(ep_w2,   wp2);
    scan1<<<SCAN_NB, 256, 0, stream>>>(cnt, partial);
    scan2<<<1, 256, 0, stream>>>(partial, row_ptr);
    scan3<<<SCAN_NB, 256, 0, stream>>>(cnt, partial, row_ptr);
    fill_place<<<KBUCK, 1024, 0, stream>>>(btail, bscr, row_ptr, col);

    const int GBN = (N_NODES + 63) / 64;   // 1563
    const int GBE = N_EL / 64;             // 3125
    const int GBA = (N_NODES + 15) / 16;   // 6250

    // ---- encoder ----
    enc1_kernel<<<GBN, 256, 0, stream>>>(x, enc_w1, enc_b1, h1b);
    mfma_enc2<<<GBN, 256, 0, stream>>>(h1b, w2p, enc_b2, h128b, N_NODES);

    // ---- GCN layer 0: 128 -> 64 (MFMA, bf16 in, f16 y out) ----
    mfma_conv0<<<GBN, 256, 0, stream>>>(h128b, w0p, dinvp, yb, N_NODES);
    agg0_kernel<<<GBA, 256, 0, stream>>>((const uint2*)yb, row_ptr, col, dinvp, conv_b0, h64);

    // ---- GCN layer 1: 64 -> 64, residual ----
    gemm_conv1<<<GBN, 256, 0, stream>>>(h64, conv_w1, yb, dinvp, N_NODES);
    agg1_kernel<<<GBA, 256, 0, stream>>>((const uint2*)yb, row_ptr, col, dinvp, conv_b1, h64);

    // ---- GCN layer 2: 64 -> 64, residual, bf16 out for ep1 ----
    gemm_conv2<<<GBN, 256, 0, stream>>>(h64, conv_w2, yb, dinvp, N_NODES);
    agg2_kernel<<<GBA, 256, 0, stream>>>((const uint2*)yb, row_ptr, col, dinvp, conv_b2, h64, (uint2*)h64b);

    // ---- edge predictor (bf16 MFMA; ep2+ep3 fused) ----
    mfma_ep1<<<GBE, 256, 0, stream>>>(h64b, w1p, ep_b1, e1b, eli, N_EL);
    mfma_ep2f<<<GBE, 256, 0, stream>>>(e1b, wp2, ep_b2, ep_w3, ep_b3, out, N_EL);
}

// Round 12
// 402.900 us; speedup vs baseline: 1.5585x; 1.0337x over previous
//
#include <hip/hip_runtime.h>
#include <math.h>

// ---------------------------------------------------------------------------
// EmergencyGNNEnhanced: encoder (32->256->128) -> 3x GCN (->64) -> edge MLP.
// CSR built on-device each call. agg[v] = dinv[v]*(sum_{u->v} y[u] + y[v]).
//
// R12: (a) CSR tail consolidated -- deg_bucket + scan1/2/3 deleted. Bucket
// segment starts are a 98-wide prefix of btail (bucket_base, 1 block);
// fill_place now does LDS histogram -> 1024-wide local scan -> coalesced
// row_ptr/dinv writes -> LDS scatter -> coalesced col write. (b) agg at
// 8 nodes/wave (8-lane groups, uint4 = 8 f16/lane): one VMEM instruction
// serves 8 edges, 8 independent gather streams/wave. The 8x-XCD fetch
// amplification (~98MB) is structural for the random gather.
// MFMA layouts HW-verified (R5-R11 passed).
// ---------------------------------------------------------------------------

#define N_NODES 100000
#define N_EDGES 1600000
#define N_EL    200000

#define KBUCK   98           // ceil(100000/1024) windows of 1024 nodes
#define WSHIFT  10
#define WMASK   1023
#define BCAP    128          // LDS entries/bucket in pass A (chunk avg 64, 8 sigma)
#define BSTRIDE 24576        // scratch ints per bucket (seglen ~16.4k avg)
#define PART_NB 256
#define CHUNK   6250         // ceil(N_EDGES / PART_NB)
#define LCAP    20480        // pass-B LDS staging (seglen max ~17k)

typedef __attribute__((ext_vector_type(8))) short short8_t;
typedef __attribute__((ext_vector_type(4))) float f32x4;

__device__ __forceinline__ unsigned short f2bf(float f) {
    unsigned u = __float_as_uint(f);
    unsigned r = u + 0x7FFFu + ((u >> 16) & 1u);   // RNE
    return (unsigned short)(r >> 16);
}

__device__ __forceinline__ float2 up16(unsigned u) {
    union { unsigned v; _Float16 h[2]; } c; c.v = u;
    return make_float2((float)c.h[0], (float)c.h[1]);
}

// ---- fill pass A: partition edges into 98 dst-window buckets ----
__global__ __launch_bounds__(256) void fill_part(const int* __restrict__ ei,
                                                 int* __restrict__ btail, int* __restrict__ bscr) {
    __shared__ int lbuf[KBUCK][BCAP];     // 50 KB
    __shared__ int lcnt[KBUCK];
    __shared__ int offs[KBUCK + 1];
    __shared__ int gbase[KBUCK];
    int t = threadIdx.x;
    for (int i = t; i < KBUCK; i += 256) lcnt[i] = 0;
    __syncthreads();

    int e0   = blockIdx.x * CHUNK;
    int eend = e0 + CHUNK; if (eend > N_EDGES) eend = N_EDGES;
    for (int e = e0 + t; e < eend; e += 256) {
        int s = __builtin_nontemporal_load(ei + e);
        int d = __builtin_nontemporal_load(ei + N_EDGES + e);
        int b = d >> WSHIFT;
        int entry = ((d & WMASK) << 17) | s;
        int pos = atomicAdd(&lcnt[b], 1);
        if (pos < BCAP) lbuf[b][pos] = entry;
        else {                                  // statistical-skew spill (rare)
            int p = atomicAdd(&btail[b], 1);
            bscr[b * BSTRIDE + p] = entry;
        }
    }
    __syncthreads();

    if (t < KBUCK) {
        int c = lcnt[t]; if (c > BCAP) c = BCAP;
        lcnt[t] = c;
        gbase[t] = atomicAdd(&btail[t], c);
    }
    __syncthreads();
    if (t == 0) {
        offs[0] = 0;
        for (int b = 0; b < KBUCK; ++b) offs[b + 1] = offs[b] + lcnt[b];
    }
    __syncthreads();

    int T = offs[KBUCK];
    for (int i = t; i < T; i += 256) {
        int loB = 0, hiB = KBUCK;               // binary search bucket
        while (hiB - loB > 1) { int mid = (loB + hiB) >> 1; if (offs[mid] <= i) loB = mid; else hiB = mid; }
        int j = i - offs[loB];
        bscr[loB * BSTRIDE + gbase[loB] + j] = lbuf[loB][j];
    }
}

// ---- bucket_base: 98-wide exclusive prefix of btail (1 block) ----
__global__ __launch_bounds__(128) void bucket_base(const int* __restrict__ btail, int* __restrict__ bbase,
                                                   int* __restrict__ row_ptr) {
    __shared__ int sm[128];
    int t = threadIdx.x;
    int v = (t < KBUCK) ? btail[t] : 0;
    sm[t] = v; __syncthreads();
    for (int s = 1; s < 128; s <<= 1) {
        int a = (t >= s) ? sm[t - s] : 0;
        __syncthreads();
        sm[t] += a;
        __syncthreads();
    }
    if (t < KBUCK) bbase[t] = sm[t] - v;        // exclusive
    if (t == 0) row_ptr[N_NODES] = N_EDGES;
}

// ---- fill_place: hist + local scan + row_ptr/dinv + LDS scatter + col ----
__global__ __launch_bounds__(1024) void fill_place(const int* __restrict__ btail, const int* __restrict__ bbase,
                                                   const int* __restrict__ bscr,
                                                   int* __restrict__ row_ptr, float* __restrict__ dinv,
                                                   int* __restrict__ col) {
    __shared__ int lcnt[1024];
    __shared__ int lpre[1024];
    __shared__ int lbuf[LCAP];                  // 80 KB
    int b = blockIdx.x, t = threadIdx.x;
    lcnt[t] = 0;
    __syncthreads();
    int n = btail[b];
    int segstart = bbase[b];
    const int* src = bscr + b * BSTRIDE;
    for (int i = t; i < n; i += 1024)
        atomicAdd(&lcnt[src[i] >> 17], 1);
    __syncthreads();

    int c = lcnt[t];
    lpre[t] = c; __syncthreads();
    for (int s = 1; s < 1024; s <<= 1) {        // inclusive scan
        int a = (t >= s) ? lpre[t - s] : 0;
        __syncthreads();
        lpre[t] += a;
        __syncthreads();
    }
    int excl = lpre[t] - c;

    int v = (b << WSHIFT) + t;
    if (v < N_NODES) {
        row_ptr[v] = segstart + excl;
        dinv[v] = rsqrtf((float)(c + 1));       // +1 self loop
    }
    lcnt[t] = excl;                             // reuse as cursor
    __syncthreads();

    if (n <= LCAP) {
        for (int i = t; i < n; i += 1024) {
            int e = src[i];
            int pos = atomicAdd(&lcnt[e >> 17], 1);
            lbuf[pos] = e & 0x1FFFF;
        }
        __syncthreads();
        for (int i = t; i < n; i += 1024)
            col[segstart + i] = lbuf[i];
    } else {                                    // safety fallback (never for this dist)
        for (int i = t; i < n; i += 1024) {
            int e = src[i];
            int pos = atomicAdd(&lcnt[e >> 17], 1);
            col[segstart + pos] = e & 0x1FFFF;
        }
    }
}

// ---------------- enc1: weight-stationary 32->256, bf16 output ----------------
__global__ __launch_bounds__(256, 2) void enc1_kernel(
    const float* __restrict__ x, const float* __restrict__ W,
    const float* __restrict__ bias, unsigned short* __restrict__ C)
{
    __shared__ float Ws[32][256];
    __shared__ float xt[32][68];
    __shared__ float bs[256];

    int t  = threadIdx.x;
    int r0 = blockIdx.x * 64;

    #pragma unroll
    for (int j = 0; j < 8; ++j) {
        int idx = t + j * 256;
        int kk = idx >> 6, cf = idx & 63;
        *(float4*)&Ws[kk][cf * 4] = *(const float4*)&W[kk * 256 + cf * 4];
    }
    if (t < 64) *(float4*)&bs[t * 4] = *(const float4*)&bias[t * 4];

    #pragma unroll
    for (int j = 0; j < 2; ++j) {
        int fidx = t + j * 256;
        int row = fidx >> 3, kf = fidx & 7;
        int gr = r0 + row;
        float4 v = (gr < N_NODES) ? *(const float4*)&x[(size_t)gr * 32 + kf * 4]
                                  : make_float4(0.f, 0.f, 0.f, 0.f);
        xt[kf * 4 + 0][row] = v.x; xt[kf * 4 + 1][row] = v.y;
        xt[kf * 4 + 2][row] = v.z; xt[kf * 4 + 3][row] = v.w;
    }
    __syncthreads();

    int tx = t & 63, ty = t >> 6;
    float4 b4 = *(const float4*)&bs[tx * 4];
    float4 acc[16];
    #pragma unroll
    for (int r = 0; r < 16; ++r) acc[r] = b4;

    #pragma unroll 4
    for (int k = 0; k < 32; ++k) {
        float4 w4 = *(const float4*)&Ws[k][tx * 4];
        #pragma unroll
        for (int j = 0; j < 4; ++j) {
            float4 a4 = *(const float4*)&xt[k][ty * 16 + j * 4];
            acc[j * 4 + 0].x += a4.x * w4.x; acc[j * 4 + 0].y += a4.x * w4.y;
            acc[j * 4 + 0].z += a4.x * w4.z; acc[j * 4 + 0].w += a4.x * w4.w;
            acc[j * 4 + 1].x += a4.y * w4.x; acc[j * 4 + 1].y += a4.y * w4.y;
            acc[j * 4 + 1].z += a4.y * w4.z; acc[j * 4 + 1].w += a4.y * w4.w;
            acc[j * 4 + 2].x += a4.z * w4.x; acc[j * 4 + 2].y += a4.z * w4.y;
            acc[j * 4 + 2].z += a4.z * w4.z; acc[j * 4 + 2].w += a4.z * w4.w;
            acc[j * 4 + 3].x += a4.w * w4.x; acc[j * 4 + 3].y += a4.w * w4.y;
            acc[j * 4 + 3].z += a4.w * w4.z; acc[j * 4 + 3].w += a4.w * w4.w;
        }
    }

    #pragma unroll
    for (int r = 0; r < 16; ++r) {
        int gr = r0 + ty * 16 + r;
        if (gr < N_NODES) {
            float4 v = acc[r];
            unsigned p0 = (unsigned)f2bf(fmaxf(v.x, 0.f)) | ((unsigned)f2bf(fmaxf(v.y, 0.f)) << 16);
            unsigned p1 = (unsigned)f2bf(fmaxf(v.z, 0.f)) | ((unsigned)f2bf(fmaxf(v.w, 0.f)) << 16);
            *(uint2*)&C[(size_t)gr * 256 + tx * 4] = make_uint2(p0, p1);
        }
    }
}

// ---------------- weight swizzle: fp32 W[K][N] -> bf16 B-fragment order -----
template<int KTOT, int NTOT>
__global__ __launch_bounds__(256) void wprep_kernel(const float* __restrict__ W, unsigned short* __restrict__ Wp) {
    int flat = blockIdx.x * 256 + threadIdx.x;
    if (flat >= KTOT * NTOT) return;
    int j = flat & 7, lane = (flat >> 3) & 63, kstep = (flat >> 9) & 1;
    int rest = flat >> 10;
    int ntile = rest % (NTOT / 16), chunk = rest / (NTOT / 16);
    int k = chunk * 64 + kstep * 32 + (lane >> 4) * 8 + j;
    int n = ntile * 16 + (lane & 15);
    Wp[flat] = f2bf(W[(size_t)k * NTOT + n]);
}

// ---------------- bf16 MFMA GEMM ----------------
template<int NTOT, int KTOT, bool GATHER, bool BIAS_RELU, int OUTT>
__device__ __forceinline__ void mfma_gemm_body(
    const unsigned short* __restrict__ A, const unsigned short* __restrict__ Wp,
    const float* __restrict__ bias, const float* __restrict__ dinv,
    void* __restrict__ Cout, const int* __restrict__ gidx, int M)
{
    constexpr int NT16 = NTOT / 16;
    constexpr int NCH  = KTOT / 64;
    __shared__ unsigned short As[64][72];
    __shared__ unsigned short Wls[NT16 * 1024];

    int t = threadIdx.x, wave = t >> 6, lane = t & 63;
    int m0 = blockIdx.x * 64;

    f32x4 acc[NT16];
    #pragma unroll
    for (int nt = 0; nt < NT16; ++nt) acc[nt] = (f32x4){0.f, 0.f, 0.f, 0.f};

    for (int ch = 0; ch < NCH; ++ch) {
        #pragma unroll
        for (int j = 0; j < 2; ++j) {
            int idx = t + j * 256;
            int row = idx >> 3, seg = idx & 7;
            int gr = m0 + row;
            uint4 v = make_uint4(0u, 0u, 0u, 0u);
            if (gr < M) {
                const unsigned short* src;
                if (GATHER) {
                    int node = (ch == 0) ? gidx[gr] : gidx[N_EL + gr];
                    src = A + (size_t)node * 64 + seg * 8;
                } else {
                    src = A + (size_t)gr * KTOT + ch * 64 + seg * 8;
                }
                v = *(const uint4*)src;
            }
            *(uint4*)&As[row][seg * 8] = v;
        }
        constexpr int WL16 = NT16 * 128;            // uint4 count
        #pragma unroll
        for (int j = 0; j < WL16 / 256; ++j) {
            int idx = t + j * 256;
            ((uint4*)Wls)[idx] = ((const uint4*)(Wp + (size_t)ch * NT16 * 1024))[idx];
        }
        __syncthreads();

        #pragma unroll
        for (int ks = 0; ks < 2; ++ks) {
            short8_t af = *(const short8_t*)&As[wave * 16 + (lane & 15)][ks * 32 + (lane >> 4) * 8];
            #pragma unroll
            for (int nt = 0; nt < NT16; ++nt) {
                short8_t bf = *(const short8_t*)&Wls[((nt * 2 + ks) * 64 + lane) * 8];
                acc[nt] = __builtin_amdgcn_mfma_f32_16x16x32_bf16(af, bf, acc[nt], 0, 0, 0);
            }
        }
        __syncthreads();
    }

    int cb = lane & 15, rq = lane >> 4;
    #pragma unroll
    for (int nt = 0; nt < NT16; ++nt) {
        int col = nt * 16 + cb;
        float bv = BIAS_RELU ? bias[col] : 0.f;
        #pragma unroll
        for (int r = 0; r < 4; ++r) {
            int gr = m0 + wave * 16 + rq * 4 + r;
            if (gr < M) {
                float val;
                if (BIAS_RELU) val = fmaxf(acc[nt][r] + bv, 0.f);
                else           val = acc[nt][r] * dinv[gr];
                size_t o = (size_t)gr * NTOT + col;
                if (OUTT == 1)      ((unsigned short*)Cout)[o] = f2bf(val);
                else if (OUTT == 2) ((_Float16*)Cout)[o] = (_Float16)val;
                else                ((float*)Cout)[o] = val;
            }
        }
    }
}

__global__ __launch_bounds__(256, 4) void mfma_enc2(const unsigned short* A, const unsigned short* Wp,
                                                    const float* b, unsigned short* C, int M) {
    mfma_gemm_body<128, 256, false, true, 1>(A, Wp, b, nullptr, C, nullptr, M);
}
__global__ __launch_bounds__(256, 4) void mfma_conv0(const unsigned short* A, const unsigned short* Wp,
                                                     const float* dinv, _Float16* C, int M) {
    mfma_gemm_body<64, 128, false, false, 2>(A, Wp, nullptr, dinv, C, nullptr, M);
}
__global__ __launch_bounds__(256, 4) void mfma_ep1(const unsigned short* A, const unsigned short* Wp,
                                                   const float* b, unsigned short* C, const int* gidx, int M) {
    mfma_gemm_body<128, 128, true, true, 1>(A, Wp, b, nullptr, C, gidx, M);
}

// ---------------- ep2 fused with ep3: sigmoid(relu(e1@W2+b2) . w3 + b3) -----
__global__ __launch_bounds__(256, 4) void mfma_ep2f(
    const unsigned short* __restrict__ A, const unsigned short* __restrict__ Wp,
    const float* __restrict__ b2, const float* __restrict__ w3,
    const float* __restrict__ b3, float* __restrict__ out, int M)
{
    constexpr int NT16 = 4;
    __shared__ unsigned short As[64][72];
    __shared__ unsigned short Wls[NT16 * 1024];

    int t = threadIdx.x, wave = t >> 6, lane = t & 63;
    int m0 = blockIdx.x * 64;

    f32x4 acc[NT16];
    #pragma unroll
    for (int nt = 0; nt < NT16; ++nt) acc[nt] = (f32x4){0.f, 0.f, 0.f, 0.f};

    for (int ch = 0; ch < 2; ++ch) {
        #pragma unroll
        for (int j = 0; j < 2; ++j) {
            int idx = t + j * 256;
            int row = idx >> 3, seg = idx & 7;
            int gr = m0 + row;
            uint4 v = make_uint4(0u, 0u, 0u, 0u);
            if (gr < M) v = *(const uint4*)(A + (size_t)gr * 128 + ch * 64 + seg * 8);
            *(uint4*)&As[row][seg * 8] = v;
        }
        #pragma unroll
        for (int j = 0; j < 2; ++j) {
            int idx = t + j * 256;
            ((uint4*)Wls)[idx] = ((const uint4*)(Wp + (size_t)ch * NT16 * 1024))[idx];
        }
        __syncthreads();

        #pragma unroll
        for (int ks = 0; ks < 2; ++ks) {
            short8_t af = *(const short8_t*)&As[wave * 16 + (lane & 15)][ks * 32 + (lane >> 4) * 8];
            #pragma unroll
            for (int nt = 0; nt < NT16; ++nt) {
                short8_t bf = *(const short8_t*)&Wls[((nt * 2 + ks) * 64 + lane) * 8];
                acc[nt] = __builtin_amdgcn_mfma_f32_16x16x32_bf16(af, bf, acc[nt], 0, 0, 0);
            }
        }
        __syncthreads();
    }

    int cb = lane & 15, rq = lane >> 4;
    float s0 = 0.f, s1 = 0.f, s2 = 0.f, s3 = 0.f;
    #pragma unroll
    for (int nt = 0; nt < NT16; ++nt) {
        int col = nt * 16 + cb;
        float bv = b2[col], wv = w3[col];
        s0 += fmaxf(acc[nt][0] + bv, 0.f) * wv;
        s1 += fmaxf(acc[nt][1] + bv, 0.f) * wv;
        s2 += fmaxf(acc[nt][2] + bv, 0.f) * wv;
        s3 += fmaxf(acc[nt][3] + bv, 0.f) * wv;
    }
    #pragma unroll
    for (int off = 1; off < 16; off <<= 1) {
        s0 += __shfl_xor(s0, off);
        s1 += __shfl_xor(s1, off);
        s2 += __shfl_xor(s2, off);
        s3 += __shfl_xor(s3, off);
    }
    if (cb == 0) {
        int gr = m0 + wave * 16 + rq * 4;
        if (gr + 3 < M) {
            float bb = b3[0];
            float4 o;
            o.x = 1.f / (1.f + expf(-(s0 + bb)));
            o.y = 1.f / (1.f + expf(-(s1 + bb)));
            o.z = 1.f / (1.f + expf(-(s2 + bb)));
            o.w = 1.f / (1.f + expf(-(s3 + bb)));
            *(float4*)&out[gr] = o;
        }
    }
}

// ---------------- fp32 tiled GEMM (conv1/2): y = f16(dinv .* (A@W)) ---------
template<int KTOT>
__device__ __forceinline__ void gemm_body(
    const float* __restrict__ A, const float* __restrict__ W,
    _Float16* __restrict__ C, const float* __restrict__ dinv, int M)
{
    constexpr int KB = 32;
    constexpr int NC = 64;
    __shared__ float As[KB][68];
    __shared__ float Ws[KB][64];

    int t  = threadIdx.x;
    int m0 = blockIdx.x * 64;
    int tx = t & 15, ty = t >> 4;

    float acc[4][4];
    #pragma unroll
    for (int r = 0; r < 4; ++r)
        #pragma unroll
        for (int c = 0; c < 4; ++c) acc[r][c] = 0.f;

    for (int k0 = 0; k0 < KTOT; k0 += KB) {
        #pragma unroll
        for (int j = 0; j < 2; ++j) {
            int idx = t + j * 256;
            int row = idx >> 3, kf = idx & 7;
            int gr  = m0 + row;
            float4 v = make_float4(0.f, 0.f, 0.f, 0.f);
            if (gr < M) v = *(const float4*)&A[(size_t)gr * KTOT + k0 + kf * 4];
            As[kf * 4 + 0][row] = v.x; As[kf * 4 + 1][row] = v.y;
            As[kf * 4 + 2][row] = v.z; As[kf * 4 + 3][row] = v.w;
        }
        #pragma unroll
        for (int j = 0; j < 2; ++j) {
            int idx = t + j * 256;
            int kk = idx >> 4, cf = idx & 15;
            *(float4*)&Ws[kk][cf * 4] = *(const float4*)&W[(size_t)(k0 + kk) * NC + cf * 4];
        }
        __syncthreads();

        #pragma unroll
        for (int kk = 0; kk < KB; ++kk) {
            float4 a4 = *(const float4*)&As[kk][ty * 4];
            float4 w4 = *(const float4*)&Ws[kk][tx * 4];
            acc[0][0] += a4.x * w4.x; acc[0][1] += a4.x * w4.y;
            acc[0][2] += a4.x * w4.z; acc[0][3] += a4.x * w4.w;
            acc[1][0] += a4.y * w4.x; acc[1][1] += a4.y * w4.y;
            acc[1][2] += a4.y * w4.z; acc[1][3] += a4.y * w4.w;
            acc[2][0] += a4.z * w4.x; acc[2][1] += a4.z * w4.y;
            acc[2][2] += a4.z * w4.z; acc[2][3] += a4.z * w4.w;
            acc[3][0] += a4.w * w4.x; acc[3][1] += a4.w * w4.y;
            acc[3][2] += a4.w * w4.z; acc[3][3] += a4.w * w4.w;
        }
        __syncthreads();
    }

    #pragma unroll
    for (int r = 0; r < 4; ++r) {
        int gr = m0 + ty * 4 + r;
        if (gr < M) {
            float s = dinv[gr];
            _Float16 tmp[4];
            tmp[0] = (_Float16)(acc[r][0] * s);
            tmp[1] = (_Float16)(acc[r][1] * s);
            tmp[2] = (_Float16)(acc[r][2] * s);
            tmp[3] = (_Float16)(acc[r][3] * s);
            *(uint2*)&C[(size_t)gr * NC + tx * 4] = *(uint2*)tmp;
        }
    }
}

__global__ __launch_bounds__(256, 4) void gemm_conv1(const float* A, const float* W, _Float16* C, const float* dinv, int M) {
    gemm_body<64>(A, W, C, dinv, M);
}
__global__ __launch_bounds__(256, 4) void gemm_conv2(const float* A, const float* W, _Float16* C, const float* dinv, int M) {
    gemm_body<64>(A, W, C, dinv, M);
}

// ---------------- CSR aggregation (R12: 8 nodes/wave, uint4 = 8 f16/lane) ---
// 8-lane group per node: row = 8 lanes x 16B = 128B. One wave-wide VMEM
// instruction serves 8 edges; 8 independent gather streams per wave.
template<bool RESIDUAL, int OUTM>
__device__ __forceinline__ void agg_body(
    const uint4* __restrict__ y4, const int* __restrict__ row_ptr, const int* __restrict__ col,
    const float* __restrict__ dinv, const float* __restrict__ bias,
    const float* __restrict__ hprev, float* __restrict__ hout,
    uint4* __restrict__ hb4)
{
    int v  = blockIdx.x * 32 + (threadIdx.x >> 3);
    int sl = threadIdx.x & 7;
    if (v >= N_NODES) return;

    uint4 a = y4[(size_t)v * 8 + sl];              // self loop
    float2 p0 = up16(a.x), p1 = up16(a.y), p2 = up16(a.z), p3 = up16(a.w);
    float s0 = p0.x, s1 = p0.y, s2 = p1.x, s3 = p1.y;
    float s4 = p2.x, s5 = p2.y, s6 = p3.x, s7 = p3.y;

    int s = row_ptr[v], e = row_ptr[v + 1];
    int i = s;
    for (; i + 3 < e; i += 4) {
        int u0 = col[i], u1 = col[i + 1], u2 = col[i + 2], u3 = col[i + 3];
        uint4 f0 = y4[(size_t)u0 * 8 + sl];
        uint4 f1 = y4[(size_t)u1 * 8 + sl];
        uint4 f2 = y4[(size_t)u2 * 8 + sl];
        uint4 f3 = y4[(size_t)u3 * 8 + sl];
        float2 g;
        g = up16(f0.x); s0 += g.x; s1 += g.y;  g = up16(f0.y); s2 += g.x; s3 += g.y;
        g = up16(f0.z); s4 += g.x; s5 += g.y;  g = up16(f0.w); s6 += g.x; s7 += g.y;
        g = up16(f1.x); s0 += g.x; s1 += g.y;  g = up16(f1.y); s2 += g.x; s3 += g.y;
        g = up16(f1.z); s4 += g.x; s5 += g.y;  g = up16(f1.w); s6 += g.x; s7 += g.y;
        g = up16(f2.x); s0 += g.x; s1 += g.y;  g = up16(f2.y); s2 += g.x; s3 += g.y;
        g = up16(f2.z); s4 += g.x; s5 += g.y;  g = up16(f2.w); s6 += g.x; s7 += g.y;
        g = up16(f3.x); s0 += g.x; s1 += g.y;  g = up16(f3.y); s2 += g.x; s3 += g.y;
        g = up16(f3.z); s4 += g.x; s5 += g.y;  g = up16(f3.w); s6 += g.x; s7 += g.y;
    }
    for (; i < e; ++i) {
        uint4 f = y4[(size_t)col[i] * 8 + sl];
        float2 g;
        g = up16(f.x); s0 += g.x; s1 += g.y;  g = up16(f.y); s2 += g.x; s3 += g.y;
        g = up16(f.z); s4 += g.x; s5 += g.y;  g = up16(f.w); s6 += g.x; s7 += g.y;
    }

    float dv = dinv[v];
    float4 ba = *(const float4*)&bias[sl * 8];
    float4 bb = *(const float4*)&bias[sl * 8 + 4];
    float v0 = fmaxf(dv * s0 + ba.x, 0.f), v1 = fmaxf(dv * s1 + ba.y, 0.f);
    float v2 = fmaxf(dv * s2 + ba.z, 0.f), v3 = fmaxf(dv * s3 + ba.w, 0.f);
    float v4 = fmaxf(dv * s4 + bb.x, 0.f), v5 = fmaxf(dv * s5 + bb.y, 0.f);
    float v6 = fmaxf(dv * s6 + bb.z, 0.f), v7 = fmaxf(dv * s7 + bb.w, 0.f);
    if (RESIDUAL) {
        float4 h0 = *(const float4*)&hprev[(size_t)v * 64 + sl * 8];
        float4 h1 = *(const float4*)&hprev[(size_t)v * 64 + sl * 8 + 4];
        v0 += h0.x; v1 += h0.y; v2 += h0.z; v3 += h0.w;
        v4 += h1.x; v5 += h1.y; v6 += h1.z; v7 += h1.w;
    }
    if (OUTM == 2) {
        uint4 p;
        p.x = (unsigned)f2bf(v0) | ((unsigned)f2bf(v1) << 16);
        p.y = (unsigned)f2bf(v2) | ((unsigned)f2bf(v3) << 16);
        p.z = (unsigned)f2bf(v4) | ((unsigned)f2bf(v5) << 16);
        p.w = (unsigned)f2bf(v6) | ((unsigned)f2bf(v7) << 16);
        hb4[(size_t)v * 8 + sl] = p;
    } else {
        *(float4*)&hout[(size_t)v * 64 + sl * 8]     = make_float4(v0, v1, v2, v3);
        *(float4*)&hout[(size_t)v * 64 + sl * 8 + 4] = make_float4(v4, v5, v6, v7);
    }
}

__global__ __launch_bounds__(256) void agg0_kernel(const uint4* y, const int* rp, const int* col,
                                                   const float* dinv, const float* b, float* h) {
    agg_body<false, 0>(y, rp, col, dinv, b, nullptr, h, nullptr);
}
__global__ __launch_bounds__(256) void agg1_kernel(const uint4* y, const int* rp, const int* col,
                                                   const float* dinv, const float* b, float* h) {
    agg_body<true, 1>(y, rp, col, dinv, b, h, h, nullptr);   // in-place: group owns its row
}
__global__ __launch_bounds__(256) void agg2_kernel(const uint4* y, const int* rp, const int* col,
                                                   const float* dinv, const float* b,
                                                   const float* hprev, uint4* hb) {
    agg_body<true, 2>(y, rp, col, dinv, b, hprev, nullptr, hb);
}

extern "C" void kernel_launch(void* const* d_in, const int* in_sizes, int n_in,
                              void* d_out, int out_size, void* d_ws, size_t ws_size,
                              hipStream_t stream) {
    const float* x       = (const float*)d_in[0];
    const int*   ei      = (const int*)d_in[1];
    const int*   eli     = (const int*)d_in[2];
    const float* enc_w1  = (const float*)d_in[3];
    const float* enc_b1  = (const float*)d_in[4];
    const float* enc_w2  = (const float*)d_in[5];
    const float* enc_b2  = (const float*)d_in[6];
    const float* conv_w0 = (const float*)d_in[7];
    const float* conv_b0 = (const float*)d_in[8];
    const float* conv_w1 = (const float*)d_in[9];
    const float* conv_b1 = (const float*)d_in[10];
    const float* conv_w2 = (const float*)d_in[11];
    const float* conv_b2 = (const float*)d_in[12];
    const float* ep_w1   = (const float*)d_in[13];
    const float* ep_b1   = (const float*)d_in[14];
    const float* ep_w2   = (const float*)d_in[15];
    const float* ep_b2   = (const float*)d_in[16];
    const float* ep_w3   = (const float*)d_in[17];
    const float* ep_b3   = (const float*)d_in[18];
    float* out = (float*)d_out;

    // ---- workspace layout (float offsets) ----
    float* fws = (float*)d_ws;
    unsigned short* h1b  = (unsigned short*)fws;                 // bf16 [100k,256] = 12.8M f
    unsigned short* e1b  = (unsigned short*)(fws + 12800000);    // bf16 [200k,128] = 12.8M f
    unsigned short* h128b= e1b;                                  // alias: bf16 [100k,128] (dead before ep1)
    _Float16* yb         = (_Float16*)(fws + 25600000);          // f16 [100k,64] = 3.2M f
    float* h64           = fws + 28800000;                       // f32 [100k,64] = 6.4M f
    unsigned short* h64b = (unsigned short*)(fws + 35200000);    // bf16 [100k,64] = 3.2M f
    int*   col     = (int*)(fws + 38400000);                     // 1.6M i
    int*   row_ptr = col + 1600000;                              // 100001 (padded)
    float* dinvp   = (float*)(row_ptr + 100032);
    unsigned short* w2p = (unsigned short*)(dinvp + 100000);     // enc_w2: 32768 us
    unsigned short* w0p = w2p + 32768;                           // conv_w0: 8192 us
    unsigned short* w1p = w0p + 8192;                            // ep_w1: 16384 us
    unsigned short* wp2 = w1p + 16384;                           // ep_w2: 8192 us
    int*   btail   = (int*)(wp2 + 8192);                         // 98 i (+pad to 128)
    int*   bbase   = btail + 128;                                // 98 i (+pad to 128)
    int*   bscr    = bbase + 128;                                // 98*24576 = 2.41M i

    // ---- CSR build + weight swizzle (no global atomics anywhere) ----
    hipMemsetAsync(btail, 0, 128 * sizeof(int), stream);
    fill_part<<<PART_NB, 256, 0, stream>>>(ei, btail, bscr);
    bucket_base<<<1, 128, 0, stream>>>(btail, bbase, row_ptr);
    wprep_kernel<256, 128><<<128, 256, 0, stream>>>(enc_w2,  w2p);
    wprep_kernel<128,  64><<< 32, 256, 0, stream>>>(conv_w0, w0p);
    wprep_kernel<128, 128><<< 64, 256, 0, stream>>>(ep_w1,   w1p);
    wprep_kernel<128,  64><<< 32, 256, 0, stream>>>(ep_w2,   wp2);
    fill_place<<<KBUCK, 1024, 0, stream>>>(btail, bbase, bscr, row_ptr, dinvp, col);

    const int GBN = (N_NODES + 63) / 64;   // 1563
    const int GBE = N_EL / 64;             // 3125
    const int GBA = (N_NODES + 31) / 32;   // 3125

    // ---- encoder ----
    enc1_kernel<<<GBN, 256, 0, stream>>>(x, enc_w1, enc_b1, h1b);
    mfma_enc2<<<GBN, 256, 0, stream>>>(h1b, w2p, enc_b2, h128b, N_NODES);

    // ---- GCN layer 0: 128 -> 64 (MFMA, bf16 in, f16 y out) ----
    mfma_conv0<<<GBN, 256, 0, stream>>>(h128b, w0p, dinvp, yb, N_NODES);
    agg0_kernel<<<GBA, 256, 0, stream>>>((const uint4*)yb, row_ptr, col, dinvp, conv_b0, h64);

    // ---- GCN layer 1: 64 -> 64, residual ----
    gemm_conv1<<<GBN, 256, 0, stream>>>(h64, conv_w1, yb, dinvp, N_NODES);
    agg1_kernel<<<GBA, 256, 0, stream>>>((const uint4*)yb, row_ptr, col, dinvp, conv_b1, h64);

    // ---- GCN layer 2: 64 -> 64, residual, bf16 out for ep1 ----
    gemm_conv2<<<GBN, 256, 0, stream>>>(h64, conv_w2, yb, dinvp, N_NODES);
    agg2_kernel<<<GBA, 256, 0, stream>>>((const uint4*)yb, row_ptr, col, dinvp, conv_b2, h64, (uint4*)h64b);

    // ---- edge predictor (bf16 MFMA; ep2+ep3 fused) ----
    mfma_ep1<<<GBE, 256, 0, stream>>>(h64b, w1p, ep_b1, e1b, eli, N_EL);
    mfma_ep2f<<<GBE, 256, 0, stream>>>(e1b, wp2, ep_b2, ep_w3, ep_b3, out, N_EL);
}

// Round 14
// 385.058 us; speedup vs baseline: 1.6307x; 1.0463x over previous
//
#include <hip/hip_runtime.h>
#include <math.h>

// ---------------------------------------------------------------------------
// EmergencyGNNEnhanced: encoder (32->256->128) -> 3x GCN (->64) -> edge MLP.
// CSR built on-device each call. agg[v] = dinv[v]*(sum_{u->v} y[u] + y[v]).
//
// R14 = R13 with the mfma_enc1 staging bug fixed: Wls is 1024 uint4 (16KB);
// R13 only copied 512 -> nt>=8 B-fragments read uninitialized LDS -> NaN.
// R13 changes kept: enc1 as MFMA (K=32 single k-step, x->bf16 in staging),
// fill_part at 512 blocks, wprep merged into one dispatch, bucket_base
// folded into fill_place. MFMA layouts HW-verified (R5-R12).
// ---------------------------------------------------------------------------

#define N_NODES 100000
#define N_EDGES 1600000
#define N_EL    200000

#define KBUCK   98           // ceil(100000/1024) windows of 1024 nodes
#define WSHIFT  10
#define WMASK   1023
#define BCAP    128          // LDS entries/bucket in pass A (chunk avg 32)
#define BSTRIDE 24576        // scratch ints per bucket (seglen ~16.4k avg)
#define PART_NB 512
#define CHUNK   3125         // ceil(N_EDGES / PART_NB)
#define LCAP    20480        // pass-B LDS staging (seglen max ~17k)

typedef __attribute__((ext_vector_type(8))) short short8_t;
typedef __attribute__((ext_vector_type(4))) float f32x4;

__device__ __forceinline__ unsigned short f2bf(float f) {
    unsigned u = __float_as_uint(f);
    unsigned r = u + 0x7FFFu + ((u >> 16) & 1u);   // RNE
    return (unsigned short)(r >> 16);
}

__device__ __forceinline__ float2 up16(unsigned u) {
    union { unsigned v; _Float16 h[2]; } c; c.v = u;
    return make_float2((float)c.h[0], (float)c.h[1]);
}

// ---- fill pass A: partition edges into 98 dst-window buckets ----
__global__ __launch_bounds__(256) void fill_part(const int* __restrict__ ei,
                                                 int* __restrict__ btail, int* __restrict__ bscr) {
    __shared__ int lbuf[KBUCK][BCAP];     // 50 KB
    __shared__ int lcnt[KBUCK];
    __shared__ int offs[KBUCK + 1];
    __shared__ int gbase[KBUCK];
    int t = threadIdx.x;
    for (int i = t; i < KBUCK; i += 256) lcnt[i] = 0;
    __syncthreads();

    int e0   = blockIdx.x * CHUNK;
    int eend = e0 + CHUNK; if (eend > N_EDGES) eend = N_EDGES;
    for (int e = e0 + t; e < eend; e += 256) {
        int s = __builtin_nontemporal_load(ei + e);
        int d = __builtin_nontemporal_load(ei + N_EDGES + e);
        int b = d >> WSHIFT;
        int entry = ((d & WMASK) << 17) | s;
        int pos = atomicAdd(&lcnt[b], 1);
        if (pos < BCAP) lbuf[b][pos] = entry;
        else {                                  // statistical-skew spill (rare)
            int p = atomicAdd(&btail[b], 1);
            bscr[b * BSTRIDE + p] = entry;
        }
    }
    __syncthreads();

    if (t < KBUCK) {
        int c = lcnt[t]; if (c > BCAP) c = BCAP;
        lcnt[t] = c;
        gbase[t] = atomicAdd(&btail[t], c);
    }
    __syncthreads();
    if (t == 0) {
        offs[0] = 0;
        for (int b = 0; b < KBUCK; ++b) offs[b + 1] = offs[b] + lcnt[b];
    }
    __syncthreads();

    int T = offs[KBUCK];
    for (int i = t; i < T; i += 256) {
        int loB = 0, hiB = KBUCK;               // binary search bucket
        while (hiB - loB > 1) { int mid = (loB + hiB) >> 1; if (offs[mid] <= i) loB = mid; else hiB = mid; }
        int j = i - offs[loB];
        bscr[loB * BSTRIDE + gbase[loB] + j] = lbuf[loB][j];
    }
}

// ---- fill_place: btail prefix + hist + local scan + row_ptr/dinv + scatter ----
__global__ __launch_bounds__(1024) void fill_place(const int* __restrict__ btail,
                                                   const int* __restrict__ bscr,
                                                   int* __restrict__ row_ptr, float* __restrict__ dinv,
                                                   int* __restrict__ col) {
    __shared__ int ssm[128];
    __shared__ int lcnt[1024];
    __shared__ int lpre[1024];
    __shared__ int lbuf[LCAP];                  // 80 KB
    int b = blockIdx.x, t = threadIdx.x;

    if (t < 128) ssm[t] = (t < KBUCK) ? btail[t] : 0;
    lcnt[t] = 0;
    __syncthreads();
    for (int s = 1; s < 128; s <<= 1) {         // inclusive scan of btail
        int a = 0;
        if (t < 128 && t >= s) a = ssm[t - s];
        __syncthreads();
        if (t < 128) ssm[t] += a;
        __syncthreads();
    }
    int segstart = (b == 0) ? 0 : ssm[b - 1];
    int n = btail[b];
    const int* src = bscr + b * BSTRIDE;
    for (int i = t; i < n; i += 1024)
        atomicAdd(&lcnt[src[i] >> 17], 1);
    __syncthreads();

    int c = lcnt[t];
    lpre[t] = c; __syncthreads();
    for (int s = 1; s < 1024; s <<= 1) {        // inclusive scan
        int a = (t >= s) ? lpre[t - s] : 0;
        __syncthreads();
        lpre[t] += a;
        __syncthreads();
    }
    int excl = lpre[t] - c;

    int v = (b << WSHIFT) + t;
    if (v < N_NODES) {
        row_ptr[v] = segstart + excl;
        dinv[v] = rsqrtf((float)(c + 1));       // +1 self loop
    }
    if (b == KBUCK - 1 && t == 0) row_ptr[N_NODES] = N_EDGES;
    lcnt[t] = excl;                             // reuse as cursor
    __syncthreads();

    if (n <= LCAP) {
        for (int i = t; i < n; i += 1024) {
            int e = src[i];
            int pos = atomicAdd(&lcnt[e >> 17], 1);
            lbuf[pos] = e & 0x1FFFF;
        }
        __syncthreads();
        for (int i = t; i < n; i += 1024)
            col[segstart + i] = lbuf[i];
    } else {                                    // safety fallback (never for this dist)
        for (int i = t; i < n; i += 1024) {
            int e = src[i];
            int pos = atomicAdd(&lcnt[e >> 17], 1);
            col[segstart + pos] = e & 0x1FFFF;
        }
    }
}

// ---------------- weight swizzle: fp32 W[K][N] -> bf16 B-fragment order -----
template<int KTOT, int NTOT>
__device__ __forceinline__ void wprep_one(const float* __restrict__ W, unsigned short* __restrict__ Wp, int flat) {
    if (flat >= KTOT * NTOT) return;
    int j = flat & 7, lane = (flat >> 3) & 63, kstep = (flat >> 9) & 1;
    int rest = flat >> 10;
    int ntile = rest % (NTOT / 16), chunk = rest / (NTOT / 16);
    int k = chunk * 64 + kstep * 32 + (lane >> 4) * 8 + j;
    int n = ntile * 16 + (lane & 15);
    Wp[flat] = f2bf(W[(size_t)k * NTOT + n]);
}

// K=32 variant (single k-step) for enc_w1 [32 x 256]
__device__ __forceinline__ void wprep32_one(const float* __restrict__ W, unsigned short* __restrict__ Wp, int flat) {
    if (flat >= 32 * 256) return;
    int j = flat & 7, lane = (flat >> 3) & 63, ntile = flat >> 9;   // 0..15
    int k = (lane >> 4) * 8 + j;
    int n = ntile * 16 + (lane & 15);
    Wp[flat] = f2bf(W[(size_t)k * 256 + n]);
}

// One dispatch for all 5 weight swizzles (288 blocks).
__global__ __launch_bounds__(256) void wprep_all(
    const float* w2, const float* w0, const float* w1, const float* wpp2, const float* w1e,
    unsigned short* p2, unsigned short* p0, unsigned short* p1, unsigned short* pp2, unsigned short* p1e)
{
    int blk = blockIdx.x, t = threadIdx.x;
    if      (blk < 128) wprep_one<256, 128>(w2,  p2,  blk * 256 + t);
    else if (blk < 160) wprep_one<128,  64>(w0,  p0,  (blk - 128) * 256 + t);
    else if (blk < 224) wprep_one<128, 128>(w1,  p1,  (blk - 160) * 256 + t);
    else if (blk < 256) wprep_one<128,  64>(wpp2, pp2, (blk - 224) * 256 + t);
    else                wprep32_one(w1e, p1e, (blk - 256) * 256 + t);
}

// ---------------- enc1 as MFMA: h1 = relu(bf16(x) @ W1 + b1), bf16 out -----
__global__ __launch_bounds__(256, 4) void mfma_enc1(
    const float* __restrict__ x, const unsigned short* __restrict__ Wp,
    const float* __restrict__ bias, unsigned short* __restrict__ C, int M)
{
    __shared__ unsigned short As[64][40];       // 40-pad: 80B rows, 16B-aligned
    __shared__ unsigned short Wls[16 * 512];    // 16 KB = 1024 uint4

    int t = threadIdx.x, wave = t >> 6, lane = t & 63;
    int m0 = blockIdx.x * 64;

    {   // stage A: 64 rows x 32 k, fp32 -> bf16 (8 floats/thread)
        int row = t >> 2, seg = t & 3;
        int gr = m0 + row;
        float4 a = make_float4(0.f, 0.f, 0.f, 0.f), b = a;
        if (gr < M) {
            a = *(const float4*)&x[(size_t)gr * 32 + seg * 8];
            b = *(const float4*)&x[(size_t)gr * 32 + seg * 8 + 4];
        }
        unsigned short tmp[8] = { f2bf(a.x), f2bf(a.y), f2bf(a.z), f2bf(a.w),
                                  f2bf(b.x), f2bf(b.y), f2bf(b.z), f2bf(b.w) };
        *(uint4*)&As[row][seg * 8] = *(uint4*)tmp;
    }
    // stage ALL of Wls: 1024 uint4 (R13 bug: only 512 copied -> NaN)
    #pragma unroll
    for (int j = 0; j < 4; ++j)
        ((uint4*)Wls)[t + j * 256] = ((const uint4*)Wp)[t + j * 256];
    __syncthreads();

    short8_t af = *(const short8_t*)&As[wave * 16 + (lane & 15)][(lane >> 4) * 8];
    f32x4 acc[16];
    #pragma unroll
    for (int nt = 0; nt < 16; ++nt) {
        short8_t bf = *(const short8_t*)&Wls[(nt * 64 + lane) * 8];
        acc[nt] = __builtin_amdgcn_mfma_f32_16x16x32_bf16(af, bf, (f32x4){0.f, 0.f, 0.f, 0.f}, 0, 0, 0);
    }

    int cb = lane & 15, rq = lane >> 4;
    #pragma unroll
    for (int nt = 0; nt < 16; ++nt) {
        int col = nt * 16 + cb;
        float bv = bias[col];
        #pragma unroll
        for (int r = 0; r < 4; ++r) {
            int gr = m0 + wave * 16 + rq * 4 + r;
            if (gr < M) C[(size_t)gr * 256 + col] = f2bf(fmaxf(acc[nt][r] + bv, 0.f));
        }
    }
}

// ---------------- bf16 MFMA GEMM ----------------
template<int NTOT, int KTOT, bool GATHER, bool BIAS_RELU, int OUTT>
__device__ __forceinline__ void mfma_gemm_body(
    const unsigned short* __restrict__ A, const unsigned short* __restrict__ Wp,
    const float* __restrict__ bias, const float* __restrict__ dinv,
    void* __restrict__ Cout, const int* __restrict__ gidx, int M)
{
    constexpr int NT16 = NTOT / 16;
    constexpr int NCH  = KTOT / 64;
    __shared__ unsigned short As[64][72];
    __shared__ unsigned short Wls[NT16 * 1024];

    int t = threadIdx.x, wave = t >> 6, lane = t & 63;
    int m0 = blockIdx.x * 64;

    f32x4 acc[NT16];
    #pragma unroll
    for (int nt = 0; nt < NT16; ++nt) acc[nt] = (f32x4){0.f, 0.f, 0.f, 0.f};

    for (int ch = 0; ch < NCH; ++ch) {
        #pragma unroll
        for (int j = 0; j < 2; ++j) {
            int idx = t + j * 256;
            int row = idx >> 3, seg = idx & 7;
            int gr = m0 + row;
            uint4 v = make_uint4(0u, 0u, 0u, 0u);
            if (gr < M) {
                const unsigned short* src;
                if (GATHER) {
                    int node = (ch == 0) ? gidx[gr] : gidx[N_EL + gr];
                    src = A + (size_t)node * 64 + seg * 8;
                } else {
                    src = A + (size_t)gr * KTOT + ch * 64 + seg * 8;
                }
                v = *(const uint4*)src;
            }
            *(uint4*)&As[row][seg * 8] = v;
        }
        constexpr int WL16 = NT16 * 128;            // uint4 count
        #pragma unroll
        for (int j = 0; j < WL16 / 256; ++j) {
            int idx = t + j * 256;
            ((uint4*)Wls)[idx] = ((const uint4*)(Wp + (size_t)ch * NT16 * 1024))[idx];
        }
        __syncthreads();

        #pragma unroll
        for (int ks = 0; ks < 2; ++ks) {
            short8_t af = *(const short8_t*)&As[wave * 16 + (lane & 15)][ks * 32 + (lane >> 4) * 8];
            #pragma unroll
            for (int nt = 0; nt < NT16; ++nt) {
                short8_t bf = *(const short8_t*)&Wls[((nt * 2 + ks) * 64 + lane) * 8];
                acc[nt] = __builtin_amdgcn_mfma_f32_16x16x32_bf16(af, bf, acc[nt], 0, 0, 0);
            }
        }
        __syncthreads();
    }

    int cb = lane & 15, rq = lane >> 4;
    #pragma unroll
    for (int nt = 0; nt < NT16; ++nt) {
        int col = nt * 16 + cb;
        float bv = BIAS_RELU ? bias[col] : 0.f;
        #pragma unroll
        for (int r = 0; r < 4; ++r) {
            int gr = m0 + wave * 16 + rq * 4 + r;
            if (gr < M) {
                float val;
                if (BIAS_RELU) val = fmaxf(acc[nt][r] + bv, 0.f);
                else           val = acc[nt][r] * dinv[gr];
                size_t o = (size_t)gr * NTOT + col;
                if (OUTT == 1)      ((unsigned short*)Cout)[o] = f2bf(val);
                else if (OUTT == 2) ((_Float16*)Cout)[o] = (_Float16)val;
                else                ((float*)Cout)[o] = val;
            }
        }
    }
}

__global__ __launch_bounds__(256, 4) void mfma_enc2(const unsigned short* A, const unsigned short* Wp,
                                                    const float* b, unsigned short* C, int M) {
    mfma_gemm_body<128, 256, false, true, 1>(A, Wp, b, nullptr, C, nullptr, M);
}
__global__ __launch_bounds__(256, 4) void mfma_conv0(const unsigned short* A, const unsigned short* Wp,
                                                     const float* dinv, _Float16* C, int M) {
    mfma_gemm_body<64, 128, false, false, 2>(A, Wp, nullptr, dinv, C, nullptr, M);
}
__global__ __launch_bounds__(256, 4) void mfma_ep1(const unsigned short* A, const unsigned short* Wp,
                                                   const float* b, unsigned short* C, const int* gidx, int M) {
    mfma_gemm_body<128, 128, true, true, 1>(A, Wp, b, nullptr, C, gidx, M);
}

// ---------------- ep2 fused with ep3: sigmoid(relu(e1@W2+b2) . w3 + b3) -----
__global__ __launch_bounds__(256, 4) void mfma_ep2f(
    const unsigned short* __restrict__ A, const unsigned short* __restrict__ Wp,
    const float* __restrict__ b2, const float* __restrict__ w3,
    const float* __restrict__ b3, float* __restrict__ out, int M)
{
    constexpr int NT16 = 4;
    __shared__ unsigned short As[64][72];
    __shared__ unsigned short Wls[NT16 * 1024];

    int t = threadIdx.x, wave = t >> 6, lane = t & 63;
    int m0 = blockIdx.x * 64;

    f32x4 acc[NT16];
    #pragma unroll
    for (int nt = 0; nt < NT16; ++nt) acc[nt] = (f32x4){0.f, 0.f, 0.f, 0.f};

    for (int ch = 0; ch < 2; ++ch) {
        #pragma unroll
        for (int j = 0; j < 2; ++j) {
            int idx = t + j * 256;
            int row = idx >> 3, seg = idx & 7;
            int gr = m0 + row;
            uint4 v = make_uint4(0u, 0u, 0u, 0u);
            if (gr < M) v = *(const uint4*)(A + (size_t)gr * 128 + ch * 64 + seg * 8);
            *(uint4*)&As[row][seg * 8] = v;
        }
        #pragma unroll
        for (int j = 0; j < 2; ++j) {
            int idx = t + j * 256;
            ((uint4*)Wls)[idx] = ((const uint4*)(Wp + (size_t)ch * NT16 * 1024))[idx];
        }
        __syncthreads();

        #pragma unroll
        for (int ks = 0; ks < 2; ++ks) {
            short8_t af = *(const short8_t*)&As[wave * 16 + (lane & 15)][ks * 32 + (lane >> 4) * 8];
            #pragma unroll
            for (int nt = 0; nt < NT16; ++nt) {
                short8_t bf = *(const short8_t*)&Wls[((nt * 2 + ks) * 64 + lane) * 8];
                acc[nt] = __builtin_amdgcn_mfma_f32_16x16x32_bf16(af, bf, acc[nt], 0, 0, 0);
            }
        }
        __syncthreads();
    }

    int cb = lane & 15, rq = lane >> 4;
    float s0 = 0.f, s1 = 0.f, s2 = 0.f, s3 = 0.f;
    #pragma unroll
    for (int nt = 0; nt < NT16; ++nt) {
        int col = nt * 16 + cb;
        float bv = b2[col], wv = w3[col];
        s0 += fmaxf(acc[nt][0] + bv, 0.f) * wv;
        s1 += fmaxf(acc[nt][1] + bv, 0.f) * wv;
        s2 += fmaxf(acc[nt][2] + bv, 0.f) * wv;
        s3 += fmaxf(acc[nt][3] + bv, 0.f) * wv;
    }
    #pragma unroll
    for (int off = 1; off < 16; off <<= 1) {
        s0 += __shfl_xor(s0, off);
        s1 += __shfl_xor(s1, off);
        s2 += __shfl_xor(s2, off);
        s3 += __shfl_xor(s3, off);
    }
    if (cb == 0) {
        int gr = m0 + wave * 16 + rq * 4;
        if (gr + 3 < M) {
            float bb = b3[0];
            float4 o;
            o.x = 1.f / (1.f + expf(-(s0 + bb)));
            o.y = 1.f / (1.f + expf(-(s1 + bb)));
            o.z = 1.f / (1.f + expf(-(s2 + bb)));
            o.w = 1.f / (1.f + expf(-(s3 + bb)));
            *(float4*)&out[gr] = o;
        }
    }
}

// ---------------- fp32 tiled GEMM (conv1/2): y = f16(dinv .* (A@W)) ---------
template<int KTOT>
__device__ __forceinline__ void gemm_body(
    const float* __restrict__ A, const float* __restrict__ W,
    _Float16* __restrict__ C, const float* __restrict__ dinv, int M)
{
    constexpr int KB = 32;
    constexpr int NC = 64;
    __shared__ float As[KB][68];
    __shared__ float Ws[KB][64];

    int t  = threadIdx.x;
    int m0 = blockIdx.x * 64;
    int tx = t & 15, ty = t >> 4;

    float acc[4][4];
    #pragma unroll
    for (int r = 0; r < 4; ++r)
        #pragma unroll
        for (int c = 0; c < 4; ++c) acc[r][c] = 0.f;

    for (int k0 = 0; k0 < KTOT; k0 += KB) {
        #pragma unroll
        for (int j = 0; j < 2; ++j) {
            int idx = t + j * 256;
            int row = idx >> 3, kf = idx & 7;
            int gr  = m0 + row;
            float4 v = make_float4(0.f, 0.f, 0.f, 0.f);
            if (gr < M) v = *(const float4*)&A[(size_t)gr * KTOT + k0 + kf * 4];
            As[kf * 4 + 0][row] = v.x; As[kf * 4 + 1][row] = v.y;
            As[kf * 4 + 2][row] = v.z; As[kf * 4 + 3][row] = v.w;
        }
        #pragma unroll
        for (int j = 0; j < 2; ++j) {
            int idx = t + j * 256;
            int kk = idx >> 4, cf = idx & 15;
            *(float4*)&Ws[kk][cf * 4] = *(const float4*)&W[(size_t)(k0 + kk) * NC + cf * 4];
        }
        __syncthreads();

        #pragma unroll
        for (int kk = 0; kk < KB; ++kk) {
            float4 a4 = *(const float4*)&As[kk][ty * 4];
            float4 w4 = *(const float4*)&Ws[kk][tx * 4];
            acc[0][0] += a4.x * w4.x; acc[0][1] += a4.x * w4.y;
            acc[0][2] += a4.x * w4.z; acc[0][3] += a4.x * w4.w;
            acc[1][0] += a4.y * w4.x; acc[1][1] += a4.y * w4.y;
            acc[1][2] += a4.y * w4.z; acc[1][3] += a4.y * w4.w;
            acc[2][0] += a4.z * w4.x; acc[2][1] += a4.z * w4.y;
            acc[2][2] += a4.z * w4.z; acc[2][3] += a4.z * w4.w;
            acc[3][0] += a4.w * w4.x; acc[3][1] += a4.w * w4.y;
            acc[3][2] += a4.w * w4.z; acc[3][3] += a4.w * w4.w;
        }
        __syncthreads();
    }

    #pragma unroll
    for (int r = 0; r < 4; ++r) {
        int gr = m0 + ty * 4 + r;
        if (gr < M) {
            float s = dinv[gr];
            _Float16 tmp[4];
            tmp[0] = (_Float16)(acc[r][0] * s);
            tmp[1] = (_Float16)(acc[r][1] * s);
            tmp[2] = (_Float16)(acc[r][2] * s);
            tmp[3] = (_Float16)(acc[r][3] * s);
            *(uint2*)&C[(size_t)gr * NC + tx * 4] = *(uint2*)tmp;
        }
    }
}

__global__ __launch_bounds__(256, 4) void gemm_conv1(const float* A, const float* W, _Float16* C, const float* dinv, int M) {
    gemm_body<64>(A, W, C, dinv, M);
}
__global__ __launch_bounds__(256, 4) void gemm_conv2(const float* A, const float* W, _Float16* C, const float* dinv, int M) {
    gemm_body<64>(A, W, C, dinv, M);
}

// ---------------- CSR aggregation (8 nodes/wave, uint4 = 8 f16/lane) --------
template<bool RESIDUAL, int OUTM>
__device__ __forceinline__ void agg_body(
    const uint4* __restrict__ y4, const int* __restrict__ row_ptr, const int* __restrict__ col,
    const float* __restrict__ dinv, const float* __restrict__ bias,
    const float* __restrict__ hprev, float* __restrict__ hout,
    uint4* __restrict__ hb4)
{
    int v  = blockIdx.x * 32 + (threadIdx.x >> 3);
    int sl = threadIdx.x & 7;
    if (v >= N_NODES) return;

    uint4 a = y4[(size_t)v * 8 + sl];              // self loop
    float2 p0 = up16(a.x), p1 = up16(a.y), p2 = up16(a.z), p3 = up16(a.w);
    float s0 = p0.x, s1 = p0.y, s2 = p1.x, s3 = p1.y;
    float s4 = p2.x, s5 = p2.y, s6 = p3.x, s7 = p3.y;

    int s = row_ptr[v], e = row_ptr[v + 1];
    int i = s;
    for (; i + 3 < e; i += 4) {
        int u0 = col[i], u1 = col[i + 1], u2 = col[i + 2], u3 = col[i + 3];
        uint4 f0 = y4[(size_t)u0 * 8 + sl];
        uint4 f1 = y4[(size_t)u1 * 8 + sl];
        uint4 f2 = y4[(size_t)u2 * 8 + sl];
        uint4 f3 = y4[(size_t)u3 * 8 + sl];
        float2 g;
        g = up16(f0.x); s0 += g.x; s1 += g.y;  g = up16(f0.y); s2 += g.x; s3 += g.y;
        g = up16(f0.z); s4 += g.x; s5 += g.y;  g = up16(f0.w); s6 += g.x; s7 += g.y;
        g = up16(f1.x); s0 += g.x; s1 += g.y;  g = up16(f1.y); s2 += g.x; s3 += g.y;
        g = up16(f1.z); s4 += g.x; s5 += g.y;  g = up16(f1.w); s6 += g.x; s7 += g.y;
        g = up16(f2.x); s0 += g.x; s1 += g.y;  g = up16(f2.y); s2 += g.x; s3 += g.y;
        g = up16(f2.z); s4 += g.x; s5 += g.y;  g = up16(f2.w); s6 += g.x; s7 += g.y;
        g = up16(f3.x); s0 += g.x; s1 += g.y;  g = up16(f3.y); s2 += g.x; s3 += g.y;
        g = up16(f3.z); s4 += g.x; s5 += g.y;  g = up16(f3.w); s6 += g.x; s7 += g.y;
    }
    for (; i < e; ++i) {
        uint4 f = y4[(size_t)col[i] * 8 + sl];
        float2 g;
        g = up16(f.x); s0 += g.x; s1 += g.y;  g = up16(f.y); s2 += g.x; s3 += g.y;
        g = up16(f.z); s4 += g.x; s5 += g.y;  g = up16(f.w); s6 += g.x; s7 += g.y;
    }

    float dv = dinv[v];
    float4 ba = *(const float4*)&bias[sl * 8];
    float4 bb = *(const float4*)&bias[sl * 8 + 4];
    float v0 = fmaxf(dv * s0 + ba.x, 0.f), v1 = fmaxf(dv * s1 + ba.y, 0.f);
    float v2 = fmaxf(dv * s2 + ba.z, 0.f), v3 = fmaxf(dv * s3 + ba.w, 0.f);
    float v4 = fmaxf(dv * s4 + bb.x, 0.f), v5 = fmaxf(dv * s5 + bb.y, 0.f);
    float v6 = fmaxf(dv * s6 + bb.z, 0.f), v7 = fmaxf(dv * s7 + bb.w, 0.f);
    if (RESIDUAL) {
        float4 h0 = *(const float4*)&hprev[(size_t)v * 64 + sl * 8];
        float4 h1 = *(const float4*)&hprev[(size_t)v * 64 + sl * 8 + 4];
        v0 += h0.x; v1 += h0.y; v2 += h0.z; v3 += h0.w;
        v4 += h1.x; v5 += h1.y; v6 += h1.z; v7 += h1.w;
    }
    if (OUTM == 2) {
        uint4 p;
        p.x = (unsigned)f2bf(v0) | ((unsigned)f2bf(v1) << 16);
        p.y = (unsigned)f2bf(v2) | ((unsigned)f2bf(v3) << 16);
        p.z = (unsigned)f2bf(v4) | ((unsigned)f2bf(v5) << 16);
        p.w = (unsigned)f2bf(v6) | ((unsigned)f2bf(v7) << 16);
        hb4[(size_t)v * 8 + sl] = p;
    } else {
        *(float4*)&hout[(size_t)v * 64 + sl * 8]     = make_float4(v0, v1, v2, v3);
        *(float4*)&hout[(size_t)v * 64 + sl * 8 + 4] = make_float4(v4, v5, v6, v7);
    }
}

__global__ __launch_bounds__(256) void agg0_kernel(const uint4* y, const int* rp, const int* col,
                                                   const float* dinv, const float* b, float* h) {
    agg_body<false, 0>(y, rp, col, dinv, b, nullptr, h, nullptr);
}
__global__ __launch_bounds__(256) void agg1_kernel(const uint4* y, const int* rp, const int* col,
                                                   const float* dinv, const float* b, float* h) {
    agg_body<true, 1>(y, rp, col, dinv, b, h, h, nullptr);   // in-place: group owns its row
}
__global__ __launch_bounds__(256) void agg2_kernel(const uint4* y, const int* rp, const int* col,
                                                   const float* dinv, const float* b,
                                                   const float* hprev, uint4* hb) {
    agg_body<true, 2>(y, rp, col, dinv, b, hprev, nullptr, hb);
}

extern "C" void kernel_launch(void* const* d_in, const int* in_sizes, int n_in,
                              void* d_out, int out_size, void* d_ws, size_t ws_size,
                              hipStream_t stream) {
    const float* x       = (const float*)d_in[0];
    const int*   ei      = (const int*)d_in[1];
    const int*   eli     = (const int*)d_in[2];
    const float* enc_w1  = (const float*)d_in[3];
    const float* enc_b1  = (const float*)d_in[4];
    const float* enc_w2  = (const float*)d_in[5];
    const float* enc_b2  = (const float*)d_in[6];
    const float* conv_w0 = (const float*)d_in[7];
    const float* conv_b0 = (const float*)d_in[8];
    const float* conv_w1 = (const float*)d_in[9];
    const float* conv_b1 = (const float*)d_in[10];
    const float* conv_w2 = (const float*)d_in[11];
    const float* conv_b2 = (const float*)d_in[12];
    const float* ep_w1   = (const float*)d_in[13];
    const float* ep_b1   = (const float*)d_in[14];
    const float* ep_w2   = (const float*)d_in[15];
    const float* ep_b2   = (const float*)d_in[16];
    const float* ep_w3   = (const float*)d_in[17];
    const float* ep_b3   = (const float*)d_in[18];
    float* out = (float*)d_out;

    // ---- workspace layout (float offsets) ----
    float* fws = (float*)d_ws;
    unsigned short* h1b  = (unsigned short*)fws;                 // bf16 [100k,256] = 12.8M f
    unsigned short* e1b  = (unsigned short*)(fws + 12800000);    // bf16 [200k,128] = 12.8M f
    unsigned short* h128b= e1b;                                  // alias: bf16 [100k,128] (dead before ep1)
    _Float16* yb         = (_Float16*)(fws + 25600000);          // f16 [100k,64] = 3.2M f
    float* h64           = fws + 28800000;                       // f32 [100k,64] = 6.4M f
    unsigned short* h64b = (unsigned short*)(fws + 35200000);    // bf16 [100k,64] = 3.2M f
    int*   col     = (int*)(fws + 38400000);                     // 1.6M i
    int*   row_ptr = col + 1600000;                              // 100001 (padded)
    float* dinvp   = (float*)(row_ptr + 100032);
    unsigned short* w2p = (unsigned short*)(dinvp + 100000);     // enc_w2: 32768 us
    unsigned short* w0p = w2p + 32768;                           // conv_w0: 8192 us
    unsigned short* w1p = w0p + 8192;                            // ep_w1: 16384 us
    unsigned short* wp2 = w1p + 16384;                           // ep_w2: 8192 us
    unsigned short* w1e = wp2 + 8192;                            // enc_w1: 8192 us
    int*   btail   = (int*)(w1e + 8192);                         // 98 i (+pad to 128)
    int*   bscr    = btail + 128;                                // 98*24576 = 2.41M i

    // ---- CSR build + weight swizzle (no global atomics anywhere) ----
    hipMemsetAsync(btail, 0, 128 * sizeof(int), stream);
    fill_part<<<PART_NB, 256, 0, stream>>>(ei, btail, bscr);
    wprep_all<<<288, 256, 0, stream>>>(enc_w2, conv_w0, ep_w1, ep_w2, enc_w1,
                                       w2p, w0p, w1p, wp2, w1e);
    fill_place<<<KBUCK, 1024, 0, stream>>>(btail, bscr, row_ptr, dinvp, col);

    const int GBN = (N_NODES + 63) / 64;   // 1563
    const int GBE = N_EL / 64;             // 3125
    const int GBA = (N_NODES + 31) / 32;   // 3125

    // ---- encoder (both MFMA) ----
    mfma_enc1<<<GBN, 256, 0, stream>>>(x, w1e, enc_b1, h1b, N_NODES);
    mfma_enc2<<<GBN, 256, 0, stream>>>(h1b, w2p, enc_b2, h128b, N_NODES);

    // ---- GCN layer 0: 128 -> 64 (MFMA, bf16 in, f16 y out) ----
    mfma_conv0<<<GBN, 256, 0, stream>>>(h128b, w0p, dinvp, yb, N_NODES);
    agg0_kernel<<<GBA, 256, 0, stream>>>((const uint4*)yb, row_ptr, col, dinvp, conv_b0, h64);

    // ---- GCN layer 1: 64 -> 64, residual ----
    gemm_conv1<<<GBN, 256, 0, stream>>>(h64, conv_w1, yb, dinvp, N_NODES);
    agg1_kernel<<<GBA, 256, 0, stream>>>((const uint4*)yb, row_ptr, col, dinvp, conv_b1, h64);

    // ---- GCN layer 2: 64 -> 64, residual, bf16 out for ep1 ----
    gemm_conv2<<<GBN, 256, 0, stream>>>(h64, conv_w2, yb, dinvp, N_NODES);
    agg2_kernel<<<GBA, 256, 0, stream>>>((const uint4*)yb, row_ptr, col, dinvp, conv_b2, h64, (uint4*)h64b);

    // ---- edge predictor (bf16 MFMA; ep2+ep3 fused) ----
    mfma_ep1<<<GBE, 256, 0, stream>>>(h64b, w1p, ep_b1, e1b, eli, N_EL);
    mfma_ep2f<<<GBE, 256, 0, stream>>>(e1b, wp2, ep_b2, ep_w3, ep_b3, out, N_EL);
}

// Round 15
// 360.155 us; speedup vs baseline: 1.7435x; 1.0691x over previous
//
#include <hip/hip_runtime.h>
#include <math.h>

// ---------------------------------------------------------------------------
// EmergencyGNNEnhanced: encoder (32->256->128) -> 3x GCN (->64) -> edge MLP.
// CSR built on-device each call. agg[v] = dinv[v]*(sum_{u->v} y[u] + y[v]).
//
// R15: (a) ep1+ep2+ep3 fused into mfma_ep12 -- ep1's 64-row block computes
// all 128 e1 cols, so e1 round-trips through LDS (stage1 As+W1 = stage2
// E1+W2 = 25.6KB, aliased) instead of 100MB of HBM. (b) conv1/conv2 now
// MFMA: aggs emit bf16 h64b each layer (residual chain stays fp32 in h64).
// MFMA layouts HW-verified (R5-R14 passed).
// ---------------------------------------------------------------------------

#define N_NODES 100000
#define N_EDGES 1600000
#define N_EL    200000

#define KBUCK   98           // ceil(100000/1024) windows of 1024 nodes
#define WSHIFT  10
#define WMASK   1023
#define BCAP    128          // LDS entries/bucket in pass A (chunk avg 32)
#define BSTRIDE 24576        // scratch ints per bucket (seglen ~16.4k avg)
#define PART_NB 512
#define CHUNK   3125         // ceil(N_EDGES / PART_NB)
#define LCAP    20480        // pass-B LDS staging (seglen max ~17k)

typedef __attribute__((ext_vector_type(8))) short short8_t;
typedef __attribute__((ext_vector_type(4))) float f32x4;

__device__ __forceinline__ unsigned short f2bf(float f) {
    unsigned u = __float_as_uint(f);
    unsigned r = u + 0x7FFFu + ((u >> 16) & 1u);   // RNE
    return (unsigned short)(r >> 16);
}

__device__ __forceinline__ float2 up16(unsigned u) {
    union { unsigned v; _Float16 h[2]; } c; c.v = u;
    return make_float2((float)c.h[0], (float)c.h[1]);
}

// ---- fill pass A: partition edges into 98 dst-window buckets ----
__global__ __launch_bounds__(256) void fill_part(const int* __restrict__ ei,
                                                 int* __restrict__ btail, int* __restrict__ bscr) {
    __shared__ int lbuf[KBUCK][BCAP];     // 50 KB
    __shared__ int lcnt[KBUCK];
    __shared__ int offs[KBUCK + 1];
    __shared__ int gbase[KBUCK];
    int t = threadIdx.x;
    for (int i = t; i < KBUCK; i += 256) lcnt[i] = 0;
    __syncthreads();

    int e0   = blockIdx.x * CHUNK;
    int eend = e0 + CHUNK; if (eend > N_EDGES) eend = N_EDGES;
    for (int e = e0 + t; e < eend; e += 256) {
        int s = __builtin_nontemporal_load(ei + e);
        int d = __builtin_nontemporal_load(ei + N_EDGES + e);
        int b = d >> WSHIFT;
        int entry = ((d & WMASK) << 17) | s;
        int pos = atomicAdd(&lcnt[b], 1);
        if (pos < BCAP) lbuf[b][pos] = entry;
        else {                                  // statistical-skew spill (rare)
            int p = atomicAdd(&btail[b], 1);
            bscr[b * BSTRIDE + p] = entry;
        }
    }
    __syncthreads();

    if (t < KBUCK) {
        int c = lcnt[t]; if (c > BCAP) c = BCAP;
        lcnt[t] = c;
        gbase[t] = atomicAdd(&btail[t], c);
    }
    __syncthreads();
    if (t == 0) {
        offs[0] = 0;
        for (int b = 0; b < KBUCK; ++b) offs[b + 1] = offs[b] + lcnt[b];
    }
    __syncthreads();

    int T = offs[KBUCK];
    for (int i = t; i < T; i += 256) {
        int loB = 0, hiB = KBUCK;               // binary search bucket
        while (hiB - loB > 1) { int mid = (loB + hiB) >> 1; if (offs[mid] <= i) loB = mid; else hiB = mid; }
        int j = i - offs[loB];
        bscr[loB * BSTRIDE + gbase[loB] + j] = lbuf[loB][j];
    }
}

// ---- fill_place: btail prefix + hist + local scan + row_ptr/dinv + scatter ----
__global__ __launch_bounds__(1024) void fill_place(const int* __restrict__ btail,
                                                   const int* __restrict__ bscr,
                                                   int* __restrict__ row_ptr, float* __restrict__ dinv,
                                                   int* __restrict__ col) {
    __shared__ int ssm[128];
    __shared__ int lcnt[1024];
    __shared__ int lpre[1024];
    __shared__ int lbuf[LCAP];                  // 80 KB
    int b = blockIdx.x, t = threadIdx.x;

    if (t < 128) ssm[t] = (t < KBUCK) ? btail[t] : 0;
    lcnt[t] = 0;
    __syncthreads();
    for (int s = 1; s < 128; s <<= 1) {         // inclusive scan of btail
        int a = 0;
        if (t < 128 && t >= s) a = ssm[t - s];
        __syncthreads();
        if (t < 128) ssm[t] += a;
        __syncthreads();
    }
    int segstart = (b == 0) ? 0 : ssm[b - 1];
    int n = btail[b];
    const int* src = bscr + b * BSTRIDE;
    for (int i = t; i < n; i += 1024)
        atomicAdd(&lcnt[src[i] >> 17], 1);
    __syncthreads();

    int c = lcnt[t];
    lpre[t] = c; __syncthreads();
    for (int s = 1; s < 1024; s <<= 1) {        // inclusive scan
        int a = (t >= s) ? lpre[t - s] : 0;
        __syncthreads();
        lpre[t] += a;
        __syncthreads();
    }
    int excl = lpre[t] - c;

    int v = (b << WSHIFT) + t;
    if (v < N_NODES) {
        row_ptr[v] = segstart + excl;
        dinv[v] = rsqrtf((float)(c + 1));       // +1 self loop
    }
    if (b == KBUCK - 1 && t == 0) row_ptr[N_NODES] = N_EDGES;
    lcnt[t] = excl;                             // reuse as cursor
    __syncthreads();

    if (n <= LCAP) {
        for (int i = t; i < n; i += 1024) {
            int e = src[i];
            int pos = atomicAdd(&lcnt[e >> 17], 1);
            lbuf[pos] = e & 0x1FFFF;
        }
        __syncthreads();
        for (int i = t; i < n; i += 1024)
            col[segstart + i] = lbuf[i];
    } else {                                    // safety fallback (never for this dist)
        for (int i = t; i < n; i += 1024) {
            int e = src[i];
            int pos = atomicAdd(&lcnt[e >> 17], 1);
            col[segstart + pos] = e & 0x1FFFF;
        }
    }
}

// ---------------- weight swizzle: fp32 W[K][N] -> bf16 B-fragment order -----
template<int KTOT, int NTOT>
__device__ __forceinline__ void wprep_one(const float* __restrict__ W, unsigned short* __restrict__ Wp, int flat) {
    if (flat >= KTOT * NTOT) return;
    int j = flat & 7, lane = (flat >> 3) & 63, kstep = (flat >> 9) & 1;
    int rest = flat >> 10;
    int ntile = rest % (NTOT / 16), chunk = rest / (NTOT / 16);
    int k = chunk * 64 + kstep * 32 + (lane >> 4) * 8 + j;
    int n = ntile * 16 + (lane & 15);
    Wp[flat] = f2bf(W[(size_t)k * NTOT + n]);
}

// K=32 variant (single k-step) for enc_w1 [32 x 256]
__device__ __forceinline__ void wprep32_one(const float* __restrict__ W, unsigned short* __restrict__ Wp, int flat) {
    if (flat >= 32 * 256) return;
    int j = flat & 7, lane = (flat >> 3) & 63, ntile = flat >> 9;   // 0..15
    int k = (lane >> 4) * 8 + j;
    int n = ntile * 16 + (lane & 15);
    Wp[flat] = f2bf(W[(size_t)k * 256 + n]);
}

// One dispatch for all 7 weight swizzles (320 blocks).
__global__ __launch_bounds__(256) void wprep_all(
    const float* w2, const float* w0, const float* w1, const float* wpp2, const float* w1e,
    const float* wc1, const float* wc2,
    unsigned short* p2, unsigned short* p0, unsigned short* p1, unsigned short* pp2,
    unsigned short* p1e, unsigned short* pc1, unsigned short* pc2)
{
    int blk = blockIdx.x, t = threadIdx.x;
    if      (blk < 128) wprep_one<256, 128>(w2,  p2,  blk * 256 + t);
    else if (blk < 160) wprep_one<128,  64>(w0,  p0,  (blk - 128) * 256 + t);
    else if (blk < 224) wprep_one<128, 128>(w1,  p1,  (blk - 160) * 256 + t);
    else if (blk < 256) wprep_one<128,  64>(wpp2, pp2, (blk - 224) * 256 + t);
    else if (blk < 288) wprep32_one(w1e, p1e, (blk - 256) * 256 + t);
    else if (blk < 304) wprep_one< 64,  64>(wc1, pc1, (blk - 288) * 256 + t);
    else                wprep_one< 64,  64>(wc2, pc2, (blk - 304) * 256 + t);
}

// ---------------- enc1 as MFMA: h1 = relu(bf16(x) @ W1 + b1), bf16 out -----
__global__ __launch_bounds__(256, 4) void mfma_enc1(
    const float* __restrict__ x, const unsigned short* __restrict__ Wp,
    const float* __restrict__ bias, unsigned short* __restrict__ C, int M)
{
    __shared__ unsigned short As[64][40];       // 40-pad: 80B rows, 16B-aligned
    __shared__ unsigned short Wls[16 * 512];    // 16 KB = 1024 uint4

    int t = threadIdx.x, wave = t >> 6, lane = t & 63;
    int m0 = blockIdx.x * 64;

    {   // stage A: 64 rows x 32 k, fp32 -> bf16 (8 floats/thread)
        int row = t >> 2, seg = t & 3;
        int gr = m0 + row;
        float4 a = make_float4(0.f, 0.f, 0.f, 0.f), b = a;
        if (gr < M) {
            a = *(const float4*)&x[(size_t)gr * 32 + seg * 8];
            b = *(const float4*)&x[(size_t)gr * 32 + seg * 8 + 4];
        }
        unsigned short tmp[8] = { f2bf(a.x), f2bf(a.y), f2bf(a.z), f2bf(a.w),
                                  f2bf(b.x), f2bf(b.y), f2bf(b.z), f2bf(b.w) };
        *(uint4*)&As[row][seg * 8] = *(uint4*)tmp;
    }
    #pragma unroll
    for (int j = 0; j < 4; ++j)
        ((uint4*)Wls)[t + j * 256] = ((const uint4*)Wp)[t + j * 256];
    __syncthreads();

    short8_t af = *(const short8_t*)&As[wave * 16 + (lane & 15)][(lane >> 4) * 8];
    f32x4 acc[16];
    #pragma unroll
    for (int nt = 0; nt < 16; ++nt) {
        short8_t bf = *(const short8_t*)&Wls[(nt * 64 + lane) * 8];
        acc[nt] = __builtin_amdgcn_mfma_f32_16x16x32_bf16(af, bf, (f32x4){0.f, 0.f, 0.f, 0.f}, 0, 0, 0);
    }

    int cb = lane & 15, rq = lane >> 4;
    #pragma unroll
    for (int nt = 0; nt < 16; ++nt) {
        int col = nt * 16 + cb;
        float bv = bias[col];
        #pragma unroll
        for (int r = 0; r < 4; ++r) {
            int gr = m0 + wave * 16 + rq * 4 + r;
            if (gr < M) C[(size_t)gr * 256 + col] = f2bf(fmaxf(acc[nt][r] + bv, 0.f));
        }
    }
}

// ---------------- bf16 MFMA GEMM ----------------
template<int NTOT, int KTOT, bool BIAS_RELU, int OUTT>
__device__ __forceinline__ void mfma_gemm_body(
    const unsigned short* __restrict__ A, const unsigned short* __restrict__ Wp,
    const float* __restrict__ bias, const float* __restrict__ dinv,
    void* __restrict__ Cout, int M)
{
    constexpr int NT16 = NTOT / 16;
    constexpr int NCH  = KTOT / 64;
    __shared__ unsigned short As[64][72];
    __shared__ unsigned short Wls[NT16 * 1024];

    int t = threadIdx.x, wave = t >> 6, lane = t & 63;
    int m0 = blockIdx.x * 64;

    f32x4 acc[NT16];
    #pragma unroll
    for (int nt = 0; nt < NT16; ++nt) acc[nt] = (f32x4){0.f, 0.f, 0.f, 0.f};

    for (int ch = 0; ch < NCH; ++ch) {
        #pragma unroll
        for (int j = 0; j < 2; ++j) {
            int idx = t + j * 256;
            int row = idx >> 3, seg = idx & 7;
            int gr = m0 + row;
            uint4 v = make_uint4(0u, 0u, 0u, 0u);
            if (gr < M) v = *(const uint4*)(A + (size_t)gr * KTOT + ch * 64 + seg * 8);
            *(uint4*)&As[row][seg * 8] = v;
        }
        constexpr int WL16 = NT16 * 128;            // uint4 count
        #pragma unroll
        for (int j = 0; j < WL16 / 256; ++j) {
            int idx = t + j * 256;
            ((uint4*)Wls)[idx] = ((const uint4*)(Wp + (size_t)ch * NT16 * 1024))[idx];
        }
        __syncthreads();

        #pragma unroll
        for (int ks = 0; ks < 2; ++ks) {
            short8_t af = *(const short8_t*)&As[wave * 16 + (lane & 15)][ks * 32 + (lane >> 4) * 8];
            #pragma unroll
            for (int nt = 0; nt < NT16; ++nt) {
                short8_t bf = *(const short8_t*)&Wls[((nt * 2 + ks) * 64 + lane) * 8];
                acc[nt] = __builtin_amdgcn_mfma_f32_16x16x32_bf16(af, bf, acc[nt], 0, 0, 0);
            }
        }
        __syncthreads();
    }

    int cb = lane & 15, rq = lane >> 4;
    #pragma unroll
    for (int nt = 0; nt < NT16; ++nt) {
        int col = nt * 16 + cb;
        float bv = BIAS_RELU ? bias[col] : 0.f;
        #pragma unroll
        for (int r = 0; r < 4; ++r) {
            int gr = m0 + wave * 16 + rq * 4 + r;
            if (gr < M) {
                float val;
                if (BIAS_RELU) val = fmaxf(acc[nt][r] + bv, 0.f);
                else           val = acc[nt][r] * dinv[gr];
                size_t o = (size_t)gr * NTOT + col;
                if (OUTT == 1)      ((unsigned short*)Cout)[o] = f2bf(val);
                else if (OUTT == 2) ((_Float16*)Cout)[o] = (_Float16)val;
                else                ((float*)Cout)[o] = val;
            }
        }
    }
}

__global__ __launch_bounds__(256, 4) void mfma_enc2(const unsigned short* A, const unsigned short* Wp,
                                                    const float* b, unsigned short* C, int M) {
    mfma_gemm_body<128, 256, true, 1>(A, Wp, b, nullptr, C, M);
}
__global__ __launch_bounds__(256, 4) void mfma_conv0(const unsigned short* A, const unsigned short* Wp,
                                                     const float* dinv, _Float16* C, int M) {
    mfma_gemm_body<64, 128, false, 2>(A, Wp, nullptr, dinv, C, M);
}
__global__ __launch_bounds__(256, 4) void mfma_conv1(const unsigned short* A, const unsigned short* Wp,
                                                     const float* dinv, _Float16* C, int M) {
    mfma_gemm_body<64, 64, false, 2>(A, Wp, nullptr, dinv, C, M);
}
__global__ __launch_bounds__(256, 4) void mfma_conv2(const unsigned short* A, const unsigned short* Wp,
                                                     const float* dinv, _Float16* C, int M) {
    mfma_gemm_body<64, 64, false, 2>(A, Wp, nullptr, dinv, C, M);
}

// ---------------- fused edge predictor ----------------
// Stage 1 (ep1): e1 = relu(concat(h[a],h[b]) @ W1 + b1)  -- gather, NT16=8, NCH=2
// Stage 2 (ep2+ep3): out = sigmoid(relu(e1@W2+b2).w3 + b3), e1 via LDS.
// LDS aliased: stage1 As[64][72]+W1(16KB) = stage2 E1[64][136]+W2(8KB) = 25600B.
__global__ __launch_bounds__(256, 4) void mfma_ep12(
    const unsigned short* __restrict__ A, const int* __restrict__ gidx,
    const unsigned short* __restrict__ Wp1, const float* __restrict__ b1,
    const unsigned short* __restrict__ Wp2, const float* __restrict__ b2,
    const float* __restrict__ w3, const float* __restrict__ b3,
    float* __restrict__ out, int M)
{
    __shared__ __align__(16) unsigned short smem[12800];    // 25600 B
    unsigned short (*As)[72] = (unsigned short(*)[72])smem;
    unsigned short* Wls = smem + 4608;

    int t = threadIdx.x, wave = t >> 6, lane = t & 63;
    int m0 = blockIdx.x * 64;
    int cb = lane & 15, rq = lane >> 4;

    f32x4 acc[8];
    #pragma unroll
    for (int nt = 0; nt < 8; ++nt) acc[nt] = (f32x4){0.f, 0.f, 0.f, 0.f};

    for (int ch = 0; ch < 2; ++ch) {
        #pragma unroll
        for (int j = 0; j < 2; ++j) {
            int idx = t + j * 256;
            int row = idx >> 3, seg = idx & 7;
            int gr = m0 + row;
            uint4 v = make_uint4(0u, 0u, 0u, 0u);
            if (gr < M) {
                int node = (ch == 0) ? gidx[gr] : gidx[N_EL + gr];
                v = *(const uint4*)(A + (size_t)node * 64 + seg * 8);
            }
            *(uint4*)&As[row][seg * 8] = v;
        }
        #pragma unroll
        for (int j = 0; j < 4; ++j) {
            int idx = t + j * 256;
            ((uint4*)Wls)[idx] = ((const uint4*)(Wp1 + (size_t)ch * 8192))[idx];
        }
        __syncthreads();

        #pragma unroll
        for (int ks = 0; ks < 2; ++ks) {
            short8_t af = *(const short8_t*)&As[wave * 16 + cb][ks * 32 + rq * 8];
            #pragma unroll
            for (int nt = 0; nt < 8; ++nt) {
                short8_t bf = *(const short8_t*)&Wls[((nt * 2 + ks) * 64 + lane) * 8];
                acc[nt] = __builtin_amdgcn_mfma_f32_16x16x32_bf16(af, bf, acc[nt], 0, 0, 0);
            }
        }
        __syncthreads();
    }

    // ---- stage 2 prep: e1 -> LDS (bf16), W2 -> LDS ----
    unsigned short (*E1)[136] = (unsigned short(*)[136])smem;
    unsigned short* W2s = smem + 8704;
    #pragma unroll
    for (int nt = 0; nt < 8; ++nt) {
        int col = nt * 16 + cb;
        float bv = b1[col];
        #pragma unroll
        for (int r = 0; r < 4; ++r) {
            int row = wave * 16 + rq * 4 + r;
            E1[row][col] = f2bf(fmaxf(acc[nt][r] + bv, 0.f));
        }
    }
    ((uint4*)W2s)[t]       = ((const uint4*)Wp2)[t];
    ((uint4*)W2s)[t + 256] = ((const uint4*)Wp2)[t + 256];
    __syncthreads();

    // ---- stage 2 MFMA: NT16=4, NCH=2 over the 128-wide e1 ----
    f32x4 acc2[4];
    #pragma unroll
    for (int nt = 0; nt < 4; ++nt) acc2[nt] = (f32x4){0.f, 0.f, 0.f, 0.f};
    #pragma unroll
    for (int ch = 0; ch < 2; ++ch) {
        #pragma unroll
        for (int ks = 0; ks < 2; ++ks) {
            short8_t af = *(const short8_t*)&E1[wave * 16 + cb][ch * 64 + ks * 32 + rq * 8];
            #pragma unroll
            for (int nt = 0; nt < 4; ++nt) {
                short8_t bf = *(const short8_t*)&W2s[(((ch * 4 + nt) * 2 + ks) * 64 + lane) * 8];
                acc2[nt] = __builtin_amdgcn_mfma_f32_16x16x32_bf16(af, bf, acc2[nt], 0, 0, 0);
            }
        }
    }

    // ---- epilogue: relu + dot(w3) + sigmoid ----
    float s0 = 0.f, s1 = 0.f, s2 = 0.f, s3 = 0.f;
    #pragma unroll
    for (int nt = 0; nt < 4; ++nt) {
        int col = nt * 16 + cb;
        float bv = b2[col], wv = w3[col];
        s0 += fmaxf(acc2[nt][0] + bv, 0.f) * wv;
        s1 += fmaxf(acc2[nt][1] + bv, 0.f) * wv;
        s2 += fmaxf(acc2[nt][2] + bv, 0.f) * wv;
        s3 += fmaxf(acc2[nt][3] + bv, 0.f) * wv;
    }
    #pragma unroll
    for (int off = 1; off < 16; off <<= 1) {
        s0 += __shfl_xor(s0, off);
        s1 += __shfl_xor(s1, off);
        s2 += __shfl_xor(s2, off);
        s3 += __shfl_xor(s3, off);
    }
    if (cb == 0) {
        int gr = m0 + wave * 16 + rq * 4;
        if (gr + 3 < M) {
            float bb = b3[0];
            float4 o;
            o.x = 1.f / (1.f + expf(-(s0 + bb)));
            o.y = 1.f / (1.f + expf(-(s1 + bb)));
            o.z = 1.f / (1.f + expf(-(s2 + bb)));
            o.w = 1.f / (1.f + expf(-(s3 + bb)));
            *(float4*)&out[gr] = o;
        }
    }
}

// ---------------- CSR aggregation (8 nodes/wave, uint4 = 8 f16/lane) --------
// WF32: write fp32 h (residual chain); WBF16: write bf16 copy for next conv.
template<bool RESIDUAL, bool WF32, bool WBF16>
__device__ __forceinline__ void agg_body(
    const uint4* __restrict__ y4, const int* __restrict__ row_ptr, const int* __restrict__ col,
    const float* __restrict__ dinv, const float* __restrict__ bias,
    const float* __restrict__ hprev, float* __restrict__ hout,
    uint4* __restrict__ hb4)
{
    int v  = blockIdx.x * 32 + (threadIdx.x >> 3);
    int sl = threadIdx.x & 7;
    if (v >= N_NODES) return;

    uint4 a = y4[(size_t)v * 8 + sl];              // self loop
    float2 p0 = up16(a.x), p1 = up16(a.y), p2 = up16(a.z), p3 = up16(a.w);
    float s0 = p0.x, s1 = p0.y, s2 = p1.x, s3 = p1.y;
    float s4 = p2.x, s5 = p2.y, s6 = p3.x, s7 = p3.y;

    int s = row_ptr[v], e = row_ptr[v + 1];
    int i = s;
    for (; i + 3 < e; i += 4) {
        int u0 = col[i], u1 = col[i + 1], u2 = col[i + 2], u3 = col[i + 3];
        uint4 f0 = y4[(size_t)u0 * 8 + sl];
        uint4 f1 = y4[(size_t)u1 * 8 + sl];
        uint4 f2 = y4[(size_t)u2 * 8 + sl];
        uint4 f3 = y4[(size_t)u3 * 8 + sl];
        float2 g;
        g = up16(f0.x); s0 += g.x; s1 += g.y;  g = up16(f0.y); s2 += g.x; s3 += g.y;
        g = up16(f0.z); s4 += g.x; s5 += g.y;  g = up16(f0.w); s6 += g.x; s7 += g.y;
        g = up16(f1.x); s0 += g.x; s1 += g.y;  g = up16(f1.y); s2 += g.x; s3 += g.y;
        g = up16(f1.z); s4 += g.x; s5 += g.y;  g = up16(f1.w); s6 += g.x; s7 += g.y;
        g = up16(f2.x); s0 += g.x; s1 += g.y;  g = up16(f2.y); s2 += g.x; s3 += g.y;
        g = up16(f2.z); s4 += g.x; s5 += g.y;  g = up16(f2.w); s6 += g.x; s7 += g.y;
        g = up16(f3.x); s0 += g.x; s1 += g.y;  g = up16(f3.y); s2 += g.x; s3 += g.y;
        g = up16(f3.z); s4 += g.x; s5 += g.y;  g = up16(f3.w); s6 += g.x; s7 += g.y;
    }
    for (; i < e; ++i) {
        uint4 f = y4[(size_t)col[i] * 8 + sl];
        float2 g;
        g = up16(f.x); s0 += g.x; s1 += g.y;  g = up16(f.y); s2 += g.x; s3 += g.y;
        g = up16(f.z); s4 += g.x; s5 += g.y;  g = up16(f.w); s6 += g.x; s7 += g.y;
    }

    float dv = dinv[v];
    float4 ba = *(const float4*)&bias[sl * 8];
    float4 bb = *(const float4*)&bias[sl * 8 + 4];
    float v0 = fmaxf(dv * s0 + ba.x, 0.f), v1 = fmaxf(dv * s1 + ba.y, 0.f);
    float v2 = fmaxf(dv * s2 + ba.z, 0.f), v3 = fmaxf(dv * s3 + ba.w, 0.f);
    float v4 = fmaxf(dv * s4 + bb.x, 0.f), v5 = fmaxf(dv * s5 + bb.y, 0.f);
    float v6 = fmaxf(dv * s6 + bb.z, 0.f), v7 = fmaxf(dv * s7 + bb.w, 0.f);
    if (RESIDUAL) {
        float4 h0 = *(const float4*)&hprev[(size_t)v * 64 + sl * 8];
        float4 h1 = *(const float4*)&hprev[(size_t)v * 64 + sl * 8 + 4];
        v0 += h0.x; v1 += h0.y; v2 += h0.z; v3 += h0.w;
        v4 += h1.x; v5 += h1.y; v6 += h1.z; v7 += h1.w;
    }
    if (WF32) {
        *(float4*)&hout[(size_t)v * 64 + sl * 8]     = make_float4(v0, v1, v2, v3);
        *(float4*)&hout[(size_t)v * 64 + sl * 8 + 4] = make_float4(v4, v5, v6, v7);
    }
    if (WBF16) {
        uint4 p;
        p.x = (unsigned)f2bf(v0) | ((unsigned)f2bf(v1) << 16);
        p.y = (unsigned)f2bf(v2) | ((unsigned)f2bf(v3) << 16);
        p.z = (unsigned)f2bf(v4) | ((unsigned)f2bf(v5) << 16);
        p.w = (unsigned)f2bf(v6) | ((unsigned)f2bf(v7) << 16);
        hb4[(size_t)v * 8 + sl] = p;
    }
}

__global__ __launch_bounds__(256) void agg0_kernel(const uint4* y, const int* rp, const int* col,
                                                   const float* dinv, const float* b, float* h, uint4* hb) {
    agg_body<false, true, true>(y, rp, col, dinv, b, nullptr, h, hb);
}
__global__ __launch_bounds__(256) void agg1_kernel(const uint4* y, const int* rp, const int* col,
                                                   const float* dinv, const float* b, float* h, uint4* hb) {
    agg_body<true, true, true>(y, rp, col, dinv, b, h, h, hb);   // in-place: group owns its row
}
__global__ __launch_bounds__(256) void agg2_kernel(const uint4* y, const int* rp, const int* col,
                                                   const float* dinv, const float* b,
                                                   const float* hprev, uint4* hb) {
    agg_body<true, false, true>(y, rp, col, dinv, b, hprev, nullptr, hb);
}

extern "C" void kernel_launch(void* const* d_in, const int* in_sizes, int n_in,
                              void* d_out, int out_size, void* d_ws, size_t ws_size,
                              hipStream_t stream) {
    const float* x       = (const float*)d_in[0];
    const int*   ei      = (const int*)d_in[1];
    const int*   eli     = (const int*)d_in[2];
    const float* enc_w1  = (const float*)d_in[3];
    const float* enc_b1  = (const float*)d_in[4];
    const float* enc_w2  = (const float*)d_in[5];
    const float* enc_b2  = (const float*)d_in[6];
    const float* conv_w0 = (const float*)d_in[7];
    const float* conv_b0 = (const float*)d_in[8];
    const float* conv_w1 = (const float*)d_in[9];
    const float* conv_b1 = (const float*)d_in[10];
    const float* conv_w2 = (const float*)d_in[11];
    const float* conv_b2 = (const float*)d_in[12];
    const float* ep_w1   = (const float*)d_in[13];
    const float* ep_b1   = (const float*)d_in[14];
    const float* ep_w2   = (const float*)d_in[15];
    const float* ep_b2   = (const float*)d_in[16];
    const float* ep_w3   = (const float*)d_in[17];
    const float* ep_b3   = (const float*)d_in[18];
    float* out = (float*)d_out;

    // ---- workspace layout (float offsets) ----
    float* fws = (float*)d_ws;
    unsigned short* h1b  = (unsigned short*)fws;                 // bf16 [100k,256] = 12.8M f
    unsigned short* h128b= (unsigned short*)(fws + 12800000);    // bf16 [100k,128] = 6.4M f
    _Float16* yb         = (_Float16*)(fws + 25600000);          // f16 [100k,64] = 3.2M f
    float* h64           = fws + 28800000;                       // f32 [100k,64] = 6.4M f
    unsigned short* h64b = (unsigned short*)(fws + 35200000);    // bf16 [100k,64] = 3.2M f
    int*   col     = (int*)(fws + 38400000);                     // 1.6M i
    int*   row_ptr = col + 1600000;                              // 100001 (padded)
    float* dinvp   = (float*)(row_ptr + 100032);
    unsigned short* w2p = (unsigned short*)(dinvp + 100000);     // enc_w2: 32768 us
    unsigned short* w0p = w2p + 32768;                           // conv_w0: 8192 us
    unsigned short* w1p = w0p + 8192;                            // ep_w1: 16384 us
    unsigned short* wp2 = w1p + 16384;                           // ep_w2: 8192 us
    unsigned short* w1e = wp2 + 8192;                            // enc_w1: 8192 us
    unsigned short* wc1p = w1e + 8192;                           // conv_w1: 4096 us
    unsigned short* wc2p = wc1p + 4096;                          // conv_w2: 4096 us
    int*   btail   = (int*)(wc2p + 4096);                        // 98 i (+pad to 128)
    int*   bscr    = btail + 128;                                // 98*24576 = 2.41M i

    // ---- CSR build + weight swizzle (no global atomics anywhere) ----
    hipMemsetAsync(btail, 0, 128 * sizeof(int), stream);
    fill_part<<<PART_NB, 256, 0, stream>>>(ei, btail, bscr);
    wprep_all<<<320, 256, 0, stream>>>(enc_w2, conv_w0, ep_w1, ep_w2, enc_w1, conv_w1, conv_w2,
                                       w2p, w0p, w1p, wp2, w1e, wc1p, wc2p);
    fill_place<<<KBUCK, 1024, 0, stream>>>(btail, bscr, row_ptr, dinvp, col);

    const int GBN = (N_NODES + 63) / 64;   // 1563
    const int GBE = N_EL / 64;             // 3125
    const int GBA = (N_NODES + 31) / 32;   // 3125

    // ---- encoder (both MFMA) ----
    mfma_enc1<<<GBN, 256, 0, stream>>>(x, w1e, enc_b1, h1b, N_NODES);
    mfma_enc2<<<GBN, 256, 0, stream>>>(h1b, w2p, enc_b2, h128b, N_NODES);

    // ---- GCN layer 0: 128 -> 64 (MFMA, bf16 in, f16 y out) ----
    mfma_conv0<<<GBN, 256, 0, stream>>>(h128b, w0p, dinvp, yb, N_NODES);
    agg0_kernel<<<GBA, 256, 0, stream>>>((const uint4*)yb, row_ptr, col, dinvp, conv_b0, h64, (uint4*)h64b);

    // ---- GCN layer 1: 64 -> 64, residual (MFMA on bf16 h) ----
    mfma_conv1<<<GBN, 256, 0, stream>>>(h64b, wc1p, dinvp, yb, N_NODES);
    agg1_kernel<<<GBA, 256, 0, stream>>>((const uint4*)yb, row_ptr, col, dinvp, conv_b1, h64, (uint4*)h64b);

    // ---- GCN layer 2: 64 -> 64, residual, bf16 out for ep ----
    mfma_conv2<<<GBN, 256, 0, stream>>>(h64b, wc2p, dinvp, yb, N_NODES);
    agg2_kernel<<<GBA, 256, 0, stream>>>((const uint4*)yb, row_ptr, col, dinvp, conv_b2, h64, (uint4*)h64b);

    // ---- edge predictor: ep1+ep2+ep3 fused, e1 lives in LDS ----
    mfma_ep12<<<GBE, 256, 0, stream>>>(h64b, eli, w1p, ep_b1, wp2, ep_b2, ep_w3, ep_b3, out, N_EL);
}

// Round 16
// 320.760 us; speedup vs baseline: 1.9576x; 1.1228x over previous
//
#include <hip/hip_runtime.h>
#include <math.h>

// ---------------------------------------------------------------------------
// EmergencyGNNEnhanced: encoder (32->256->128) -> 3x GCN (->64) -> edge MLP.
// CSR built on-device each call. agg[v] = dinv[v]*(sum_{u->v} y[u] + y[v]).
//
// R16: enc1+enc2+conv0 fused into mfma_encfull -- all three are row-local,
// so h1 (64x256) and h128 (64x136) live in LDS overlays (50.2KB, 3 blk/CU)
// and ~154MB of h1b/h128b HBM round-trips disappear along with 2 dispatches.
// Aggs / ep12 unchanged (structural gather floor). MFMA layouts HW-verified
// (R5-R15 passed).
// ---------------------------------------------------------------------------

#define N_NODES 100000
#define N_EDGES 1600000
#define N_EL    200000

#define KBUCK   98           // ceil(100000/1024) windows of 1024 nodes
#define WSHIFT  10
#define WMASK   1023
#define BCAP    128          // LDS entries/bucket in pass A (chunk avg 32)
#define BSTRIDE 24576        // scratch ints per bucket (seglen ~16.4k avg)
#define PART_NB 512
#define CHUNK   3125         // ceil(N_EDGES / PART_NB)
#define LCAP    20480        // pass-B LDS staging (seglen max ~17k)

typedef __attribute__((ext_vector_type(8))) short short8_t;
typedef __attribute__((ext_vector_type(4))) float f32x4;

__device__ __forceinline__ unsigned short f2bf(float f) {
    unsigned u = __float_as_uint(f);
    unsigned r = u + 0x7FFFu + ((u >> 16) & 1u);   // RNE
    return (unsigned short)(r >> 16);
}

__device__ __forceinline__ float2 up16(unsigned u) {
    union { unsigned v; _Float16 h[2]; } c; c.v = u;
    return make_float2((float)c.h[0], (float)c.h[1]);
}

// ---- fill pass A: partition edges into 98 dst-window buckets ----
__global__ __launch_bounds__(256) void fill_part(const int* __restrict__ ei,
                                                 int* __restrict__ btail, int* __restrict__ bscr) {
    __shared__ int lbuf[KBUCK][BCAP];     // 50 KB
    __shared__ int lcnt[KBUCK];
    __shared__ int offs[KBUCK + 1];
    __shared__ int gbase[KBUCK];
    int t = threadIdx.x;
    for (int i = t; i < KBUCK; i += 256) lcnt[i] = 0;
    __syncthreads();

    int e0   = blockIdx.x * CHUNK;
    int eend = e0 + CHUNK; if (eend > N_EDGES) eend = N_EDGES;
    for (int e = e0 + t; e < eend; e += 256) {
        int s = __builtin_nontemporal_load(ei + e);
        int d = __builtin_nontemporal_load(ei + N_EDGES + e);
        int b = d >> WSHIFT;
        int entry = ((d & WMASK) << 17) | s;
        int pos = atomicAdd(&lcnt[b], 1);
        if (pos < BCAP) lbuf[b][pos] = entry;
        else {                                  // statistical-skew spill (rare)
            int p = atomicAdd(&btail[b], 1);
            bscr[b * BSTRIDE + p] = entry;
        }
    }
    __syncthreads();

    if (t < KBUCK) {
        int c = lcnt[t]; if (c > BCAP) c = BCAP;
        lcnt[t] = c;
        gbase[t] = atomicAdd(&btail[t], c);
    }
    __syncthreads();
    if (t == 0) {
        offs[0] = 0;
        for (int b = 0; b < KBUCK; ++b) offs[b + 1] = offs[b] + lcnt[b];
    }
    __syncthreads();

    int T = offs[KBUCK];
    for (int i = t; i < T; i += 256) {
        int loB = 0, hiB = KBUCK;               // binary search bucket
        while (hiB - loB > 1) { int mid = (loB + hiB) >> 1; if (offs[mid] <= i) loB = mid; else hiB = mid; }
        int j = i - offs[loB];
        bscr[loB * BSTRIDE + gbase[loB] + j] = lbuf[loB][j];
    }
}

// ---- fill_place: btail prefix + hist + local scan + row_ptr/dinv + scatter ----
__global__ __launch_bounds__(1024) void fill_place(const int* __restrict__ btail,
                                                   const int* __restrict__ bscr,
                                                   int* __restrict__ row_ptr, float* __restrict__ dinv,
                                                   int* __restrict__ col) {
    __shared__ int ssm[128];
    __shared__ int lcnt[1024];
    __shared__ int lpre[1024];
    __shared__ int lbuf[LCAP];                  // 80 KB
    int b = blockIdx.x, t = threadIdx.x;

    if (t < 128) ssm[t] = (t < KBUCK) ? btail[t] : 0;
    lcnt[t] = 0;
    __syncthreads();
    for (int s = 1; s < 128; s <<= 1) {         // inclusive scan of btail
        int a = 0;
        if (t < 128 && t >= s) a = ssm[t - s];
        __syncthreads();
        if (t < 128) ssm[t] += a;
        __syncthreads();
    }
    int segstart = (b == 0) ? 0 : ssm[b - 1];
    int n = btail[b];
    const int* src = bscr + b * BSTRIDE;
    for (int i = t; i < n; i += 1024)
        atomicAdd(&lcnt[src[i] >> 17], 1);
    __syncthreads();

    int c = lcnt[t];
    lpre[t] = c; __syncthreads();
    for (int s = 1; s < 1024; s <<= 1) {        // inclusive scan
        int a = (t >= s) ? lpre[t - s] : 0;
        __syncthreads();
        lpre[t] += a;
        __syncthreads();
    }
    int excl = lpre[t] - c;

    int v = (b << WSHIFT) + t;
    if (v < N_NODES) {
        row_ptr[v] = segstart + excl;
        dinv[v] = rsqrtf((float)(c + 1));       // +1 self loop
    }
    if (b == KBUCK - 1 && t == 0) row_ptr[N_NODES] = N_EDGES;
    lcnt[t] = excl;                             // reuse as cursor
    __syncthreads();

    if (n <= LCAP) {
        for (int i = t; i < n; i += 1024) {
            int e = src[i];
            int pos = atomicAdd(&lcnt[e >> 17], 1);
            lbuf[pos] = e & 0x1FFFF;
        }
        __syncthreads();
        for (int i = t; i < n; i += 1024)
            col[segstart + i] = lbuf[i];
    } else {                                    // safety fallback (never for this dist)
        for (int i = t; i < n; i += 1024) {
            int e = src[i];
            int pos = atomicAdd(&lcnt[e >> 17], 1);
            col[segstart + pos] = e & 0x1FFFF;
        }
    }
}

// ---------------- weight swizzle: fp32 W[K][N] -> bf16 B-fragment order -----
template<int KTOT, int NTOT>
__device__ __forceinline__ void wprep_one(const float* __restrict__ W, unsigned short* __restrict__ Wp, int flat) {
    if (flat >= KTOT * NTOT) return;
    int j = flat & 7, lane = (flat >> 3) & 63, kstep = (flat >> 9) & 1;
    int rest = flat >> 10;
    int ntile = rest % (NTOT / 16), chunk = rest / (NTOT / 16);
    int k = chunk * 64 + kstep * 32 + (lane >> 4) * 8 + j;
    int n = ntile * 16 + (lane & 15);
    Wp[flat] = f2bf(W[(size_t)k * NTOT + n]);
}

// K=32 variant (single k-step) for enc_w1 [32 x 256]
__device__ __forceinline__ void wprep32_one(const float* __restrict__ W, unsigned short* __restrict__ Wp, int flat) {
    if (flat >= 32 * 256) return;
    int j = flat & 7, lane = (flat >> 3) & 63, ntile = flat >> 9;   // 0..15
    int k = (lane >> 4) * 8 + j;
    int n = ntile * 16 + (lane & 15);
    Wp[flat] = f2bf(W[(size_t)k * 256 + n]);
}

// One dispatch for all 7 weight swizzles (320 blocks).
__global__ __launch_bounds__(256) void wprep_all(
    const float* w2, const float* w0, const float* w1, const float* wpp2, const float* w1e,
    const float* wc1, const float* wc2,
    unsigned short* p2, unsigned short* p0, unsigned short* p1, unsigned short* pp2,
    unsigned short* p1e, unsigned short* pc1, unsigned short* pc2)
{
    int blk = blockIdx.x, t = threadIdx.x;
    if      (blk < 128) wprep_one<256, 128>(w2,  p2,  blk * 256 + t);
    else if (blk < 160) wprep_one<128,  64>(w0,  p0,  (blk - 128) * 256 + t);
    else if (blk < 224) wprep_one<128, 128>(w1,  p1,  (blk - 160) * 256 + t);
    else if (blk < 256) wprep_one<128,  64>(wpp2, pp2, (blk - 224) * 256 + t);
    else if (blk < 288) wprep32_one(w1e, p1e, (blk - 256) * 256 + t);
    else if (blk < 304) wprep_one< 64,  64>(wc1, pc1, (blk - 288) * 256 + t);
    else                wprep_one< 64,  64>(wc2, pc2, (blk - 304) * 256 + t);
}

// ---------------- fused encoder: x -> h1 -> h128 -> y0, all in LDS ----------
// Stage1 (enc1): h1 = relu(bf16(x)@W1+b1)      -- K=32, NT16=16, h1 -> LDS
// Stage2 (enc2): h128 = relu(h1@W2+b2)          -- K=256 (4 chunks), NT16=8
// Stage3 (conv0): y = f16(dinv .* (h128@W0))    -- K=128 (2 chunks), NT16=4
// LDS overlays: region0 = {As+W1 | H1[64][264] | H128[64][136]} (33792 B),
//               region1 = {W2chunk 16KB | W0 8KB} -> total 50176 B, 3 blk/CU.
__global__ __launch_bounds__(256, 3) void mfma_encfull(
    const float* __restrict__ x,
    const unsigned short* __restrict__ Wp1, const float* __restrict__ b1,
    const unsigned short* __restrict__ Wp2, const float* __restrict__ b2,
    const unsigned short* __restrict__ Wp0, const float* __restrict__ dinv,
    _Float16* __restrict__ yout, int M)
{
    __shared__ __align__(16) unsigned short smem[25088];   // 50176 B
    unsigned short (*As)[40]   = (unsigned short(*)[40])smem;      // 5120 B
    unsigned short* Wls1       = smem + 2560;                      // 16384 B (ends 21504)
    unsigned short (*H1)[264]  = (unsigned short(*)[264])smem;     // 33792 B
    unsigned short (*H128)[136]= (unsigned short(*)[136])smem;     // 17408 B
    unsigned short* Wls2       = smem + 16896;                     // region1: 16384 B
    unsigned short* W0s        = smem + 16896;                     // region1 alias: 8192 B

    int t = threadIdx.x, wave = t >> 6, lane = t & 63;
    int m0 = blockIdx.x * 64;
    int cb = lane & 15, rq = lane >> 4;

    {   // stage A: 64 rows x 32 k, fp32 -> bf16 (8 floats/thread)
        int row = t >> 2, seg = t & 3;
        int gr = m0 + row;
        float4 a = make_float4(0.f, 0.f, 0.f, 0.f), b = a;
        if (gr < M) {
            a = *(const float4*)&x[(size_t)gr * 32 + seg * 8];
            b = *(const float4*)&x[(size_t)gr * 32 + seg * 8 + 4];
        }
        unsigned short tmp[8] = { f2bf(a.x), f2bf(a.y), f2bf(a.z), f2bf(a.w),
                                  f2bf(b.x), f2bf(b.y), f2bf(b.z), f2bf(b.w) };
        *(uint4*)&As[row][seg * 8] = *(uint4*)tmp;
    }
    #pragma unroll
    for (int j = 0; j < 4; ++j)
        ((uint4*)Wls1)[t + j * 256] = ((const uint4*)Wp1)[t + j * 256];
    __syncthreads();

    // ---- stage1 MFMA: 16 ntiles, K=32 single step ----
    short8_t af1 = *(const short8_t*)&As[wave * 16 + cb][rq * 8];
    f32x4 acc[16];
    #pragma unroll
    for (int nt = 0; nt < 16; ++nt) {
        short8_t bf = *(const short8_t*)&Wls1[(nt * 64 + lane) * 8];
        acc[nt] = __builtin_amdgcn_mfma_f32_16x16x32_bf16(af1, bf, (f32x4){0.f, 0.f, 0.f, 0.f}, 0, 0, 0);
    }
    __syncthreads();                            // As/Wls1 reads done; region0 -> H1

    #pragma unroll
    for (int nt = 0; nt < 16; ++nt) {
        int col = nt * 16 + cb;
        float bv = b1[col];
        #pragma unroll
        for (int r = 0; r < 4; ++r)
            H1[wave * 16 + rq * 4 + r][col] = f2bf(fmaxf(acc[nt][r] + bv, 0.f));
    }

    // ---- stage2: enc2 over 4 K-chunks of 64 ----
    f32x4 acc2[8];
    #pragma unroll
    for (int nt = 0; nt < 8; ++nt) acc2[nt] = (f32x4){0.f, 0.f, 0.f, 0.f};
    for (int ch = 0; ch < 4; ++ch) {
        #pragma unroll
        for (int j = 0; j < 4; ++j)
            ((uint4*)Wls2)[t + j * 256] = ((const uint4*)(Wp2 + (size_t)ch * 8192))[t + j * 256];
        __syncthreads();                        // also orders H1 writes (ch==0)
        #pragma unroll
        for (int ks = 0; ks < 2; ++ks) {
            short8_t af = *(const short8_t*)&H1[wave * 16 + cb][ch * 64 + ks * 32 + rq * 8];
            #pragma unroll
            for (int nt = 0; nt < 8; ++nt) {
                short8_t bf = *(const short8_t*)&Wls2[((nt * 2 + ks) * 64 + lane) * 8];
                acc2[nt] = __builtin_amdgcn_mfma_f32_16x16x32_bf16(af, bf, acc2[nt], 0, 0, 0);
            }
        }
        __syncthreads();                        // before next chunk overwrites Wls2
    }

    // ---- h128 -> LDS (overwrites H1 region; last sync above ordered reads) --
    #pragma unroll
    for (int nt = 0; nt < 8; ++nt) {
        int col = nt * 16 + cb;
        float bv = b2[col];
        #pragma unroll
        for (int r = 0; r < 4; ++r)
            H128[wave * 16 + rq * 4 + r][col] = f2bf(fmaxf(acc2[nt][r] + bv, 0.f));
    }
    // stage W0 (8192 us = 512 uint4; overwrites Wls2 -- ordered by loop-exit sync)
    ((uint4*)W0s)[t]       = ((const uint4*)Wp0)[t];
    ((uint4*)W0s)[t + 256] = ((const uint4*)Wp0)[t + 256];
    __syncthreads();

    // ---- stage3: conv0, K=128 (2 chunks), NT16=4 ----
    f32x4 acc3[4];
    #pragma unroll
    for (int nt = 0; nt < 4; ++nt) acc3[nt] = (f32x4){0.f, 0.f, 0.f, 0.f};
    #pragma unroll
    for (int ch = 0; ch < 2; ++ch) {
        #pragma unroll
        for (int ks = 0; ks < 2; ++ks) {
            short8_t af = *(const short8_t*)&H128[wave * 16 + cb][ch * 64 + ks * 32 + rq * 8];
            #pragma unroll
            for (int nt = 0; nt < 4; ++nt) {
                short8_t bf = *(const short8_t*)&W0s[(((ch * 4 + nt) * 2 + ks) * 64 + lane) * 8];
                acc3[nt] = __builtin_amdgcn_mfma_f32_16x16x32_bf16(af, bf, acc3[nt], 0, 0, 0);
            }
        }
    }

    #pragma unroll
    for (int nt = 0; nt < 4; ++nt) {
        int col = nt * 16 + cb;
        #pragma unroll
        for (int r = 0; r < 4; ++r) {
            int gr = m0 + wave * 16 + rq * 4 + r;
            if (gr < M) yout[(size_t)gr * 64 + col] = (_Float16)(acc3[nt][r] * dinv[gr]);
        }
    }
}

// ---------------- bf16 MFMA GEMM (conv1/2) ----------------
template<int NTOT, int KTOT, bool BIAS_RELU, int OUTT>
__device__ __forceinline__ void mfma_gemm_body(
    const unsigned short* __restrict__ A, const unsigned short* __restrict__ Wp,
    const float* __restrict__ bias, const float* __restrict__ dinv,
    void* __restrict__ Cout, int M)
{
    constexpr int NT16 = NTOT / 16;
    constexpr int NCH  = KTOT / 64;
    __shared__ unsigned short As[64][72];
    __shared__ unsigned short Wls[NT16 * 1024];

    int t = threadIdx.x, wave = t >> 6, lane = t & 63;
    int m0 = blockIdx.x * 64;

    f32x4 acc[NT16];
    #pragma unroll
    for (int nt = 0; nt < NT16; ++nt) acc[nt] = (f32x4){0.f, 0.f, 0.f, 0.f};

    for (int ch = 0; ch < NCH; ++ch) {
        #pragma unroll
        for (int j = 0; j < 2; ++j) {
            int idx = t + j * 256;
            int row = idx >> 3, seg = idx & 7;
            int gr = m0 + row;
            uint4 v = make_uint4(0u, 0u, 0u, 0u);
            if (gr < M) v = *(const uint4*)(A + (size_t)gr * KTOT + ch * 64 + seg * 8);
            *(uint4*)&As[row][seg * 8] = v;
        }
        constexpr int WL16 = NT16 * 128;            // uint4 count
        #pragma unroll
        for (int j = 0; j < WL16 / 256; ++j) {
            int idx = t + j * 256;
            ((uint4*)Wls)[idx] = ((const uint4*)(Wp + (size_t)ch * NT16 * 1024))[idx];
        }
        __syncthreads();

        #pragma unroll
        for (int ks = 0; ks < 2; ++ks) {
            short8_t af = *(const short8_t*)&As[wave * 16 + (lane & 15)][ks * 32 + (lane >> 4) * 8];
            #pragma unroll
            for (int nt = 0; nt < NT16; ++nt) {
                short8_t bf = *(const short8_t*)&Wls[((nt * 2 + ks) * 64 + lane) * 8];
                acc[nt] = __builtin_amdgcn_mfma_f32_16x16x32_bf16(af, bf, acc[nt], 0, 0, 0);
            }
        }
        __syncthreads();
    }

    int cb = lane & 15, rq = lane >> 4;
    #pragma unroll
    for (int nt = 0; nt < NT16; ++nt) {
        int col = nt * 16 + cb;
        float bv = BIAS_RELU ? bias[col] : 0.f;
        #pragma unroll
        for (int r = 0; r < 4; ++r) {
            int gr = m0 + wave * 16 + rq * 4 + r;
            if (gr < M) {
                float val;
                if (BIAS_RELU) val = fmaxf(acc[nt][r] + bv, 0.f);
                else           val = acc[nt][r] * dinv[gr];
                size_t o = (size_t)gr * NTOT + col;
                if (OUTT == 1)      ((unsigned short*)Cout)[o] = f2bf(val);
                else if (OUTT == 2) ((_Float16*)Cout)[o] = (_Float16)val;
                else                ((float*)Cout)[o] = val;
            }
        }
    }
}

__global__ __launch_bounds__(256, 4) void mfma_conv1(const unsigned short* A, const unsigned short* Wp,
                                                     const float* dinv, _Float16* C, int M) {
    mfma_gemm_body<64, 64, false, 2>(A, Wp, nullptr, dinv, C, M);
}
__global__ __launch_bounds__(256, 4) void mfma_conv2(const unsigned short* A, const unsigned short* Wp,
                                                     const float* dinv, _Float16* C, int M) {
    mfma_gemm_body<64, 64, false, 2>(A, Wp, nullptr, dinv, C, M);
}

// ---------------- fused edge predictor ----------------
__global__ __launch_bounds__(256, 4) void mfma_ep12(
    const unsigned short* __restrict__ A, const int* __restrict__ gidx,
    const unsigned short* __restrict__ Wp1, const float* __restrict__ b1,
    const unsigned short* __restrict__ Wp2, const float* __restrict__ b2,
    const float* __restrict__ w3, const float* __restrict__ b3,
    float* __restrict__ out, int M)
{
    __shared__ __align__(16) unsigned short smem[12800];    // 25600 B
    unsigned short (*As)[72] = (unsigned short(*)[72])smem;
    unsigned short* Wls = smem + 4608;

    int t = threadIdx.x, wave = t >> 6, lane = t & 63;
    int m0 = blockIdx.x * 64;
    int cb = lane & 15, rq = lane >> 4;

    f32x4 acc[8];
    #pragma unroll
    for (int nt = 0; nt < 8; ++nt) acc[nt] = (f32x4){0.f, 0.f, 0.f, 0.f};

    for (int ch = 0; ch < 2; ++ch) {
        #pragma unroll
        for (int j = 0; j < 2; ++j) {
            int idx = t + j * 256;
            int row = idx >> 3, seg = idx & 7;
            int gr = m0 + row;
            uint4 v = make_uint4(0u, 0u, 0u, 0u);
            if (gr < M) {
                int node = (ch == 0) ? gidx[gr] : gidx[N_EL + gr];
                v = *(const uint4*)(A + (size_t)node * 64 + seg * 8);
            }
            *(uint4*)&As[row][seg * 8] = v;
        }
        #pragma unroll
        for (int j = 0; j < 4; ++j) {
            int idx = t + j * 256;
            ((uint4*)Wls)[idx] = ((const uint4*)(Wp1 + (size_t)ch * 8192))[idx];
        }
        __syncthreads();

        #pragma unroll
        for (int ks = 0; ks < 2; ++ks) {
            short8_t af = *(const short8_t*)&As[wave * 16 + cb][ks * 32 + rq * 8];
            #pragma unroll
            for (int nt = 0; nt < 8; ++nt) {
                short8_t bf = *(const short8_t*)&Wls[((nt * 2 + ks) * 64 + lane) * 8];
                acc[nt] = __builtin_amdgcn_mfma_f32_16x16x32_bf16(af, bf, acc[nt], 0, 0, 0);
            }
        }
        __syncthreads();
    }

    // ---- stage 2 prep: e1 -> LDS (bf16), W2 -> LDS ----
    unsigned short (*E1)[136] = (unsigned short(*)[136])smem;
    unsigned short* W2s = smem + 8704;
    #pragma unroll
    for (int nt = 0; nt < 8; ++nt) {
        int col = nt * 16 + cb;
        float bv = b1[col];
        #pragma unroll
        for (int r = 0; r < 4; ++r) {
            int row = wave * 16 + rq * 4 + r;
            E1[row][col] = f2bf(fmaxf(acc[nt][r] + bv, 0.f));
        }
    }
    ((uint4*)W2s)[t]       = ((const uint4*)Wp2)[t];
    ((uint4*)W2s)[t + 256] = ((const uint4*)Wp2)[t + 256];
    __syncthreads();

    // ---- stage 2 MFMA: NT16=4, NCH=2 over the 128-wide e1 ----
    f32x4 acc2[4];
    #pragma unroll
    for (int nt = 0; nt < 4; ++nt) acc2[nt] = (f32x4){0.f, 0.f, 0.f, 0.f};
    #pragma unroll
    for (int ch = 0; ch < 2; ++ch) {
        #pragma unroll
        for (int ks = 0; ks < 2; ++ks) {
            short8_t af = *(const short8_t*)&E1[wave * 16 + cb][ch * 64 + ks * 32 + rq * 8];
            #pragma unroll
            for (int nt = 0; nt < 4; ++nt) {
                short8_t bf = *(const short8_t*)&W2s[(((ch * 4 + nt) * 2 + ks) * 64 + lane) * 8];
                acc2[nt] = __builtin_amdgcn_mfma_f32_16x16x32_bf16(af, bf, acc2[nt], 0, 0, 0);
            }
        }
    }

    // ---- epilogue: relu + dot(w3) + sigmoid ----
    float s0 = 0.f, s1 = 0.f, s2 = 0.f, s3 = 0.f;
    #pragma unroll
    for (int nt = 0; nt < 4; ++nt) {
        int col = nt * 16 + cb;
        float bv = b2[col], wv = w3[col];
        s0 += fmaxf(acc2[nt][0] + bv, 0.f) * wv;
        s1 += fmaxf(acc2[nt][1] + bv, 0.f) * wv;
        s2 += fmaxf(acc2[nt][2] + bv, 0.f) * wv;
        s3 += fmaxf(acc2[nt][3] + bv, 0.f) * wv;
    }
    #pragma unroll
    for (int off = 1; off < 16; off <<= 1) {
        s0 += __shfl_xor(s0, off);
        s1 += __shfl_xor(s1, off);
        s2 += __shfl_xor(s2, off);
        s3 += __shfl_xor(s3, off);
    }
    if (cb == 0) {
        int gr = m0 + wave * 16 + rq * 4;
        if (gr + 3 < M) {
            float bb = b3[0];
            float4 o;
            o.x = 1.f / (1.f + expf(-(s0 + bb)));
            o.y = 1.f / (1.f + expf(-(s1 + bb)));
            o.z = 1.f / (1.f + expf(-(s2 + bb)));
            o.w = 1.f / (1.f + expf(-(s3 + bb)));
            *(float4*)&out[gr] = o;
        }
    }
}

// ---------------- CSR aggregation (8 nodes/wave, uint4 = 8 f16/lane) --------
template<bool RESIDUAL, bool WF32, bool WBF16>
__device__ __forceinline__ void agg_body(
    const uint4* __restrict__ y4, const int* __restrict__ row_ptr, const int* __restrict__ col,
    const float* __restrict__ dinv, const float* __restrict__ bias,
    const float* __restrict__ hprev, float* __restrict__ hout,
    uint4* __restrict__ hb4)
{
    int v  = blockIdx.x * 32 + (threadIdx.x >> 3);
    int sl = threadIdx.x & 7;
    if (v >= N_NODES) return;

    uint4 a = y4[(size_t)v * 8 + sl];              // self loop
    float2 p0 = up16(a.x), p1 = up16(a.y), p2 = up16(a.z), p3 = up16(a.w);
    float s0 = p0.x, s1 = p0.y, s2 = p1.x, s3 = p1.y;
    float s4 = p2.x, s5 = p2.y, s6 = p3.x, s7 = p3.y;

    int s = row_ptr[v], e = row_ptr[v + 1];
    int i = s;
    for (; i + 3 < e; i += 4) {
        int u0 = col[i], u1 = col[i + 1], u2 = col[i + 2], u3 = col[i + 3];
        uint4 f0 = y4[(size_t)u0 * 8 + sl];
        uint4 f1 = y4[(size_t)u1 * 8 + sl];
        uint4 f2 = y4[(size_t)u2 * 8 + sl];
        uint4 f3 = y4[(size_t)u3 * 8 + sl];
        float2 g;
        g = up16(f0.x); s0 += g.x; s1 += g.y;  g = up16(f0.y); s2 += g.x; s3 += g.y;
        g = up16(f0.z); s4 += g.x; s5 += g.y;  g = up16(f0.w); s6 += g.x; s7 += g.y;
        g = up16(f1.x); s0 += g.x; s1 += g.y;  g = up16(f1.y); s2 += g.x; s3 += g.y;
        g = up16(f1.z); s4 += g.x; s5 += g.y;  g = up16(f1.w); s6 += g.x; s7 += g.y;
        g = up16(f2.x); s0 += g.x; s1 += g.y;  g = up16(f2.y); s2 += g.x; s3 += g.y;
        g = up16(f2.z); s4 += g.x; s5 += g.y;  g = up16(f2.w); s6 += g.x; s7 += g.y;
        g = up16(f3.x); s0 += g.x; s1 += g.y;  g = up16(f3.y); s2 += g.x; s3 += g.y;
        g = up16(f3.z); s4 += g.x; s5 += g.y;  g = up16(f3.w); s6 += g.x; s7 += g.y;
    }
    for (; i < e; ++i) {
        uint4 f = y4[(size_t)col[i] * 8 + sl];
        float2 g;
        g = up16(f.x); s0 += g.x; s1 += g.y;  g = up16(f.y); s2 += g.x; s3 += g.y;
        g = up16(f.z); s4 += g.x; s5 += g.y;  g = up16(f.w); s6 += g.x; s7 += g.y;
    }

    float dv = dinv[v];
    float4 ba = *(const float4*)&bias[sl * 8];
    float4 bb = *(const float4*)&bias[sl * 8 + 4];
    float v0 = fmaxf(dv * s0 + ba.x, 0.f), v1 = fmaxf(dv * s1 + ba.y, 0.f);
    float v2 = fmaxf(dv * s2 + ba.z, 0.f), v3 = fmaxf(dv * s3 + ba.w, 0.f);
    float v4 = fmaxf(dv * s4 + bb.x, 0.f), v5 = fmaxf(dv * s5 + bb.y, 0.f);
    float v6 = fmaxf(dv * s6 + bb.z, 0.f), v7 = fmaxf(dv * s7 + bb.w, 0.f);
    if (RESIDUAL) {
        float4 h0 = *(const float4*)&hprev[(size_t)v * 64 + sl * 8];
        float4 h1 = *(const float4*)&hprev[(size_t)v * 64 + sl * 8 + 4];
        v0 += h0.x; v1 += h0.y; v2 += h0.z; v3 += h0.w;
        v4 += h1.x; v5 += h1.y; v6 += h1.z; v7 += h1.w;
    }
    if (WF32) {
        *(float4*)&hout[(size_t)v * 64 + sl * 8]     = make_float4(v0, v1, v2, v3);
        *(float4*)&hout[(size_t)v * 64 + sl * 8 + 4] = make_float4(v4, v5, v6, v7);
    }
    if (WBF16) {
        uint4 p;
        p.x = (unsigned)f2bf(v0) | ((unsigned)f2bf(v1) << 16);
        p.y = (unsigned)f2bf(v2) | ((unsigned)f2bf(v3) << 16);
        p.z = (unsigned)f2bf(v4) | ((unsigned)f2bf(v5) << 16);
        p.w = (unsigned)f2bf(v6) | ((unsigned)f2bf(v7) << 16);
        hb4[(size_t)v * 8 + sl] = p;
    }
}

__global__ __launch_bounds__(256) void agg0_kernel(const uint4* y, const int* rp, const int* col,
                                                   const float* dinv, const float* b, float* h, uint4* hb) {
    agg_body<false, true, true>(y, rp, col, dinv, b, nullptr, h, hb);
}
__global__ __launch_bounds__(256) void agg1_kernel(const uint4* y, const int* rp, const int* col,
                                                   const float* dinv, const float* b, float* h, uint4* hb) {
    agg_body<true, true, true>(y, rp, col, dinv, b, h, h, hb);   // in-place: group owns its row
}
__global__ __launch_bounds__(256) void agg2_kernel(const uint4* y, const int* rp, const int* col,
                                                   const float* dinv, const float* b,
                                                   const float* hprev, uint4* hb) {
    agg_body<true, false, true>(y, rp, col, dinv, b, hprev, nullptr, hb);
}

extern "C" void kernel_launch(void* const* d_in, const int* in_sizes, int n_in,
                              void* d_out, int out_size, void* d_ws, size_t ws_size,
                              hipStream_t stream) {
    const float* x       = (const float*)d_in[0];
    const int*   ei      = (const int*)d_in[1];
    const int*   eli     = (const int*)d_in[2];
    const float* enc_w1  = (const float*)d_in[3];
    const float* enc_b1  = (const float*)d_in[4];
    const float* enc_w2  = (const float*)d_in[5];
    const float* enc_b2  = (const float*)d_in[6];
    const float* conv_w0 = (const float*)d_in[7];
    const float* conv_b0 = (const float*)d_in[8];
    const float* conv_w1 = (const float*)d_in[9];
    const float* conv_b1 = (const float*)d_in[10];
    const float* conv_w2 = (const float*)d_in[11];
    const float* conv_b2 = (const float*)d_in[12];
    const float* ep_w1   = (const float*)d_in[13];
    const float* ep_b1   = (const float*)d_in[14];
    const float* ep_w2   = (const float*)d_in[15];
    const float* ep_b2   = (const float*)d_in[16];
    const float* ep_w3   = (const float*)d_in[17];
    const float* ep_b3   = (const float*)d_in[18];
    float* out = (float*)d_out;

    // ---- workspace layout (float offsets) ----
    float* fws = (float*)d_ws;
    _Float16* yb         = (_Float16*)fws;                       // f16 [100k,64] = 3.2M f
    float* h64           = fws + 3200000;                        // f32 [100k,64] = 6.4M f
    unsigned short* h64b = (unsigned short*)(fws + 9600000);     // bf16 [100k,64] = 3.2M f
    int*   col     = (int*)(fws + 12800000);                     // 1.6M i
    int*   row_ptr = col + 1600000;                              // 100001 (padded)
    float* dinvp   = (float*)(row_ptr + 100032);
    unsigned short* w2p = (unsigned short*)(dinvp + 100000);     // enc_w2: 32768 us
    unsigned short* w0p = w2p + 32768;                           // conv_w0: 8192 us
    unsigned short* w1p = w0p + 8192;                            // ep_w1: 16384 us
    unsigned short* wp2 = w1p + 16384;                           // ep_w2: 8192 us
    unsigned short* w1e = wp2 + 8192;                            // enc_w1: 8192 us
    unsigned short* wc1p = w1e + 8192;                           // conv_w1: 4096 us
    unsigned short* wc2p = wc1p + 4096;                          // conv_w2: 4096 us
    int*   btail   = (int*)(wc2p + 4096);                        // 98 i (+pad to 128)
    int*   bscr    = btail + 128;                                // 98*24576 = 2.41M i

    // ---- CSR build + weight swizzle (no global atomics anywhere) ----
    hipMemsetAsync(btail, 0, 128 * sizeof(int), stream);
    fill_part<<<PART_NB, 256, 0, stream>>>(ei, btail, bscr);
    wprep_all<<<320, 256, 0, stream>>>(enc_w2, conv_w0, ep_w1, ep_w2, enc_w1, conv_w1, conv_w2,
                                       w2p, w0p, w1p, wp2, w1e, wc1p, wc2p);
    fill_place<<<KBUCK, 1024, 0, stream>>>(btail, bscr, row_ptr, dinvp, col);

    const int GBN = (N_NODES + 63) / 64;   // 1563
    const int GBE = N_EL / 64;             // 3125
    const int GBA = (N_NODES + 31) / 32;   // 3125

    // ---- encoder + conv0 fused: x -> h1 -> h128 -> y0, all in LDS ----
    mfma_encfull<<<GBN, 256, 0, stream>>>(x, w1e, enc_b1, w2p, enc_b2, w0p, dinvp, yb, N_NODES);
    agg0_kernel<<<GBA, 256, 0, stream>>>((const uint4*)yb, row_ptr, col, dinvp, conv_b0, h64, (uint4*)h64b);

    // ---- GCN layer 1: 64 -> 64, residual (MFMA on bf16 h) ----
    mfma_conv1<<<GBN, 256, 0, stream>>>(h64b, wc1p, dinvp, yb, N_NODES);
    agg1_kernel<<<GBA, 256, 0, stream>>>((const uint4*)yb, row_ptr, col, dinvp, conv_b1, h64, (uint4*)h64b);

    // ---- GCN layer 2: 64 -> 64, residual, bf16 out for ep ----
    mfma_conv2<<<GBN, 256, 0, stream>>>(h64b, wc2p, dinvp, yb, N_NODES);
    agg2_kernel<<<GBA, 256, 0, stream>>>((const uint4*)yb, row_ptr, col, dinvp, conv_b2, h64, (uint4*)h64b);

    // ---- edge predictor: ep1+ep2+ep3 fused, e1 lives in LDS ----
    mfma_ep12<<<GBE, 256, 0, stream>>>(h64b, eli, w1p, ep_b1, wp2, ep_b2, ep_w3, ep_b3, out, N_EL);
}